// Round 3
// baseline (334.061 us; speedup 1.0000x reference)
//
#include <hip/hip_runtime.h>
#include <hip/hip_bf16.h>
#include <math.h>

#define N_NODES 32768
#define N_EDGES 262144
#define EPS_C 0.24253562503633297f   // 1/sqrt(17)
#define NSPEC 10

typedef __attribute__((ext_vector_type(8))) short short8;   // 8 bf16
typedef __attribute__((ext_vector_type(4))) float f32x4;    // 4 fp32 acc

#define MFMA16(a, b, c) __builtin_amdgcn_mfma_f32_16x16x32_bf16(a, b, c, 0, 0, 0)

__device__ __forceinline__ short2 cvt2(float a, float b) {
    union { __hip_bfloat162 h; short2 s; } u;
    u.h = __float22bfloat162_rn(make_float2(a, b));
    return u.s;
}
__device__ __forceinline__ unsigned short f2bf(float a) {
    return (unsigned short)cvt2(a, 0.f).x;
}
__device__ __forceinline__ float bf2f(unsigned short u) {
    return __uint_as_float(((unsigned)u) << 16);
}
__device__ __forceinline__ short8 cvt8(float4 a, float4 b) {
    short2 p0 = cvt2(a.x, a.y), p1 = cvt2(a.z, a.w);
    short2 p2 = cvt2(b.x, b.y), p3 = cvt2(b.z, b.w);
    short8 r;
    r[0] = p0.x; r[1] = p0.y; r[2] = p1.x; r[3] = p1.y;
    r[4] = p2.x; r[5] = p2.y; r[6] = p3.x; r[7] = p3.y;
    return r;
}
__device__ __forceinline__ short8 loadArow(const float* rowp, int h, int q) {
    const float* p = rowp + h * 32 + q * 8;
    return cvt8(*(const float4*)p, *(const float4*)(p + 4));
}
__device__ __forceinline__ short8 loadB(const short* P, int t, int h, int l) {
    return *(const short8*)(P + (((t * 2 + h) * 64 + l) << 3));
}

// ---------------------------------------------------------------------------
// Species counting sort — contention-free, deterministic. sort1 also zeroes
// the receiver-CSR counts array.
// ---------------------------------------------------------------------------
__global__ __launch_bounds__(256) void sort1_kernel(
    const int* __restrict__ species, int* __restrict__ counts_blk,
    int* __restrict__ lrank_arr, int* __restrict__ counts)
{
    __shared__ int wcnt[4][16];
    int n = blockIdx.x * 256 + threadIdx.x;
    counts[n] = 0;
    int sp = species[n];
    int lane = threadIdx.x & 63, wv = threadIdx.x >> 6;
    unsigned long long ltmask = (1ull << lane) - 1;
    int lrank_w = 0;
#pragma unroll
    for (int z = 0; z < NSPEC; ++z) {
        unsigned long long m = __ballot(sp == z);
        if (sp == z) lrank_w = __popcll(m & ltmask);
        if (lane == 0) wcnt[wv][z] = __popcll(m);
    }
    __syncthreads();
    int off = 0;
    for (int w = 0; w < wv; ++w) off += wcnt[w][sp];
    lrank_arr[n] = lrank_w + off;
    if (threadIdx.x < NSPEC)
        counts_blk[blockIdx.x * NSPEC + threadIdx.x] =
            wcnt[0][threadIdx.x] + wcnt[1][threadIdx.x] +
            wcnt[2][threadIdx.x] + wcnt[3][threadIdx.x];
}

// parallel block-offset scan: wave z shuffle-scans its 128 block counts
__global__ __launch_bounds__(640) void sort2_kernel(
    const int* __restrict__ counts_blk, int* __restrict__ off_blk)
{
    __shared__ int totals[16];
    int wv = threadIdx.x >> 6;        // 0..9 == species z
    int lane = threadIdx.x & 63;
    int c0 = counts_blk[lane * NSPEC + wv];
    int c1 = counts_blk[(64 + lane) * NSPEC + wv];
    int s0 = c0;
#pragma unroll
    for (int off = 1; off < 64; off <<= 1) {
        int y = __shfl_up(s0, off);
        if (lane >= off) s0 += y;
    }
    int tot0 = __shfl(s0, 63);
    int s1 = c1;
#pragma unroll
    for (int off = 1; off < 64; off <<= 1) {
        int y = __shfl_up(s1, off);
        if (lane >= off) s1 += y;
    }
    s1 += tot0;
    if (lane == 63) totals[wv] = s1;
    __syncthreads();
    int base = 0;
    for (int q = 0; q < wv; ++q) base += totals[q];
    off_blk[lane * NSPEC + wv] = base + s0 - c0;
    off_blk[(64 + lane) * NSPEC + wv] = base + s1 - c1;
}

__global__ __launch_bounds__(256) void sort3_kernel(
    const int* __restrict__ species, const int* __restrict__ lrank_arr,
    const int* __restrict__ off_blk,
    int* __restrict__ sidx, int* __restrict__ rank, int* __restrict__ spec_srt)
{
    int n = blockIdx.x * 256 + threadIdx.x;
    int sp = species[n];
    int slot = off_blk[blockIdx.x * NSPEC + sp] + lrank_arr[n];
    sidx[slot] = n;
    rank[n] = slot;
    spec_srt[slot] = sp;
}

// ---------------------------------------------------------------------------
// Receiver CSR in SORTED space
// ---------------------------------------------------------------------------
__global__ __launch_bounds__(256) void hist_kernel(
    const int* __restrict__ receivers, const int* __restrict__ rank,
    int* __restrict__ counts)
{
    int e = blockIdx.x * 256 + threadIdx.x;
    atomicAdd(&counts[rank[receivers[e]]], 1);
}

__global__ __launch_bounds__(1024) void scan_kernel(
    const int* __restrict__ counts, int* __restrict__ row_start, int* __restrict__ cursor)
{
    __shared__ int wave_tot[16];
    int tid = threadIdx.x;
    int c[32];
    int sum = 0;
#pragma unroll
    for (int i = 0; i < 32; ++i) { c[i] = counts[tid * 32 + i]; sum += c[i]; }
    int lane = tid & 63, wv = tid >> 6;
    int x = sum;
#pragma unroll
    for (int off = 1; off < 64; off <<= 1) {
        int y = __shfl_up(x, off);
        if (lane >= off) x += y;
    }
    if (lane == 63) wave_tot[wv] = x;
    __syncthreads();
    if (wv == 0 && lane < 16) {
        int t = wave_tot[lane];
#pragma unroll
        for (int off = 1; off < 16; off <<= 1) {
            int y = __shfl_up(t, off);
            if (lane >= off) t += y;
        }
        wave_tot[lane] = t;
    }
    __syncthreads();
    int excl = x - sum + (wv ? wave_tot[wv - 1] : 0);
    int run = excl;
#pragma unroll
    for (int i = 0; i < 32; ++i) {
        row_start[tid * 32 + i] = run;
        cursor[tid * 32 + i] = run;
        run += c[i];
    }
    if (tid == 1023) row_start[32768] = run;
}

__global__ __launch_bounds__(256) void scatter_kernel(
    const int* __restrict__ receivers, const int* __restrict__ rank,
    int* __restrict__ cursor, int* __restrict__ edge_ids)
{
    int e = blockIdx.x * 256 + threadIdx.x;
    int slot = atomicAdd(&cursor[rank[receivers[e]]], 1);
    edge_ids[slot] = e;
}

// ---------------------------------------------------------------------------
// Edge precompute in slot order + fused sender-rank/species stream + grp_row.
// srk[p] = rank | (species << 16)
// ---------------------------------------------------------------------------
__global__ __launch_bounds__(256) void edge_pre_kernel(
    const float* __restrict__ vectors, const int* __restrict__ edge_ids,
    const int* __restrict__ senders, const int* __restrict__ rank,
    const int* __restrict__ species, const int* __restrict__ row_start,
    float* __restrict__ edata, int* __restrict__ srk, int* __restrict__ grp_row)
{
    int p = blockIdx.x * 256 + threadIdx.x;
    int e = edge_ids[p];
    int snd = senders[e];
    srk[p] = rank[snd] | (species[snd] << 16);
    float x = vectors[e * 3 + 0], y = vectors[e * 3 + 1], z = vectors[e * 3 + 2];
    float r2 = x * x + y * y + z * z + 1e-12f;
    float r = sqrtf(r2);
    float inv = 1.0f / r;
    float* d = edata + (size_t)p * 16;
    *(float4*)d = make_float4(x * inv, y * inv, z * inv, 0.0f);
    float rc = fmaxf(r, 1e-6f);
    float r6 = r2 * r2 * r2;
    float r7 = r6 * r;
    float r8 = r6 * r2;
    float env = (r < 1.0f) ? (1.0f - 28.0f * r6 + 48.0f * r7 - 21.0f * r8) : 0.0f;
    float sc = 1.41421356237309515f * env / rc;
#pragma unroll
    for (int j = 0; j < 8; ++j)
        d[4 + j] = sc * sinf((float)(j + 1) * 3.14159265358979323846f * rc);
    d[12] = 0.f; d[13] = 0.f; d[14] = 0.f; d[15] = 0.f;

    if (p < N_EDGES / 16) {
        int target = p * 16;
        int lo = 0, hi = N_NODES - 1;
        while (lo < hi) {
            int mid = (lo + hi + 1) >> 1;
            if (row_start[mid] <= target) lo = mid; else hi = mid - 1;
        }
        grp_row[p] = lo;
    }
}

// ---------------------------------------------------------------------------
// Merged prep: weight pack (blocks<448) + zero_bnd for interaction 0.
// ---------------------------------------------------------------------------
__global__ __launch_bounds__(256) void prep_kernel(
    const float* __restrict__ Wls, const float* __restrict__ Wlv,
    const float* __restrict__ Wps, const float* __restrict__ Wpv,
    const float* __restrict__ skip_s, const float* __restrict__ skip_v,
    short* __restrict__ packW,
    const int* __restrict__ row_start,
    float* __restrict__ agg_s, float* __restrict__ agg_v)
{
    int idx = blockIdx.x * 256 + threadIdx.x;
    if (blockIdx.x < 448 && idx < 28 * 4096) {
        int m = idx >> 12, e = idx & 4095;
        int t = e >> 10, h = (e >> 9) & 1, l = (e >> 3) & 63, j = e & 7;
        int fi = h * 32 + ((l >> 4) << 3) + j;
        int fo = t * 16 + (l & 15);
        const float* src;
        if      (m < 2)  src = Wls    + m * 4096;
        else if (m < 4)  src = Wlv    + (m - 2) * 4096;
        else if (m < 6)  src = Wps    + (m - 4) * 4096;
        else if (m < 8)  src = Wpv    + (m - 6) * 4096;
        else if (m < 18) src = skip_s + (m - 8) * 4096;
        else             src = skip_v + (m - 18) * 4096;
        packW[idx] = cvt2(src[fi * 64 + fo], 0.f).x;
    }
    const int wid = threadIdx.x >> 6;
    const int f = threadIdx.x & 63;
    const int base = (blockIdx.x * 4 + wid) * 4;
#pragma unroll
    for (int t = 0; t < 4; ++t) {
        int i = base + t;
        int beg = row_start[i], end = row_start[i + 1];
        bool need = (end == beg) || (end > (((beg >> 4) + 1) << 4));
        if (need) {
            agg_s[(size_t)i * 64 + f] = 0.f;
            agg_v[((size_t)i * 3 + 0) * 64 + f] = 0.f;
            agg_v[((size_t)i * 3 + 1) * 64 + f] = 0.f;
            agg_v[((size_t)i * 3 + 2) * 64 + f] = 0.f;
        }
    }
}

// ---------------------------------------------------------------------------
// Dual-chain edge-balanced gather with depth-2 software pipeline (raw bf16
// staging, consume-time conversion, fully unrolled 16-iter loop).
// NOW 2 waves/block (128 threads): per-wave code identical; this doubles the
// workgroup-per-CU-cap-limited residency (1-wave WGs cap ~16 waves/CU,
// measured occupancy 33%). __launch_bounds__(128,4) pins VGPR <= 128 so the
// WG cap stays the binding limit. No LDS, no cross-wave interaction.
// VZERO: s from 2.5KB embed table (L1-resident; pipeline depth irrelevant).
// ---------------------------------------------------------------------------
template<int VZERO>
__global__ __launch_bounds__(128, 4) void gather_kernel(
    const float* __restrict__ edata, const int* __restrict__ srk,
    const int* __restrict__ row_start, const int* __restrict__ grp_row,
    const float* __restrict__ embed_s,
    const unsigned short* __restrict__ s_in, const unsigned short* __restrict__ v_in,
    const float* __restrict__ Wr_i,
    float* __restrict__ agg_s, float* __restrict__ agg_v)
{
    const int f = threadIdx.x & 63;
    const int w = blockIdx.x * 2 + (threadIdx.x >> 6);
    const int pA0 = w * 32;
    const int pB0 = pA0 + 16;

    float wr[5][8];
#pragma unroll
    for (int j = 0; j < 8; ++j)
#pragma unroll
        for (int p = 0; p < 5; ++p)
            wr[p][j] = (VZERO && (p == 1 || p == 3 || p == 4))
                       ? 0.f : Wr_i[j * 320 + p * 64 + f];

    int rA = grp_row[2 * w], rB = grp_row[2 * w + 1];
    int begA = row_start[rA], endA = row_start[rA + 1];
    int begB = row_start[rB], endB = row_start[rB + 1];
    float aA0 = 0.f, aA1 = 0.f, aA2 = 0.f, aA3 = 0.f;
    float aB0 = 0.f, aB1 = 0.f, aB2 = 0.f, aB3 = 0.f;

    // 3-stage pipeline state. Stage0 = edge k (consumed this iter),
    // stage1 = edge k+1 (in flight), stage2 = edge k+2 (issued this iter).
    int svA2 = srk[pA0 + 2], svB2 = srk[pB0 + 2];
    unsigned short sA0r = 0, sB0r = 0, sA1r = 0, sB1r = 0;
    float sA0f = 0.f, sB0f = 0.f, sA1f = 0.f, sB1f = 0.f;
    unsigned short vA0r0 = 0, vA0r1 = 0, vA0r2 = 0, vB0r0 = 0, vB0r1 = 0, vB0r2 = 0;
    unsigned short vA1r0 = 0, vA1r1 = 0, vA1r2 = 0, vB1r0 = 0, vB1r1 = 0, vB1r2 = 0;
    {
        int svA0 = srk[pA0], svB0 = srk[pB0];
        int svA1 = srk[pA0 + 1], svB1 = srk[pB0 + 1];
        if (VZERO) {
            sA0f = embed_s[(svA0 >> 16) * 64 + f];
            sB0f = embed_s[(svB0 >> 16) * 64 + f];
            sA1f = embed_s[(svA1 >> 16) * 64 + f];
            sB1f = embed_s[(svB1 >> 16) * 64 + f];
        } else {
            int a0 = svA0 & 0xFFFF, b0 = svB0 & 0xFFFF;
            int a1 = svA1 & 0xFFFF, b1 = svB1 & 0xFFFF;
            sA0r = s_in[(size_t)a0 * 64 + f];
            sB0r = s_in[(size_t)b0 * 64 + f];
            sA1r = s_in[(size_t)a1 * 64 + f];
            sB1r = s_in[(size_t)b1 * 64 + f];
            vA0r0 = v_in[((size_t)a0 * 3 + 0) * 64 + f];
            vA0r1 = v_in[((size_t)a0 * 3 + 1) * 64 + f];
            vA0r2 = v_in[((size_t)a0 * 3 + 2) * 64 + f];
            vB0r0 = v_in[((size_t)b0 * 3 + 0) * 64 + f];
            vB0r1 = v_in[((size_t)b0 * 3 + 1) * 64 + f];
            vB0r2 = v_in[((size_t)b0 * 3 + 2) * 64 + f];
            vA1r0 = v_in[((size_t)a1 * 3 + 0) * 64 + f];
            vA1r1 = v_in[((size_t)a1 * 3 + 1) * 64 + f];
            vA1r2 = v_in[((size_t)a1 * 3 + 2) * 64 + f];
            vB1r0 = v_in[((size_t)b1 * 3 + 0) * 64 + f];
            vB1r1 = v_in[((size_t)b1 * 3 + 1) * 64 + f];
            vB1r2 = v_in[((size_t)b1 * 3 + 2) * 64 + f];
        }
    }

#pragma unroll
    for (int k = 0; k < 16; ++k) {
        const int pA = pA0 + k, pB = pB0 + k;
        // srk prefetch for edge k+3 (A side is always in-bounds; B side
        // clamps to the last valid entry so the value stays well-formed)
        int svA3 = srk[pA + 3];
        int iB3 = pB + 3;
        int svB3 = srk[iB3 < N_EDGES ? iB3 : N_EDGES - 1];

        // issue stage-2 state loads (edge k+2) — raw bits, no conversion here
        unsigned short sA2r = 0, sB2r = 0;
        float sA2f = 0.f, sB2f = 0.f;
        unsigned short vA2r0 = 0, vA2r1 = 0, vA2r2 = 0;
        unsigned short vB2r0 = 0, vB2r1 = 0, vB2r2 = 0;
        if (VZERO) {
            sA2f = embed_s[(svA2 >> 16) * 64 + f];
            sB2f = embed_s[(svB2 >> 16) * 64 + f];
        } else {
            int a2 = svA2 & 0xFFFF, b2 = svB2 & 0xFFFF;
            sA2r = s_in[(size_t)a2 * 64 + f];
            sB2r = s_in[(size_t)b2 * 64 + f];
            vA2r0 = v_in[((size_t)a2 * 3 + 0) * 64 + f];
            vA2r1 = v_in[((size_t)a2 * 3 + 1) * 64 + f];
            vA2r2 = v_in[((size_t)a2 * 3 + 2) * 64 + f];
            vB2r0 = v_in[((size_t)b2 * 3 + 0) * 64 + f];
            vB2r1 = v_in[((size_t)b2 * 3 + 1) * 64 + f];
            vB2r2 = v_in[((size_t)b2 * 3 + 2) * 64 + f];
        }

        const float* dA = edata + (size_t)pA * 16;
        const float* dB = edata + (size_t)pB * 16;
        float4 yA = *(const float4*)dA;
        float4 qA0 = *(const float4*)(dA + 4);
        float4 qA1 = *(const float4*)(dA + 8);
        float4 yB = *(const float4*)dB;
        float4 qB0 = *(const float4*)(dB + 4);
        float4 qB1 = *(const float4*)(dB + 8);

        float rbA[8] = {qA0.x, qA0.y, qA0.z, qA0.w, qA1.x, qA1.y, qA1.z, qA1.w};
        float rbB[8] = {qB0.x, qB0.y, qB0.z, qB0.w, qB1.x, qB1.y, qB1.z, qB1.w};
        float wA0 = 0.f, wA1 = 0.f, wA2 = 0.f, wA3 = 0.f, wA4 = 0.f;
        float wB0 = 0.f, wB1 = 0.f, wB2 = 0.f, wB3 = 0.f, wB4 = 0.f;
#pragma unroll
        for (int j = 0; j < 8; ++j) {
            wA0 = fmaf(rbA[j], wr[0][j], wA0);  wB0 = fmaf(rbB[j], wr[0][j], wB0);
            if (!VZERO) { wA1 = fmaf(rbA[j], wr[1][j], wA1);  wB1 = fmaf(rbB[j], wr[1][j], wB1); }
            wA2 = fmaf(rbA[j], wr[2][j], wA2);  wB2 = fmaf(rbB[j], wr[2][j], wB2);
            if (!VZERO) { wA3 = fmaf(rbA[j], wr[3][j], wA3);  wB3 = fmaf(rbB[j], wr[3][j], wB3); }
            if (!VZERO) { wA4 = fmaf(rbA[j], wr[4][j], wA4);  wB4 = fmaf(rbB[j], wr[4][j], wB4); }
        }

        // consume stage0 — conversion (exact shift) happens HERE, so the
        // s_waitcnt for these loads lands 2 iterations after issue.
        if (VZERO) {
            float ssA = sA0f, ssB = sB0f;
            aA0 += wA0 * ssA;
            float wsA = wA2 * ssA;
            aA1 += wsA * yA.x; aA2 += wsA * yA.y; aA3 += wsA * yA.z;
            aB0 += wB0 * ssB;
            float wsB = wB2 * ssB;
            aB1 += wsB * yB.x; aB2 += wsB * yB.y; aB3 += wsB * yB.z;
        } else {
            float ssA = bf2f(sA0r), ssB = bf2f(sB0r);
            float va0 = bf2f(vA0r0), va1 = bf2f(vA0r1), va2 = bf2f(vA0r2);
            float vb0 = bf2f(vB0r0), vb1 = bf2f(vB0r1), vb2 = bf2f(vB0r2);
            float dotA = va0 * yA.x + va1 * yA.y + va2 * yA.z;
            aA0 += wA0 * ssA + wA1 * dotA;
            float cA0 = va1 * yA.z - va2 * yA.y;
            float cA1 = va2 * yA.x - va0 * yA.z;
            float cA2 = va0 * yA.y - va1 * yA.x;
            float wsA = wA2 * ssA;
            aA1 += wsA * yA.x + wA3 * va0 + wA4 * cA0;
            aA2 += wsA * yA.y + wA3 * va1 + wA4 * cA1;
            aA3 += wsA * yA.z + wA3 * va2 + wA4 * cA2;
            float dotB = vb0 * yB.x + vb1 * yB.y + vb2 * yB.z;
            aB0 += wB0 * ssB + wB1 * dotB;
            float cB0 = vb1 * yB.z - vb2 * yB.y;
            float cB1 = vb2 * yB.x - vb0 * yB.z;
            float cB2 = vb0 * yB.y - vb1 * yB.x;
            float wsB = wB2 * ssB;
            aB1 += wsB * yB.x + wB3 * vb0 + wB4 * cB0;
            aB2 += wsB * yB.y + wB3 * vb1 + wB4 * cB1;
            aB3 += wsB * yB.z + wB3 * vb2 + wB4 * cB2;
        }

        if (pA + 1 == endA || k == 15) {
            bool interior = (begA >= pA0) && (endA <= pA0 + 16);
            if (interior) {
                agg_s[(size_t)rA * 64 + f] = aA0;
                agg_v[((size_t)rA * 3 + 0) * 64 + f] = aA1;
                agg_v[((size_t)rA * 3 + 1) * 64 + f] = aA2;
                agg_v[((size_t)rA * 3 + 2) * 64 + f] = aA3;
            } else {
                unsafeAtomicAdd(&agg_s[(size_t)rA * 64 + f], aA0);
                unsafeAtomicAdd(&agg_v[((size_t)rA * 3 + 0) * 64 + f], aA1);
                unsafeAtomicAdd(&agg_v[((size_t)rA * 3 + 1) * 64 + f], aA2);
                unsafeAtomicAdd(&agg_v[((size_t)rA * 3 + 2) * 64 + f], aA3);
            }
            aA0 = aA1 = aA2 = aA3 = 0.f;
            if (pA + 1 == endA && k < 15) {
                begA = endA; ++rA; endA = row_start[rA + 1];
                while (endA == begA) { ++rA; endA = row_start[rA + 1]; }
            }
        }
        if (pB + 1 == endB || k == 15) {
            bool interior = (begB >= pB0) && (endB <= pB0 + 16);
            if (interior) {
                agg_s[(size_t)rB * 64 + f] = aB0;
                agg_v[((size_t)rB * 3 + 0) * 64 + f] = aB1;
                agg_v[((size_t)rB * 3 + 1) * 64 + f] = aB2;
                agg_v[((size_t)rB * 3 + 2) * 64 + f] = aB3;
            } else {
                unsafeAtomicAdd(&agg_s[(size_t)rB * 64 + f], aB0);
                unsafeAtomicAdd(&agg_v[((size_t)rB * 3 + 0) * 64 + f], aB1);
                unsafeAtomicAdd(&agg_v[((size_t)rB * 3 + 1) * 64 + f], aB2);
                unsafeAtomicAdd(&agg_v[((size_t)rB * 3 + 2) * 64 + f], aB3);
            }
            aB0 = aB1 = aB2 = aB3 = 0.f;
            if (pB + 1 == endB && k < 15) {
                begB = endB; ++rB; endB = row_start[rB + 1];
                while (endB == begB) { ++rB; endB = row_start[rB + 1]; }
            }
        }

        // rotate stages (SSA renames under full unroll — no movs, no waits)
        sA0r = sA1r; sB0r = sB1r; sA1r = sA2r; sB1r = sB2r;
        sA0f = sA1f; sB0f = sB1f; sA1f = sA2f; sB1f = sB2f;
        vA0r0 = vA1r0; vA0r1 = vA1r1; vA0r2 = vA1r2;
        vB0r0 = vB1r0; vB0r1 = vB1r1; vB0r2 = vB1r2;
        vA1r0 = vA2r0; vA1r1 = vA2r1; vA1r2 = vA2r2;
        vB1r0 = vB2r0; vB1r1 = vB2r1; vB1r2 = vB2r2;
        svA2 = svA3; svB2 = svB3;
    }
}

// ---------------------------------------------------------------------------
// MFMA node kernel, bf16 s/v state: skip A-fragments are direct short8 loads
// (bit-exact vs fp32 path); s/v stores are RNE-bf16. Fused readout uses
// pre-rounded fp32 registers. wave = 16 sorted nodes.
// ---------------------------------------------------------------------------
__global__ __launch_bounds__(256) void node_mfma_kernel(
    const float* __restrict__ agg_s, const float* __restrict__ agg_v,
    unsigned short* s, unsigned short* v,
    const short* __restrict__ packW, int it,
    const float* __restrict__ pw_i,
    const int* __restrict__ spec_srt,
    const int* __restrict__ row_start, const int* __restrict__ sidx,
    const float* __restrict__ Wread0, const float* __restrict__ Wr1a,
    const float* __restrict__ Wr1b,
    float* __restrict__ out,
    int has_skip)
{
    const int l = threadIdx.x & 63;
    const int wid = threadIdx.x >> 6;
    const int cl = l & 15;
    const int q = l >> 4;
    const int i16 = (blockIdx.x * 4 + wid) * 16;
    __shared__ float xls_all[4][16 * 65];
    float* xls = xls_all[wid];

    const short* pWls = packW + (size_t)(0 + it) * 4096;
    const short* pWlv = packW + (size_t)(2 + it) * 4096;
    const short* pWps = packW + (size_t)(4 + it) * 4096;
    const short* pWpv = packW + (size_t)(6 + it) * 4096;
    const short* pSkS = packW + (size_t)8 * 4096;
    const short* pSkV = packW + (size_t)18 * 4096;
    const short8 z8 = {0, 0, 0, 0, 0, 0, 0, 0};

    const float* ars = agg_s + (size_t)(i16 + cl) * 64;
    short8 As[2] = { loadArow(ars, 0, q), loadArow(ars, 1, q) };
    short8 Av[3][2];
#pragma unroll
    for (int k = 0; k < 3; ++k) {
        const float* r = agg_v + ((size_t)(i16 + cl) * 3 + k) * 64;
        Av[k][0] = loadArow(r, 0, q);
        Av[k][1] = loadArow(r, 1, q);
    }

    f32x4 sD[4];
#pragma unroll
    for (int t = 0; t < 4; ++t) {
        f32x4 acc = {0.f, 0.f, 0.f, 0.f};
        acc = MFMA16(As[0], loadB(pWls, t, 0, l), acc);
        acc = MFMA16(As[1], loadB(pWls, t, 1, l), acc);
        sD[t] = acc;
    }

    f32x4 vD[3][4];
#pragma unroll
    for (int k = 0; k < 3; ++k)
#pragma unroll
        for (int t = 0; t < 4; ++t) vD[k][t] = (f32x4){0.f, 0.f, 0.f, 0.f};
#pragma unroll
    for (int t = 0; t < 4; ++t)
#pragma unroll
        for (int h = 0; h < 2; ++h) {
            short8 b = loadB(pWlv, t, h, l);
#pragma unroll
            for (int k = 0; k < 3; ++k) vD[k][t] = MFMA16(Av[k][h], b, vD[k][t]);
        }

    int z0 = spec_srt[i16], z1 = spec_srt[i16 + 15];
    float psD[4][4], pvsD[4][4];
    if (z0 == z1) {
        const float* pb = pw_i + z0 * 576 + cl;
        float pc[9][4];
#pragma unroll
        for (int c = 0; c < 9; ++c)
#pragma unroll
            for (int t = 0; t < 4; ++t) pc[c][t] = pb[c * 64 + t * 16];
#pragma unroll
        for (int t = 0; t < 4; ++t)
#pragma unroll
            for (int r = 0; r < 4; ++r) {
                float x = sD[t][r] * EPS_C;
                float w0 = vD[0][t][r] * EPS_C;
                float w1 = vD[1][t][r] * EPS_C;
                float w2 = vD[2][t][r] * EPS_C;
                vD[0][t][r] = w0; vD[1][t][r] = w1; vD[2][t][r] = w2;
                float vv = w0 * w0 + w1 * w1 + w2 * w2;
                float x2 = x * x;
                psD[t][r] = pc[0][t] * x + pc[1][t] * x2 + pc[2][t] * vv
                          + pc[3][t] * x2 * x + pc[4][t] * x * vv;
                pvsD[t][r] = pc[5][t] + pc[6][t] * x + pc[7][t] * x2 + pc[8][t] * vv;
            }
    } else {
#pragma unroll
        for (int r = 0; r < 4; ++r) {
            int z = spec_srt[i16 + q * 4 + r];
            const float* pb = pw_i + z * 576 + cl;
#pragma unroll
            for (int t = 0; t < 4; ++t) {
                float p0 = pb[t*16], p1 = pb[64+t*16], p2 = pb[128+t*16];
                float p3 = pb[192+t*16], p4 = pb[256+t*16], p5 = pb[320+t*16];
                float p6 = pb[384+t*16], p7 = pb[448+t*16], p8 = pb[512+t*16];
                float x = sD[t][r] * EPS_C;
                float w0 = vD[0][t][r] * EPS_C;
                float w1 = vD[1][t][r] * EPS_C;
                float w2 = vD[2][t][r] * EPS_C;
                vD[0][t][r] = w0; vD[1][t][r] = w1; vD[2][t][r] = w2;
                float vv = w0 * w0 + w1 * w1 + w2 * w2;
                float x2 = x * x;
                psD[t][r] = p0 * x + p1 * x2 + p2 * vv + p3 * x2 * x + p4 * x * vv;
                pvsD[t][r] = p5 + p6 * x + p7 * x2 + p8 * vv;
            }
        }
    }

#pragma unroll
    for (int t = 0; t < 4; ++t)
#pragma unroll
        for (int r = 0; r < 4; ++r)
            xls[(q * 4 + r) * 65 + t * 16 + cl] = psD[t][r];
    short8 psA[2];
#pragma unroll
    for (int h = 0; h < 2; ++h) {
        const float* rp = xls + cl * 65 + h * 32 + q * 8;
        float t0 = rp[0], t1 = rp[1], t2 = rp[2], t3 = rp[3];
        float t4 = rp[4], t5 = rp[5], t6 = rp[6], t7 = rp[7];
        psA[h] = cvt8(make_float4(t0, t1, t2, t3), make_float4(t4, t5, t6, t7));
    }

    f32x4 snD[4];
#pragma unroll
    for (int t = 0; t < 4; ++t) {
        f32x4 acc = {0.f, 0.f, 0.f, 0.f};
        acc = MFMA16(psA[0], loadB(pWps, t, 0, l), acc);
        acc = MFMA16(psA[1], loadB(pWps, t, 1, l), acc);
        snD[t] = acc;
    }
    if (has_skip) {
        const unsigned short* srow = s + (size_t)(i16 + cl) * 64;
        short8 Ai0 = *(const short8*)(srow + q * 8);
        short8 Ai1 = *(const short8*)(srow + 32 + q * 8);
        int myz = spec_srt[i16 + cl];
        for (int z = z0; z <= z1; ++z) {
            bool keep = (myz == z);
            short8 m0 = keep ? Ai0 : z8;
            short8 m1 = keep ? Ai1 : z8;
            const short* pz = pSkS + (size_t)z * 4096;
#pragma unroll
            for (int t = 0; t < 4; ++t) {
                snD[t] = MFMA16(m0, loadB(pz, t, 0, l), snD[t]);
                snD[t] = MFMA16(m1, loadB(pz, t, 1, l), snD[t]);
            }
        }
    }
#pragma unroll
    for (int t = 0; t < 4; ++t)
#pragma unroll
        for (int r = 0; r < 4; ++r)
            s[(size_t)(i16 + q * 4 + r) * 64 + t * 16 + cl] = f2bf(snD[t][r]);

    // ---- fused readout (pre-rounded fp32 registers)
    if (it == 0) {
        float w0c[4];
#pragma unroll
        for (int t = 0; t < 4; ++t) w0c[t] = Wread0[t * 16 + cl];
#pragma unroll
        for (int r = 0; r < 4; ++r) {
            float a = snD[0][r] * w0c[0] + snD[1][r] * w0c[1]
                    + snD[2][r] * w0c[2] + snD[3][r] * w0c[3];
            a += __shfl_down(a, 8);
            a += __shfl_down(a, 4);
            a += __shfl_down(a, 2);
            a += __shfl_down(a, 1);
            if (cl == 0) out[(size_t)sidx[i16 + q * 4 + r] * 2 + 0] = a;
        }
    } else {
#pragma unroll
        for (int t = 0; t < 4; ++t)
#pragma unroll
            for (int r = 0; r < 4; ++r)
                xls[(q * 4 + r) * 65 + t * 16 + cl] = snD[t][r];
        float acc4[4] = {0.f, 0.f, 0.f, 0.f};
        for (int g = 0; g < 64; ++g) {
            float wa = Wr1a[g * 16 + cl];
#pragma unroll
            for (int j = 0; j < 4; ++j)
                acc4[j] = fmaf(xls[(q + 4 * j) * 65 + g], wa, acc4[j]);
        }
        float wb = Wr1b[cl];
#pragma unroll
        for (int j = 0; j < 4; ++j) {
            float av = acc4[j];
            float rr = (av / (1.f + expf(-av))) * wb;
            rr += __shfl_down(rr, 8);
            rr += __shfl_down(rr, 4);
            rr += __shfl_down(rr, 2);
            rr += __shfl_down(rr, 1);
            if (cl == 0) out[(size_t)sidx[i16 + q + 4 * j] * 2 + 1] = rr;
        }
    }

    short8 pvA[3][2];
#pragma unroll
    for (int k = 0; k < 3; ++k) {
#pragma unroll
        for (int t = 0; t < 4; ++t)
#pragma unroll
            for (int r = 0; r < 4; ++r)
                xls[(q * 4 + r) * 65 + t * 16 + cl] = pvsD[t][r] * vD[k][t][r];
#pragma unroll
        for (int h = 0; h < 2; ++h) {
            const float* rp = xls + cl * 65 + h * 32 + q * 8;
            float t0 = rp[0], t1 = rp[1], t2 = rp[2], t3 = rp[3];
            float t4 = rp[4], t5 = rp[5], t6 = rp[6], t7 = rp[7];
            pvA[k][h] = cvt8(make_float4(t0, t1, t2, t3), make_float4(t4, t5, t6, t7));
        }
    }

    f32x4 vnD[3][4];
#pragma unroll
    for (int k = 0; k < 3; ++k)
#pragma unroll
        for (int t = 0; t < 4; ++t) vnD[k][t] = (f32x4){0.f, 0.f, 0.f, 0.f};
#pragma unroll
    for (int t = 0; t < 4; ++t)
#pragma unroll
        for (int h = 0; h < 2; ++h) {
            short8 b = loadB(pWpv, t, h, l);
#pragma unroll
            for (int k = 0; k < 3; ++k) vnD[k][t] = MFMA16(pvA[k][h], b, vnD[k][t]);
        }
    if (has_skip) {
        short8 Aiv[3][2];
#pragma unroll
        for (int k = 0; k < 3; ++k) {
            const unsigned short* r = v + ((size_t)(i16 + cl) * 3 + k) * 64;
            Aiv[k][0] = *(const short8*)(r + q * 8);
            Aiv[k][1] = *(const short8*)(r + 32 + q * 8);
        }
        int myz = spec_srt[i16 + cl];
        for (int z = z0; z <= z1; ++z) {
            bool keep = (myz == z);
            const short* pz = pSkV + (size_t)z * 4096;
#pragma unroll
            for (int t = 0; t < 4; ++t)
#pragma unroll
                for (int h = 0; h < 2; ++h) {
                    short8 b = loadB(pz, t, h, l);
#pragma unroll
                    for (int k = 0; k < 3; ++k) {
                        short8 a = keep ? Aiv[k][h] : z8;
                        vnD[k][t] = MFMA16(a, b, vnD[k][t]);
                    }
                }
        }
    }
#pragma unroll
    for (int k = 0; k < 3; ++k)
#pragma unroll
        for (int t = 0; t < 4; ++t)
#pragma unroll
            for (int r = 0; r < 4; ++r)
                v[((size_t)(i16 + q * 4 + r) * 3 + k) * 64 + t * 16 + cl] = f2bf(vnD[k][t][r]);

    // ---- it==0: zero this wave's own agg boundary rows for interaction 1.
    if (it == 0) {
        for (int rr = 0; rr < 16; ++rr) {
            int i = i16 + rr;
            int beg = row_start[i], end = row_start[i + 1];
            bool need = (end == beg) || (end > (((beg >> 4) + 1) << 4));
            if (need) {
                float* as = (float*)agg_s;
                float* av = (float*)agg_v;
                as[(size_t)i * 64 + l] = 0.f;
                av[((size_t)i * 3 + 0) * 64 + l] = 0.f;
                av[((size_t)i * 3 + 1) * 64 + l] = 0.f;
                av[((size_t)i * 3 + 2) * 64 + l] = 0.f;
            }
        }
    }
}

// ---------------------------------------------------------------------------
extern "C" void kernel_launch(void* const* d_in, const int* in_sizes, int n_in,
                              void* d_out, int out_size, void* d_ws, size_t ws_size,
                              hipStream_t stream)
{
    const float* vectors = (const float*)d_in[0];
    const float* embed_s = (const float*)d_in[1];
    const float* Wr      = (const float*)d_in[2];   // [2,8,320]
    const float* Wls     = (const float*)d_in[3];   // [2,64,64]
    const float* Wlv     = (const float*)d_in[4];
    const float* skip_s  = (const float*)d_in[5];   // [10,64,64]
    const float* skip_v  = (const float*)d_in[6];
    const float* pw      = (const float*)d_in[7];   // [2,10,9,64]
    const float* Wps     = (const float*)d_in[8];
    const float* Wpv     = (const float*)d_in[9];
    const float* Wread0  = (const float*)d_in[10];  // [64,1]
    const float* Wr1a    = (const float*)d_in[11];  // [64,16]
    const float* Wr1b    = (const float*)d_in[12];  // [16,1]
    const int* senders   = (const int*)d_in[13];
    const int* receivers = (const int*)d_in[14];
    const int* species   = (const int*)d_in[15];
    float* out = (float*)d_out;

    float* ws = (float*)d_ws;
    float* edata = ws; ws += (size_t)N_EDGES * 16;  // 16 MB (slot-ordered)
    float* agg_s = ws; ws += (size_t)N_NODES * 64;  // 8 MB
    float* agg_v = ws; ws += (size_t)N_NODES * 192; // 24 MB
    unsigned short* s = (unsigned short*)ws; ws += (size_t)N_NODES * 32;  // 4 MB bf16
    unsigned short* v = (unsigned short*)ws; ws += (size_t)N_NODES * 96;  // 12 MB bf16
    int* counts    = (int*)ws; ws += N_NODES;
    int* row_start = (int*)ws; ws += N_NODES + 4;
    int* cursor    = (int*)ws; ws += N_NODES;
    int* edge_ids  = (int*)ws; ws += N_EDGES;
    int* srk       = (int*)ws; ws += N_EDGES;
    int* grp_row   = (int*)ws; ws += N_EDGES / 16;
    int* sidx      = (int*)ws; ws += N_NODES;
    int* rank      = (int*)ws; ws += N_NODES;
    int* spec_srt  = (int*)ws; ws += N_NODES;
    int* lrank_arr = (int*)ws; ws += N_NODES;
    int* counts_blk = (int*)ws; ws += 128 * NSPEC;
    int* off_blk    = (int*)ws; ws += 128 * NSPEC;
    short* packW   = (short*)ws;                    // 224 KB

    // species counting sort (sort1 also zeroes CSR counts)
    sort1_kernel<<<N_NODES / 256, 256, 0, stream>>>(
        species, counts_blk, lrank_arr, counts);
    sort2_kernel<<<1, 640, 0, stream>>>(counts_blk, off_blk);
    sort3_kernel<<<N_NODES / 256, 256, 0, stream>>>(
        species, lrank_arr, off_blk, sidx, rank, spec_srt);

    // receiver CSR in sorted space
    hist_kernel<<<N_EDGES / 256, 256, 0, stream>>>(receivers, rank, counts);
    scan_kernel<<<1, 1024, 0, stream>>>(counts, row_start, cursor);
    scatter_kernel<<<N_EDGES / 256, 256, 0, stream>>>(receivers, rank, cursor, edge_ids);

    // edge features + packed sender rank/species + grp_row (one pass)
    edge_pre_kernel<<<N_EDGES / 256, 256, 0, stream>>>(
        vectors, edge_ids, senders, rank, species, row_start, edata, srk, grp_row);

    // merged prep: weight pack + zero boundary agg rows (i0). No init_s.
    prep_kernel<<<2048, 256, 0, stream>>>(
        Wls, Wlv, Wps, Wpv, skip_s, skip_v, packW, row_start, agg_s, agg_v);

    // interaction 0 (gather reads embed table; node fuses read0 + re-zeroing)
    gather_kernel<1><<<N_EDGES / 64, 128, 0, stream>>>(
        edata, srk, row_start, grp_row, embed_s, s, v, Wr, agg_s, agg_v);
    node_mfma_kernel<<<N_NODES / 64, 256, 0, stream>>>(
        agg_s, agg_v, s, v, packW, 0, pw, spec_srt,
        row_start, sidx, Wread0, Wr1a, Wr1b, out, 0);

    // interaction 1 (bf16 s/v state halves random gather traffic)
    gather_kernel<0><<<N_EDGES / 64, 128, 0, stream>>>(
        edata, srk, row_start, grp_row, embed_s, s, v, Wr + 2560, agg_s, agg_v);
    node_mfma_kernel<<<N_NODES / 64, 256, 0, stream>>>(
        agg_s, agg_v, s, v, packW, 1, pw + 5760, spec_srt,
        row_start, sidx, Wread0, Wr1a, Wr1b, out, 1);
}

// Round 5
// 307.270 us; speedup vs baseline: 1.0872x; 1.0872x over previous
//
#include <hip/hip_runtime.h>
#include <hip/hip_bf16.h>
#include <math.h>

#define N_NODES 32768
#define N_EDGES 262144
#define EPS_C 0.24253562503633297f   // 1/sqrt(17)
#define NSPEC 10

typedef __attribute__((ext_vector_type(8))) short short8;   // 8 bf16
typedef __attribute__((ext_vector_type(4))) float f32x4;    // 4 fp32 acc

#define MFMA16(a, b, c) __builtin_amdgcn_mfma_f32_16x16x32_bf16(a, b, c, 0, 0, 0)

__device__ __forceinline__ short2 cvt2(float a, float b) {
    union { __hip_bfloat162 h; short2 s; } u;
    u.h = __float22bfloat162_rn(make_float2(a, b));
    return u.s;
}
__device__ __forceinline__ unsigned cvt2u(float a, float b) {
    union { __hip_bfloat162 h; unsigned u; } u;
    u.h = __float22bfloat162_rn(make_float2(a, b));
    return u.u;   // lo16 = bf(a), hi16 = bf(b)
}
__device__ __forceinline__ unsigned short f2bf(float a) {
    return (unsigned short)cvt2(a, 0.f).x;
}
__device__ __forceinline__ float bf2f(unsigned short u) {
    return __uint_as_float(((unsigned)u) << 16);
}
__device__ __forceinline__ short8 cvt8(float4 a, float4 b) {
    short2 p0 = cvt2(a.x, a.y), p1 = cvt2(a.z, a.w);
    short2 p2 = cvt2(b.x, b.y), p3 = cvt2(b.z, b.w);
    short8 r;
    r[0] = p0.x; r[1] = p0.y; r[2] = p1.x; r[3] = p1.y;
    r[4] = p2.x; r[5] = p2.y; r[6] = p3.x; r[7] = p3.y;
    return r;
}
__device__ __forceinline__ short8 loadArow(const float* rowp, int h, int q) {
    const float* p = rowp + h * 32 + q * 8;
    return cvt8(*(const float4*)p, *(const float4*)(p + 4));
}
__device__ __forceinline__ short8 loadB(const short* P, int t, int h, int l) {
    return *(const short8*)(P + (((t * 2 + h) * 64 + l) << 3));
}

// packed state svp[node][64 ch][4] = ushort4 {s, v0, v1, v2} (bf16 bits).
// unpack helpers for the node kernel's skip-fragment reads: 8 channels
// starting at ch0 for one node row (prow = svp + node*256).
__device__ __forceinline__ short8 unpack_s(const unsigned short* prow, int ch0) {
    const uint4* p = (const uint4*)(prow + ch0 * 4);
    uint4 u0 = p[0], u1 = p[1], u2 = p[2], u3 = p[3];
    short8 r;
    r[0] = (short)(u0.x & 0xffff); r[1] = (short)(u0.z & 0xffff);
    r[2] = (short)(u1.x & 0xffff); r[3] = (short)(u1.z & 0xffff);
    r[4] = (short)(u2.x & 0xffff); r[5] = (short)(u2.z & 0xffff);
    r[6] = (short)(u3.x & 0xffff); r[7] = (short)(u3.z & 0xffff);
    return r;
}
__device__ __forceinline__ void unpack_v(const unsigned short* prow, int ch0,
                                         short8 (&Aiv)[3][2], int h) {
    const uint4* p = (const uint4*)(prow + ch0 * 4);
    uint4 u0 = p[0], u1 = p[1], u2 = p[2], u3 = p[3];
    Aiv[0][h][0] = (short)(u0.x >> 16); Aiv[0][h][1] = (short)(u0.z >> 16);
    Aiv[0][h][2] = (short)(u1.x >> 16); Aiv[0][h][3] = (short)(u1.z >> 16);
    Aiv[0][h][4] = (short)(u2.x >> 16); Aiv[0][h][5] = (short)(u2.z >> 16);
    Aiv[0][h][6] = (short)(u3.x >> 16); Aiv[0][h][7] = (short)(u3.z >> 16);
    Aiv[1][h][0] = (short)(u0.y & 0xffff); Aiv[1][h][1] = (short)(u0.w & 0xffff);
    Aiv[1][h][2] = (short)(u1.y & 0xffff); Aiv[1][h][3] = (short)(u1.w & 0xffff);
    Aiv[1][h][4] = (short)(u2.y & 0xffff); Aiv[1][h][5] = (short)(u2.w & 0xffff);
    Aiv[1][h][6] = (short)(u3.y & 0xffff); Aiv[1][h][7] = (short)(u3.w & 0xffff);
    Aiv[2][h][0] = (short)(u0.y >> 16); Aiv[2][h][1] = (short)(u0.w >> 16);
    Aiv[2][h][2] = (short)(u1.y >> 16); Aiv[2][h][3] = (short)(u1.w >> 16);
    Aiv[2][h][4] = (short)(u2.y >> 16); Aiv[2][h][5] = (short)(u2.w >> 16);
    Aiv[2][h][6] = (short)(u3.y >> 16); Aiv[2][h][7] = (short)(u3.w >> 16);
}

// ---------------------------------------------------------------------------
// Species counting sort — contention-free, deterministic. sort1 also zeroes
// the receiver-CSR counts array.
// ---------------------------------------------------------------------------
__global__ __launch_bounds__(256) void sort1_kernel(
    const int* __restrict__ species, int* __restrict__ counts_blk,
    int* __restrict__ lrank_arr, int* __restrict__ counts)
{
    __shared__ int wcnt[4][16];
    int n = blockIdx.x * 256 + threadIdx.x;
    counts[n] = 0;
    int sp = species[n];
    int lane = threadIdx.x & 63, wv = threadIdx.x >> 6;
    unsigned long long ltmask = (1ull << lane) - 1;
    int lrank_w = 0;
#pragma unroll
    for (int z = 0; z < NSPEC; ++z) {
        unsigned long long m = __ballot(sp == z);
        if (sp == z) lrank_w = __popcll(m & ltmask);
        if (lane == 0) wcnt[wv][z] = __popcll(m);
    }
    __syncthreads();
    int off = 0;
    for (int w = 0; w < wv; ++w) off += wcnt[w][sp];
    lrank_arr[n] = lrank_w + off;
    if (threadIdx.x < NSPEC)
        counts_blk[blockIdx.x * NSPEC + threadIdx.x] =
            wcnt[0][threadIdx.x] + wcnt[1][threadIdx.x] +
            wcnt[2][threadIdx.x] + wcnt[3][threadIdx.x];
}

// parallel block-offset scan: wave z shuffle-scans its 128 block counts
__global__ __launch_bounds__(640) void sort2_kernel(
    const int* __restrict__ counts_blk, int* __restrict__ off_blk)
{
    __shared__ int totals[16];
    int wv = threadIdx.x >> 6;        // 0..9 == species z
    int lane = threadIdx.x & 63;
    int c0 = counts_blk[lane * NSPEC + wv];
    int c1 = counts_blk[(64 + lane) * NSPEC + wv];
    int s0 = c0;
#pragma unroll
    for (int off = 1; off < 64; off <<= 1) {
        int y = __shfl_up(s0, off);
        if (lane >= off) s0 += y;
    }
    int tot0 = __shfl(s0, 63);
    int s1 = c1;
#pragma unroll
    for (int off = 1; off < 64; off <<= 1) {
        int y = __shfl_up(s1, off);
        if (lane >= off) s1 += y;
    }
    s1 += tot0;
    if (lane == 63) totals[wv] = s1;
    __syncthreads();
    int base = 0;
    for (int q = 0; q < wv; ++q) base += totals[q];
    off_blk[lane * NSPEC + wv] = base + s0 - c0;
    off_blk[(64 + lane) * NSPEC + wv] = base + s1 - c1;
}

__global__ __launch_bounds__(256) void sort3_kernel(
    const int* __restrict__ species, const int* __restrict__ lrank_arr,
    const int* __restrict__ off_blk,
    int* __restrict__ sidx, int* __restrict__ rank, int* __restrict__ spec_srt)
{
    int n = blockIdx.x * 256 + threadIdx.x;
    int sp = species[n];
    int slot = off_blk[blockIdx.x * NSPEC + sp] + lrank_arr[n];
    sidx[slot] = n;
    rank[n] = slot;
    spec_srt[slot] = sp;
}

// ---------------------------------------------------------------------------
// Receiver CSR in SORTED space
// ---------------------------------------------------------------------------
__global__ __launch_bounds__(256) void hist_kernel(
    const int* __restrict__ receivers, const int* __restrict__ rank,
    int* __restrict__ counts)
{
    int e = blockIdx.x * 256 + threadIdx.x;
    atomicAdd(&counts[rank[receivers[e]]], 1);
}

__global__ __launch_bounds__(1024) void scan_kernel(
    const int* __restrict__ counts, int* __restrict__ row_start, int* __restrict__ cursor)
{
    __shared__ int wave_tot[16];
    int tid = threadIdx.x;
    int c[32];
    int sum = 0;
#pragma unroll
    for (int i = 0; i < 32; ++i) { c[i] = counts[tid * 32 + i]; sum += c[i]; }
    int lane = tid & 63, wv = tid >> 6;
    int x = sum;
#pragma unroll
    for (int off = 1; off < 64; off <<= 1) {
        int y = __shfl_up(x, off);
        if (lane >= off) x += y;
    }
    if (lane == 63) wave_tot[wv] = x;
    __syncthreads();
    if (wv == 0 && lane < 16) {
        int t = wave_tot[lane];
#pragma unroll
        for (int off = 1; off < 16; off <<= 1) {
            int y = __shfl_up(t, off);
            if (lane >= off) t += y;
        }
        wave_tot[lane] = t;
    }
    __syncthreads();
    int excl = x - sum + (wv ? wave_tot[wv - 1] : 0);
    int run = excl;
#pragma unroll
    for (int i = 0; i < 32; ++i) {
        row_start[tid * 32 + i] = run;
        cursor[tid * 32 + i] = run;
        run += c[i];
    }
    if (tid == 1023) row_start[32768] = run;
}

__global__ __launch_bounds__(256) void scatter_kernel(
    const int* __restrict__ receivers, const int* __restrict__ rank,
    int* __restrict__ cursor, int* __restrict__ edge_ids)
{
    int e = blockIdx.x * 256 + threadIdx.x;
    int slot = atomicAdd(&cursor[rank[receivers[e]]], 1);
    edge_ids[slot] = e;
}

// ---------------------------------------------------------------------------
// Edge precompute in slot order + fused sender-rank/species stream + grp_row.
// srk[p] = rank | (species << 16)
// ---------------------------------------------------------------------------
__global__ __launch_bounds__(256) void edge_pre_kernel(
    const float* __restrict__ vectors, const int* __restrict__ edge_ids,
    const int* __restrict__ senders, const int* __restrict__ rank,
    const int* __restrict__ species, const int* __restrict__ row_start,
    float* __restrict__ edata, int* __restrict__ srk, int* __restrict__ grp_row)
{
    int p = blockIdx.x * 256 + threadIdx.x;
    int e = edge_ids[p];
    int snd = senders[e];
    srk[p] = rank[snd] | (species[snd] << 16);
    float x = vectors[e * 3 + 0], y = vectors[e * 3 + 1], z = vectors[e * 3 + 2];
    float r2 = x * x + y * y + z * z + 1e-12f;
    float r = sqrtf(r2);
    float inv = 1.0f / r;
    float* d = edata + (size_t)p * 16;
    *(float4*)d = make_float4(x * inv, y * inv, z * inv, 0.0f);
    float rc = fmaxf(r, 1e-6f);
    float r6 = r2 * r2 * r2;
    float r7 = r6 * r;
    float r8 = r6 * r2;
    float env = (r < 1.0f) ? (1.0f - 28.0f * r6 + 48.0f * r7 - 21.0f * r8) : 0.0f;
    float sc = 1.41421356237309515f * env / rc;
#pragma unroll
    for (int j = 0; j < 8; ++j)
        d[4 + j] = sc * sinf((float)(j + 1) * 3.14159265358979323846f * rc);
    d[12] = 0.f; d[13] = 0.f; d[14] = 0.f; d[15] = 0.f;

    if (p < N_EDGES / 16) {
        int target = p * 16;
        int lo = 0, hi = N_NODES - 1;
        while (lo < hi) {
            int mid = (lo + hi + 1) >> 1;
            if (row_start[mid] <= target) lo = mid; else hi = mid - 1;
        }
        grp_row[p] = lo;
    }
}

// ---------------------------------------------------------------------------
// Merged prep: weight pack (blocks<448) + zero_bnd for interaction 0.
// ---------------------------------------------------------------------------
__global__ __launch_bounds__(256) void prep_kernel(
    const float* __restrict__ Wls, const float* __restrict__ Wlv,
    const float* __restrict__ Wps, const float* __restrict__ Wpv,
    const float* __restrict__ skip_s, const float* __restrict__ skip_v,
    short* __restrict__ packW,
    const int* __restrict__ row_start,
    float* __restrict__ agg_s, float* __restrict__ agg_v)
{
    int idx = blockIdx.x * 256 + threadIdx.x;
    if (blockIdx.x < 448 && idx < 28 * 4096) {
        int m = idx >> 12, e = idx & 4095;
        int t = e >> 10, h = (e >> 9) & 1, l = (e >> 3) & 63, j = e & 7;
        int fi = h * 32 + ((l >> 4) << 3) + j;
        int fo = t * 16 + (l & 15);
        const float* src;
        if      (m < 2)  src = Wls    + m * 4096;
        else if (m < 4)  src = Wlv    + (m - 2) * 4096;
        else if (m < 6)  src = Wps    + (m - 4) * 4096;
        else if (m < 8)  src = Wpv    + (m - 6) * 4096;
        else if (m < 18) src = skip_s + (m - 8) * 4096;
        else             src = skip_v + (m - 18) * 4096;
        packW[idx] = cvt2(src[fi * 64 + fo], 0.f).x;
    }
    const int wid = threadIdx.x >> 6;
    const int f = threadIdx.x & 63;
    const int base = (blockIdx.x * 4 + wid) * 4;
#pragma unroll
    for (int t = 0; t < 4; ++t) {
        int i = base + t;
        int beg = row_start[i], end = row_start[i + 1];
        bool need = (end == beg) || (end > (((beg >> 4) + 1) << 4));
        if (need) {
            agg_s[(size_t)i * 64 + f] = 0.f;
            agg_v[((size_t)i * 3 + 0) * 64 + f] = 0.f;
            agg_v[((size_t)i * 3 + 1) * 64 + f] = 0.f;
            agg_v[((size_t)i * 3 + 2) * 64 + f] = 0.f;
        }
    }
}

// ---------------------------------------------------------------------------
// Dual-chain edge-balanced gather, 1 wave/block, depth-2 software pipeline
// (raw bits staged, consume-time conversion, fully unrolled 16-iter loop).
// DO NOT use multi-wave workgroups here: tried 4-wave (r1) and 2-wave (r3);
// both regress badly (VGPR 52->64, scratch spills visible as +42MB
// WRITE_SIZE, occupancy unchanged ~33%). 1-wave/64-thread is the config.
// !VZERO reads the PACKED state svp[node][ch] = ushort4{s,v0,v1,v2}: ONE
// 8-B uint2 per edge per lane instead of 4 scattered line accesses.
// VZERO: s from 2.5KB embed table (L1-resident).
// ---------------------------------------------------------------------------
template<int VZERO>
__global__ __launch_bounds__(64, 4) void gather_kernel(
    const float* __restrict__ edata, const int* __restrict__ srk,
    const int* __restrict__ row_start, const int* __restrict__ grp_row,
    const float* __restrict__ embed_s,
    const unsigned short* __restrict__ svp,
    const float* __restrict__ Wr_i,
    float* __restrict__ agg_s, float* __restrict__ agg_v)
{
    const int f = threadIdx.x & 63;
    const int w = blockIdx.x;
    const int pA0 = w * 32;
    const int pB0 = pA0 + 16;

    float wr[5][8];
#pragma unroll
    for (int j = 0; j < 8; ++j)
#pragma unroll
        for (int p = 0; p < 5; ++p)
            wr[p][j] = (VZERO && (p == 1 || p == 3 || p == 4))
                       ? 0.f : Wr_i[j * 320 + p * 64 + f];

    int rA = grp_row[2 * w], rB = grp_row[2 * w + 1];
    int begA = row_start[rA], endA = row_start[rA + 1];
    int begB = row_start[rB], endB = row_start[rB + 1];
    float aA0 = 0.f, aA1 = 0.f, aA2 = 0.f, aA3 = 0.f;
    float aB0 = 0.f, aB1 = 0.f, aB2 = 0.f, aB3 = 0.f;

    // 3-stage pipeline. Stage0 = edge k (consumed this iter), stage1 = k+1
    // (in flight), stage2 = k+2 (issued this iter).
    int svA2 = srk[pA0 + 2], svB2 = srk[pB0 + 2];
    uint2 pkA0 = {0, 0}, pkB0 = {0, 0}, pkA1 = {0, 0}, pkB1 = {0, 0};
    float sA0f = 0.f, sB0f = 0.f, sA1f = 0.f, sB1f = 0.f;
    {
        int svA0 = srk[pA0], svB0 = srk[pB0];
        int svA1 = srk[pA0 + 1], svB1 = srk[pB0 + 1];
        if (VZERO) {
            sA0f = embed_s[(svA0 >> 16) * 64 + f];
            sB0f = embed_s[(svB0 >> 16) * 64 + f];
            sA1f = embed_s[(svA1 >> 16) * 64 + f];
            sB1f = embed_s[(svB1 >> 16) * 64 + f];
        } else {
            pkA0 = *(const uint2*)(svp + (((size_t)(svA0 & 0xFFFF)) * 64 + f) * 4);
            pkB0 = *(const uint2*)(svp + (((size_t)(svB0 & 0xFFFF)) * 64 + f) * 4);
            pkA1 = *(const uint2*)(svp + (((size_t)(svA1 & 0xFFFF)) * 64 + f) * 4);
            pkB1 = *(const uint2*)(svp + (((size_t)(svB1 & 0xFFFF)) * 64 + f) * 4);
        }
    }

#pragma unroll
    for (int k = 0; k < 16; ++k) {
        const int pA = pA0 + k, pB = pB0 + k;
        // srk prefetch for edge k+3 (A side always in-bounds; B clamps)
        int svA3 = srk[pA + 3];
        int iB3 = pB + 3;
        int svB3 = srk[iB3 < N_EDGES ? iB3 : N_EDGES - 1];

        // issue stage-2 state loads (edge k+2) — raw bits, no conversion
        uint2 pkA2 = {0, 0}, pkB2 = {0, 0};
        float sA2f = 0.f, sB2f = 0.f;
        if (VZERO) {
            sA2f = embed_s[(svA2 >> 16) * 64 + f];
            sB2f = embed_s[(svB2 >> 16) * 64 + f];
        } else {
            pkA2 = *(const uint2*)(svp + (((size_t)(svA2 & 0xFFFF)) * 64 + f) * 4);
            pkB2 = *(const uint2*)(svp + (((size_t)(svB2 & 0xFFFF)) * 64 + f) * 4);
        }

        const float* dA = edata + (size_t)pA * 16;
        const float* dB = edata + (size_t)pB * 16;
        float4 yA = *(const float4*)dA;
        float4 qA0 = *(const float4*)(dA + 4);
        float4 qA1 = *(const float4*)(dA + 8);
        float4 yB = *(const float4*)dB;
        float4 qB0 = *(const float4*)(dB + 4);
        float4 qB1 = *(const float4*)(dB + 8);

        float rbA[8] = {qA0.x, qA0.y, qA0.z, qA0.w, qA1.x, qA1.y, qA1.z, qA1.w};
        float rbB[8] = {qB0.x, qB0.y, qB0.z, qB0.w, qB1.x, qB1.y, qB1.z, qB1.w};
        float wA0 = 0.f, wA1 = 0.f, wA2 = 0.f, wA3 = 0.f, wA4 = 0.f;
        float wB0 = 0.f, wB1 = 0.f, wB2 = 0.f, wB3 = 0.f, wB4 = 0.f;
#pragma unroll
        for (int j = 0; j < 8; ++j) {
            wA0 = fmaf(rbA[j], wr[0][j], wA0);  wB0 = fmaf(rbB[j], wr[0][j], wB0);
            if (!VZERO) { wA1 = fmaf(rbA[j], wr[1][j], wA1);  wB1 = fmaf(rbB[j], wr[1][j], wB1); }
            wA2 = fmaf(rbA[j], wr[2][j], wA2);  wB2 = fmaf(rbB[j], wr[2][j], wB2);
            if (!VZERO) { wA3 = fmaf(rbA[j], wr[3][j], wA3);  wB3 = fmaf(rbB[j], wr[3][j], wB3); }
            if (!VZERO) { wA4 = fmaf(rbA[j], wr[4][j], wA4);  wB4 = fmaf(rbB[j], wr[4][j], wB4); }
        }

        // consume stage0 — conversion (exact shift/and) happens HERE, so the
        // s_waitcnt for these loads lands 2 iterations after issue.
        if (VZERO) {
            float ssA = sA0f, ssB = sB0f;
            aA0 += wA0 * ssA;
            float wsA = wA2 * ssA;
            aA1 += wsA * yA.x; aA2 += wsA * yA.y; aA3 += wsA * yA.z;
            aB0 += wB0 * ssB;
            float wsB = wB2 * ssB;
            aB1 += wsB * yB.x; aB2 += wsB * yB.y; aB3 += wsB * yB.z;
        } else {
            float ssA = __uint_as_float(pkA0.x << 16);
            float va0 = __uint_as_float(pkA0.x & 0xffff0000u);
            float va1 = __uint_as_float(pkA0.y << 16);
            float va2 = __uint_as_float(pkA0.y & 0xffff0000u);
            float ssB = __uint_as_float(pkB0.x << 16);
            float vb0 = __uint_as_float(pkB0.x & 0xffff0000u);
            float vb1 = __uint_as_float(pkB0.y << 16);
            float vb2 = __uint_as_float(pkB0.y & 0xffff0000u);
            float dotA = va0 * yA.x + va1 * yA.y + va2 * yA.z;
            aA0 += wA0 * ssA + wA1 * dotA;
            float cA0 = va1 * yA.z - va2 * yA.y;
            float cA1 = va2 * yA.x - va0 * yA.z;
            float cA2 = va0 * yA.y - va1 * yA.x;
            float wsA = wA2 * ssA;
            aA1 += wsA * yA.x + wA3 * va0 + wA4 * cA0;
            aA2 += wsA * yA.y + wA3 * va1 + wA4 * cA1;
            aA3 += wsA * yA.z + wA3 * va2 + wA4 * cA2;
            float dotB = vb0 * yB.x + vb1 * yB.y + vb2 * yB.z;
            aB0 += wB0 * ssB + wB1 * dotB;
            float cB0 = vb1 * yB.z - vb2 * yB.y;
            float cB1 = vb2 * yB.x - vb0 * yB.z;
            float cB2 = vb0 * yB.y - vb1 * yB.x;
            float wsB = wB2 * ssB;
            aB1 += wsB * yB.x + wB3 * vb0 + wB4 * cB0;
            aB2 += wsB * yB.y + wB3 * vb1 + wB4 * cB1;
            aB3 += wsB * yB.z + wB3 * vb2 + wB4 * cB2;
        }

        if (pA + 1 == endA || k == 15) {
            bool interior = (begA >= pA0) && (endA <= pA0 + 16);
            if (interior) {
                agg_s[(size_t)rA * 64 + f] = aA0;
                agg_v[((size_t)rA * 3 + 0) * 64 + f] = aA1;
                agg_v[((size_t)rA * 3 + 1) * 64 + f] = aA2;
                agg_v[((size_t)rA * 3 + 2) * 64 + f] = aA3;
            } else {
                unsafeAtomicAdd(&agg_s[(size_t)rA * 64 + f], aA0);
                unsafeAtomicAdd(&agg_v[((size_t)rA * 3 + 0) * 64 + f], aA1);
                unsafeAtomicAdd(&agg_v[((size_t)rA * 3 + 1) * 64 + f], aA2);
                unsafeAtomicAdd(&agg_v[((size_t)rA * 3 + 2) * 64 + f], aA3);
            }
            aA0 = aA1 = aA2 = aA3 = 0.f;
            if (pA + 1 == endA && k < 15) {
                begA = endA; ++rA; endA = row_start[rA + 1];
                while (endA == begA) { ++rA; endA = row_start[rA + 1]; }
            }
        }
        if (pB + 1 == endB || k == 15) {
            bool interior = (begB >= pB0) && (endB <= pB0 + 16);
            if (interior) {
                agg_s[(size_t)rB * 64 + f] = aB0;
                agg_v[((size_t)rB * 3 + 0) * 64 + f] = aB1;
                agg_v[((size_t)rB * 3 + 1) * 64 + f] = aB2;
                agg_v[((size_t)rB * 3 + 2) * 64 + f] = aB3;
            } else {
                unsafeAtomicAdd(&agg_s[(size_t)rB * 64 + f], aB0);
                unsafeAtomicAdd(&agg_v[((size_t)rB * 3 + 0) * 64 + f], aB1);
                unsafeAtomicAdd(&agg_v[((size_t)rB * 3 + 1) * 64 + f], aB2);
                unsafeAtomicAdd(&agg_v[((size_t)rB * 3 + 2) * 64 + f], aB3);
            }
            aB0 = aB1 = aB2 = aB3 = 0.f;
            if (pB + 1 == endB && k < 15) {
                begB = endB; ++rB; endB = row_start[rB + 1];
                while (endB == begB) { ++rB; endB = row_start[rB + 1]; }
            }
        }

        // rotate stages (SSA renames under full unroll — no movs, no waits)
        pkA0 = pkA1; pkB0 = pkB1; pkA1 = pkA2; pkB1 = pkB2;
        sA0f = sA1f; sB0f = sB1f; sA1f = sA2f; sB1f = sB2f;
        svA2 = svA3; svB2 = svB3;
    }
}

// ---------------------------------------------------------------------------
// MFMA node kernel. State lives ONLY in packed svp[node][ch]=ushort4
// {s,v0,v1,v2} (bf16 bits, RNE — bit-exact vs the old split s/v arrays).
// it==0 writes svp (16x 8-B stores/lane); it==1 reads svp for skip fragments
// and writes NOTHING (state is dead after the last interaction).
// Fused readout uses pre-rounded fp32 registers. wave = 16 sorted nodes.
// ---------------------------------------------------------------------------
__global__ __launch_bounds__(256) void node_mfma_kernel(
    const float* __restrict__ agg_s, const float* __restrict__ agg_v,
    unsigned short* svp,
    const short* __restrict__ packW, int it,
    const float* __restrict__ pw_i,
    const int* __restrict__ spec_srt,
    const int* __restrict__ row_start, const int* __restrict__ sidx,
    const float* __restrict__ Wread0, const float* __restrict__ Wr1a,
    const float* __restrict__ Wr1b,
    float* __restrict__ out,
    int has_skip)
{
    const int l = threadIdx.x & 63;
    const int wid = threadIdx.x >> 6;
    const int cl = l & 15;
    const int q = l >> 4;
    const int i16 = (blockIdx.x * 4 + wid) * 16;
    __shared__ float xls_all[4][16 * 65];
    float* xls = xls_all[wid];

    const short* pWls = packW + (size_t)(0 + it) * 4096;
    const short* pWlv = packW + (size_t)(2 + it) * 4096;
    const short* pWps = packW + (size_t)(4 + it) * 4096;
    const short* pWpv = packW + (size_t)(6 + it) * 4096;
    const short* pSkS = packW + (size_t)8 * 4096;
    const short* pSkV = packW + (size_t)18 * 4096;
    const short8 z8 = {0, 0, 0, 0, 0, 0, 0, 0};

    const float* ars = agg_s + (size_t)(i16 + cl) * 64;
    short8 As[2] = { loadArow(ars, 0, q), loadArow(ars, 1, q) };
    short8 Av[3][2];
#pragma unroll
    for (int k = 0; k < 3; ++k) {
        const float* r = agg_v + ((size_t)(i16 + cl) * 3 + k) * 64;
        Av[k][0] = loadArow(r, 0, q);
        Av[k][1] = loadArow(r, 1, q);
    }

    f32x4 sD[4];
#pragma unroll
    for (int t = 0; t < 4; ++t) {
        f32x4 acc = {0.f, 0.f, 0.f, 0.f};
        acc = MFMA16(As[0], loadB(pWls, t, 0, l), acc);
        acc = MFMA16(As[1], loadB(pWls, t, 1, l), acc);
        sD[t] = acc;
    }

    f32x4 vD[3][4];
#pragma unroll
    for (int k = 0; k < 3; ++k)
#pragma unroll
        for (int t = 0; t < 4; ++t) vD[k][t] = (f32x4){0.f, 0.f, 0.f, 0.f};
#pragma unroll
    for (int t = 0; t < 4; ++t)
#pragma unroll
        for (int h = 0; h < 2; ++h) {
            short8 b = loadB(pWlv, t, h, l);
#pragma unroll
            for (int k = 0; k < 3; ++k) vD[k][t] = MFMA16(Av[k][h], b, vD[k][t]);
        }

    int z0 = spec_srt[i16], z1 = spec_srt[i16 + 15];
    float psD[4][4], pvsD[4][4];
    if (z0 == z1) {
        const float* pb = pw_i + z0 * 576 + cl;
        float pc[9][4];
#pragma unroll
        for (int c = 0; c < 9; ++c)
#pragma unroll
            for (int t = 0; t < 4; ++t) pc[c][t] = pb[c * 64 + t * 16];
#pragma unroll
        for (int t = 0; t < 4; ++t)
#pragma unroll
            for (int r = 0; r < 4; ++r) {
                float x = sD[t][r] * EPS_C;
                float w0 = vD[0][t][r] * EPS_C;
                float w1 = vD[1][t][r] * EPS_C;
                float w2 = vD[2][t][r] * EPS_C;
                vD[0][t][r] = w0; vD[1][t][r] = w1; vD[2][t][r] = w2;
                float vv = w0 * w0 + w1 * w1 + w2 * w2;
                float x2 = x * x;
                psD[t][r] = pc[0][t] * x + pc[1][t] * x2 + pc[2][t] * vv
                          + pc[3][t] * x2 * x + pc[4][t] * x * vv;
                pvsD[t][r] = pc[5][t] + pc[6][t] * x + pc[7][t] * x2 + pc[8][t] * vv;
            }
    } else {
#pragma unroll
        for (int r = 0; r < 4; ++r) {
            int z = spec_srt[i16 + q * 4 + r];
            const float* pb = pw_i + z * 576 + cl;
#pragma unroll
            for (int t = 0; t < 4; ++t) {
                float p0 = pb[t*16], p1 = pb[64+t*16], p2 = pb[128+t*16];
                float p3 = pb[192+t*16], p4 = pb[256+t*16], p5 = pb[320+t*16];
                float p6 = pb[384+t*16], p7 = pb[448+t*16], p8 = pb[512+t*16];
                float x = sD[t][r] * EPS_C;
                float w0 = vD[0][t][r] * EPS_C;
                float w1 = vD[1][t][r] * EPS_C;
                float w2 = vD[2][t][r] * EPS_C;
                vD[0][t][r] = w0; vD[1][t][r] = w1; vD[2][t][r] = w2;
                float vv = w0 * w0 + w1 * w1 + w2 * w2;
                float x2 = x * x;
                psD[t][r] = p0 * x + p1 * x2 + p2 * vv + p3 * x2 * x + p4 * x * vv;
                pvsD[t][r] = p5 + p6 * x + p7 * x2 + p8 * vv;
            }
        }
    }

#pragma unroll
    for (int t = 0; t < 4; ++t)
#pragma unroll
        for (int r = 0; r < 4; ++r)
            xls[(q * 4 + r) * 65 + t * 16 + cl] = psD[t][r];
    short8 psA[2];
#pragma unroll
    for (int h = 0; h < 2; ++h) {
        const float* rp = xls + cl * 65 + h * 32 + q * 8;
        float t0 = rp[0], t1 = rp[1], t2 = rp[2], t3 = rp[3];
        float t4 = rp[4], t5 = rp[5], t6 = rp[6], t7 = rp[7];
        psA[h] = cvt8(make_float4(t0, t1, t2, t3), make_float4(t4, t5, t6, t7));
    }

    f32x4 snD[4];
#pragma unroll
    for (int t = 0; t < 4; ++t) {
        f32x4 acc = {0.f, 0.f, 0.f, 0.f};
        acc = MFMA16(psA[0], loadB(pWps, t, 0, l), acc);
        acc = MFMA16(psA[1], loadB(pWps, t, 1, l), acc);
        snD[t] = acc;
    }
    if (has_skip) {
        const unsigned short* prow = svp + (size_t)(i16 + cl) * 256;
        short8 Ai0 = unpack_s(prow, q * 8);
        short8 Ai1 = unpack_s(prow, 32 + q * 8);
        int myz = spec_srt[i16 + cl];
        for (int z = z0; z <= z1; ++z) {
            bool keep = (myz == z);
            short8 m0 = keep ? Ai0 : z8;
            short8 m1 = keep ? Ai1 : z8;
            const short* pz = pSkS + (size_t)z * 4096;
#pragma unroll
            for (int t = 0; t < 4; ++t) {
                snD[t] = MFMA16(m0, loadB(pz, t, 0, l), snD[t]);
                snD[t] = MFMA16(m1, loadB(pz, t, 1, l), snD[t]);
            }
        }
    }

    // ---- fused readout (pre-rounded fp32 registers)
    if (it == 0) {
        float w0c[4];
#pragma unroll
        for (int t = 0; t < 4; ++t) w0c[t] = Wread0[t * 16 + cl];
#pragma unroll
        for (int r = 0; r < 4; ++r) {
            float a = snD[0][r] * w0c[0] + snD[1][r] * w0c[1]
                    + snD[2][r] * w0c[2] + snD[3][r] * w0c[3];
            a += __shfl_down(a, 8);
            a += __shfl_down(a, 4);
            a += __shfl_down(a, 2);
            a += __shfl_down(a, 1);
            if (cl == 0) out[(size_t)sidx[i16 + q * 4 + r] * 2 + 0] = a;
        }
    } else {
#pragma unroll
        for (int t = 0; t < 4; ++t)
#pragma unroll
            for (int r = 0; r < 4; ++r)
                xls[(q * 4 + r) * 65 + t * 16 + cl] = snD[t][r];
        float acc4[4] = {0.f, 0.f, 0.f, 0.f};
        for (int g = 0; g < 64; ++g) {
            float wa = Wr1a[g * 16 + cl];
#pragma unroll
            for (int j = 0; j < 4; ++j)
                acc4[j] = fmaf(xls[(q + 4 * j) * 65 + g], wa, acc4[j]);
        }
        float wb = Wr1b[cl];
#pragma unroll
        for (int j = 0; j < 4; ++j) {
            float av = acc4[j];
            float rr = (av / (1.f + expf(-av))) * wb;
            rr += __shfl_down(rr, 8);
            rr += __shfl_down(rr, 4);
            rr += __shfl_down(rr, 2);
            rr += __shfl_down(rr, 1);
            if (cl == 0) out[(size_t)sidx[i16 + q + 4 * j] * 2 + 1] = rr;
        }
    }

    short8 pvA[3][2];
#pragma unroll
    for (int k = 0; k < 3; ++k) {
#pragma unroll
        for (int t = 0; t < 4; ++t)
#pragma unroll
            for (int r = 0; r < 4; ++r)
                xls[(q * 4 + r) * 65 + t * 16 + cl] = pvsD[t][r] * vD[k][t][r];
#pragma unroll
        for (int h = 0; h < 2; ++h) {
            const float* rp = xls + cl * 65 + h * 32 + q * 8;
            float t0 = rp[0], t1 = rp[1], t2 = rp[2], t3 = rp[3];
            float t4 = rp[4], t5 = rp[5], t6 = rp[6], t7 = rp[7];
            pvA[k][h] = cvt8(make_float4(t0, t1, t2, t3), make_float4(t4, t5, t6, t7));
        }
    }

    f32x4 vnD[3][4];
#pragma unroll
    for (int k = 0; k < 3; ++k)
#pragma unroll
        for (int t = 0; t < 4; ++t) vnD[k][t] = (f32x4){0.f, 0.f, 0.f, 0.f};
#pragma unroll
    for (int t = 0; t < 4; ++t)
#pragma unroll
        for (int h = 0; h < 2; ++h) {
            short8 b = loadB(pWpv, t, h, l);
#pragma unroll
            for (int k = 0; k < 3; ++k) vnD[k][t] = MFMA16(pvA[k][h], b, vnD[k][t]);
        }
    if (has_skip) {
        const unsigned short* prow = svp + (size_t)(i16 + cl) * 256;
        short8 Aiv[3][2];
        unpack_v(prow, q * 8, Aiv, 0);
        unpack_v(prow, 32 + q * 8, Aiv, 1);
        int myz = spec_srt[i16 + cl];
        for (int z = z0; z <= z1; ++z) {
            bool keep = (myz == z);
            const short* pz = pSkV + (size_t)z * 4096;
#pragma unroll
            for (int t = 0; t < 4; ++t)
#pragma unroll
                for (int h = 0; h < 2; ++h) {
                    short8 b = loadB(pz, t, h, l);
#pragma unroll
                    for (int k = 0; k < 3; ++k) {
                        short8 a = keep ? Aiv[k][h] : z8;
                        vnD[k][t] = MFMA16(a, b, vnD[k][t]);
                    }
                }
        }
    }

    // ---- state store: ONLY at it==0 (state is dead after last interaction).
    // Packed ushort4 {s,v0,v1,v2} per (node,channel): 16x 8-B stores/lane.
    if (it == 0) {
#pragma unroll
        for (int t = 0; t < 4; ++t)
#pragma unroll
            for (int r = 0; r < 4; ++r) {
                uint2 pk;
                pk.x = cvt2u(snD[t][r], vnD[0][t][r]);
                pk.y = cvt2u(vnD[1][t][r], vnD[2][t][r]);
                *(uint2*)(svp + ((size_t)(i16 + q * 4 + r) * 64 + t * 16 + cl) * 4) = pk;
            }
    }

    // ---- it==0: zero this wave's own agg boundary rows for interaction 1.
    if (it == 0) {
        for (int rr = 0; rr < 16; ++rr) {
            int i = i16 + rr;
            int beg = row_start[i], end = row_start[i + 1];
            bool need = (end == beg) || (end > (((beg >> 4) + 1) << 4));
            if (need) {
                float* as = (float*)agg_s;
                float* av = (float*)agg_v;
                as[(size_t)i * 64 + l] = 0.f;
                av[((size_t)i * 3 + 0) * 64 + l] = 0.f;
                av[((size_t)i * 3 + 1) * 64 + l] = 0.f;
                av[((size_t)i * 3 + 2) * 64 + l] = 0.f;
            }
        }
    }
}

// ---------------------------------------------------------------------------
extern "C" void kernel_launch(void* const* d_in, const int* in_sizes, int n_in,
                              void* d_out, int out_size, void* d_ws, size_t ws_size,
                              hipStream_t stream)
{
    const float* vectors = (const float*)d_in[0];
    const float* embed_s = (const float*)d_in[1];
    const float* Wr      = (const float*)d_in[2];   // [2,8,320]
    const float* Wls     = (const float*)d_in[3];   // [2,64,64]
    const float* Wlv     = (const float*)d_in[4];
    const float* skip_s  = (const float*)d_in[5];   // [10,64,64]
    const float* skip_v  = (const float*)d_in[6];
    const float* pw      = (const float*)d_in[7];   // [2,10,9,64]
    const float* Wps     = (const float*)d_in[8];
    const float* Wpv     = (const float*)d_in[9];
    const float* Wread0  = (const float*)d_in[10];  // [64,1]
    const float* Wr1a    = (const float*)d_in[11];  // [64,16]
    const float* Wr1b    = (const float*)d_in[12];  // [16,1]
    const int* senders   = (const int*)d_in[13];
    const int* receivers = (const int*)d_in[14];
    const int* species   = (const int*)d_in[15];
    float* out = (float*)d_out;

    float* ws = (float*)d_ws;
    float* edata = ws; ws += (size_t)N_EDGES * 16;  // 16 MB (slot-ordered)
    float* agg_s = ws; ws += (size_t)N_NODES * 64;  // 8 MB
    float* agg_v = ws; ws += (size_t)N_NODES * 192; // 24 MB
    unsigned short* svp = (unsigned short*)ws; ws += (size_t)N_NODES * 128; // 16 MB packed {s,v0,v1,v2} bf16
    int* counts    = (int*)ws; ws += N_NODES;
    int* row_start = (int*)ws; ws += N_NODES + 4;
    int* cursor    = (int*)ws; ws += N_NODES;
    int* edge_ids  = (int*)ws; ws += N_EDGES;
    int* srk       = (int*)ws; ws += N_EDGES;
    int* grp_row   = (int*)ws; ws += N_EDGES / 16;
    int* sidx      = (int*)ws; ws += N_NODES;
    int* rank      = (int*)ws; ws += N_NODES;
    int* spec_srt  = (int*)ws; ws += N_NODES;
    int* lrank_arr = (int*)ws; ws += N_NODES;
    int* counts_blk = (int*)ws; ws += 128 * NSPEC;
    int* off_blk    = (int*)ws; ws += 128 * NSPEC;
    short* packW   = (short*)ws;                    // 224 KB

    // species counting sort (sort1 also zeroes CSR counts)
    sort1_kernel<<<N_NODES / 256, 256, 0, stream>>>(
        species, counts_blk, lrank_arr, counts);
    sort2_kernel<<<1, 640, 0, stream>>>(counts_blk, off_blk);
    sort3_kernel<<<N_NODES / 256, 256, 0, stream>>>(
        species, lrank_arr, off_blk, sidx, rank, spec_srt);

    // receiver CSR in sorted space
    hist_kernel<<<N_EDGES / 256, 256, 0, stream>>>(receivers, rank, counts);
    scan_kernel<<<1, 1024, 0, stream>>>(counts, row_start, cursor);
    scatter_kernel<<<N_EDGES / 256, 256, 0, stream>>>(receivers, rank, cursor, edge_ids);

    // edge features + packed sender rank/species + grp_row (one pass)
    edge_pre_kernel<<<N_EDGES / 256, 256, 0, stream>>>(
        vectors, edge_ids, senders, rank, species, row_start, edata, srk, grp_row);

    // merged prep: weight pack + zero boundary agg rows (i0). No init_s.
    prep_kernel<<<2048, 256, 0, stream>>>(
        Wls, Wlv, Wps, Wpv, skip_s, skip_v, packW, row_start, agg_s, agg_v);

    // interaction 0 (gather reads embed table; node fuses read0 + re-zeroing
    // and writes the packed state for interaction 1's gather)
    gather_kernel<1><<<N_EDGES / 32, 64, 0, stream>>>(
        edata, srk, row_start, grp_row, embed_s, svp, Wr, agg_s, agg_v);
    node_mfma_kernel<<<N_NODES / 64, 256, 0, stream>>>(
        agg_s, agg_v, svp, packW, 0, pw, spec_srt,
        row_start, sidx, Wread0, Wr1a, Wr1b, out, 0);

    // interaction 1 (packed bf16 state: ONE 8-B random load per edge/lane)
    gather_kernel<0><<<N_EDGES / 32, 64, 0, stream>>>(
        edata, srk, row_start, grp_row, embed_s, svp, Wr + 2560, agg_s, agg_v);
    node_mfma_kernel<<<N_NODES / 64, 256, 0, stream>>>(
        agg_s, agg_v, svp, packW, 1, pw + 5760, spec_srt,
        row_start, sidx, Wread0, Wr1a, Wr1b, out, 1);
}

// Round 6
// 295.464 us; speedup vs baseline: 1.1306x; 1.0400x over previous
//
#include <hip/hip_runtime.h>
#include <hip/hip_bf16.h>
#include <math.h>

#define N_NODES 32768
#define N_EDGES 262144
#define EPS_C 0.24253562503633297f   // 1/sqrt(17)
#define NSPEC 10

typedef __attribute__((ext_vector_type(8))) short short8;   // 8 bf16
typedef __attribute__((ext_vector_type(4))) float f32x4;    // 4 fp32 acc

#define MFMA16(a, b, c) __builtin_amdgcn_mfma_f32_16x16x32_bf16(a, b, c, 0, 0, 0)

__device__ __forceinline__ short2 cvt2(float a, float b) {
    union { __hip_bfloat162 h; short2 s; } u;
    u.h = __float22bfloat162_rn(make_float2(a, b));
    return u.s;
}
__device__ __forceinline__ unsigned cvt2u(float a, float b) {
    union { __hip_bfloat162 h; unsigned u; } u;
    u.h = __float22bfloat162_rn(make_float2(a, b));
    return u.u;   // lo16 = bf(a), hi16 = bf(b)
}
__device__ __forceinline__ unsigned short f2bf(float a) {
    return (unsigned short)cvt2(a, 0.f).x;
}
__device__ __forceinline__ float bf2f(unsigned short u) {
    return __uint_as_float(((unsigned)u) << 16);
}
__device__ __forceinline__ short8 cvt8(float4 a, float4 b) {
    short2 p0 = cvt2(a.x, a.y), p1 = cvt2(a.z, a.w);
    short2 p2 = cvt2(b.x, b.y), p3 = cvt2(b.z, b.w);
    short8 r;
    r[0] = p0.x; r[1] = p0.y; r[2] = p1.x; r[3] = p1.y;
    r[4] = p2.x; r[5] = p2.y; r[6] = p3.x; r[7] = p3.y;
    return r;
}
__device__ __forceinline__ short8 loadArow(const float* rowp, int h, int q) {
    const float* p = rowp + h * 32 + q * 8;
    return cvt8(*(const float4*)p, *(const float4*)(p + 4));
}
__device__ __forceinline__ short8 loadB(const short* P, int t, int h, int l) {
    return *(const short8*)(P + (((t * 2 + h) * 64 + l) << 3));
}

// packed state svp[node][64 ch][4] = ushort4 {s, v0, v1, v2} (bf16 bits).
// unpack helpers for the node kernel's skip-fragment reads: 8 channels
// starting at ch0 for one node row (prow = svp + node*256).
__device__ __forceinline__ short8 unpack_s(const unsigned short* prow, int ch0) {
    const uint4* p = (const uint4*)(prow + ch0 * 4);
    uint4 u0 = p[0], u1 = p[1], u2 = p[2], u3 = p[3];
    short8 r;
    r[0] = (short)(u0.x & 0xffff); r[1] = (short)(u0.z & 0xffff);
    r[2] = (short)(u1.x & 0xffff); r[3] = (short)(u1.z & 0xffff);
    r[4] = (short)(u2.x & 0xffff); r[5] = (short)(u2.z & 0xffff);
    r[6] = (short)(u3.x & 0xffff); r[7] = (short)(u3.z & 0xffff);
    return r;
}
__device__ __forceinline__ void unpack_v(const unsigned short* prow, int ch0,
                                         short8 (&Aiv)[3][2], int h) {
    const uint4* p = (const uint4*)(prow + ch0 * 4);
    uint4 u0 = p[0], u1 = p[1], u2 = p[2], u3 = p[3];
    Aiv[0][h][0] = (short)(u0.x >> 16); Aiv[0][h][1] = (short)(u0.z >> 16);
    Aiv[0][h][2] = (short)(u1.x >> 16); Aiv[0][h][3] = (short)(u1.z >> 16);
    Aiv[0][h][4] = (short)(u2.x >> 16); Aiv[0][h][5] = (short)(u2.z >> 16);
    Aiv[0][h][6] = (short)(u3.x >> 16); Aiv[0][h][7] = (short)(u3.z >> 16);
    Aiv[1][h][0] = (short)(u0.y & 0xffff); Aiv[1][h][1] = (short)(u0.w & 0xffff);
    Aiv[1][h][2] = (short)(u1.y & 0xffff); Aiv[1][h][3] = (short)(u1.w & 0xffff);
    Aiv[1][h][4] = (short)(u2.y & 0xffff); Aiv[1][h][5] = (short)(u2.w & 0xffff);
    Aiv[1][h][6] = (short)(u3.y & 0xffff); Aiv[1][h][7] = (short)(u3.w & 0xffff);
    Aiv[2][h][0] = (short)(u0.y >> 16); Aiv[2][h][1] = (short)(u0.w >> 16);
    Aiv[2][h][2] = (short)(u1.y >> 16); Aiv[2][h][3] = (short)(u1.w >> 16);
    Aiv[2][h][4] = (short)(u2.y >> 16); Aiv[2][h][5] = (short)(u2.w >> 16);
    Aiv[2][h][6] = (short)(u3.y >> 16); Aiv[2][h][7] = (short)(u3.w >> 16);
}

// ---------------------------------------------------------------------------
// Species counting sort — contention-free, deterministic. sort1 also zeroes
// the receiver-CSR counts array.
// ---------------------------------------------------------------------------
__global__ __launch_bounds__(256) void sort1_kernel(
    const int* __restrict__ species, int* __restrict__ counts_blk,
    int* __restrict__ lrank_arr, int* __restrict__ counts)
{
    __shared__ int wcnt[4][16];
    int n = blockIdx.x * 256 + threadIdx.x;
    counts[n] = 0;
    int sp = species[n];
    int lane = threadIdx.x & 63, wv = threadIdx.x >> 6;
    unsigned long long ltmask = (1ull << lane) - 1;
    int lrank_w = 0;
#pragma unroll
    for (int z = 0; z < NSPEC; ++z) {
        unsigned long long m = __ballot(sp == z);
        if (sp == z) lrank_w = __popcll(m & ltmask);
        if (lane == 0) wcnt[wv][z] = __popcll(m);
    }
    __syncthreads();
    int off = 0;
    for (int w = 0; w < wv; ++w) off += wcnt[w][sp];
    lrank_arr[n] = lrank_w + off;
    if (threadIdx.x < NSPEC)
        counts_blk[blockIdx.x * NSPEC + threadIdx.x] =
            wcnt[0][threadIdx.x] + wcnt[1][threadIdx.x] +
            wcnt[2][threadIdx.x] + wcnt[3][threadIdx.x];
}

// parallel block-offset scan: wave z shuffle-scans its 128 block counts
__global__ __launch_bounds__(640) void sort2_kernel(
    const int* __restrict__ counts_blk, int* __restrict__ off_blk)
{
    __shared__ int totals[16];
    int wv = threadIdx.x >> 6;        // 0..9 == species z
    int lane = threadIdx.x & 63;
    int c0 = counts_blk[lane * NSPEC + wv];
    int c1 = counts_blk[(64 + lane) * NSPEC + wv];
    int s0 = c0;
#pragma unroll
    for (int off = 1; off < 64; off <<= 1) {
        int y = __shfl_up(s0, off);
        if (lane >= off) s0 += y;
    }
    int tot0 = __shfl(s0, 63);
    int s1 = c1;
#pragma unroll
    for (int off = 1; off < 64; off <<= 1) {
        int y = __shfl_up(s1, off);
        if (lane >= off) s1 += y;
    }
    s1 += tot0;
    if (lane == 63) totals[wv] = s1;
    __syncthreads();
    int base = 0;
    for (int q = 0; q < wv; ++q) base += totals[q];
    off_blk[lane * NSPEC + wv] = base + s0 - c0;
    off_blk[(64 + lane) * NSPEC + wv] = base + s1 - c1;
}

__global__ __launch_bounds__(256) void sort3_kernel(
    const int* __restrict__ species, const int* __restrict__ lrank_arr,
    const int* __restrict__ off_blk,
    int* __restrict__ sidx, int* __restrict__ rank, int* __restrict__ spec_srt)
{
    int n = blockIdx.x * 256 + threadIdx.x;
    int sp = species[n];
    int slot = off_blk[blockIdx.x * NSPEC + sp] + lrank_arr[n];
    sidx[slot] = n;
    rank[n] = slot;
    spec_srt[slot] = sp;
}

// ---------------------------------------------------------------------------
// Receiver CSR in SORTED space
// ---------------------------------------------------------------------------
__global__ __launch_bounds__(256) void hist_kernel(
    const int* __restrict__ receivers, const int* __restrict__ rank,
    int* __restrict__ counts)
{
    int e = blockIdx.x * 256 + threadIdx.x;
    atomicAdd(&counts[rank[receivers[e]]], 1);
}

__global__ __launch_bounds__(1024) void scan_kernel(
    const int* __restrict__ counts, int* __restrict__ row_start, int* __restrict__ cursor)
{
    __shared__ int wave_tot[16];
    int tid = threadIdx.x;
    int c[32];
    int sum = 0;
#pragma unroll
    for (int i = 0; i < 32; ++i) { c[i] = counts[tid * 32 + i]; sum += c[i]; }
    int lane = tid & 63, wv = tid >> 6;
    int x = sum;
#pragma unroll
    for (int off = 1; off < 64; off <<= 1) {
        int y = __shfl_up(x, off);
        if (lane >= off) x += y;
    }
    if (lane == 63) wave_tot[wv] = x;
    __syncthreads();
    if (wv == 0 && lane < 16) {
        int t = wave_tot[lane];
#pragma unroll
        for (int off = 1; off < 16; off <<= 1) {
            int y = __shfl_up(t, off);
            if (lane >= off) t += y;
        }
        wave_tot[lane] = t;
    }
    __syncthreads();
    int excl = x - sum + (wv ? wave_tot[wv - 1] : 0);
    int run = excl;
#pragma unroll
    for (int i = 0; i < 32; ++i) {
        row_start[tid * 32 + i] = run;
        cursor[tid * 32 + i] = run;
        run += c[i];
    }
    if (tid == 1023) row_start[32768] = run;
}

__global__ __launch_bounds__(256) void scatter_kernel(
    const int* __restrict__ receivers, const int* __restrict__ rank,
    int* __restrict__ cursor, int* __restrict__ edge_ids)
{
    int e = blockIdx.x * 256 + threadIdx.x;
    int slot = atomicAdd(&cursor[rank[receivers[e]]], 1);
    edge_ids[slot] = e;
}

// ---------------------------------------------------------------------------
// Edge precompute in slot order + fused sender-rank/species stream + grp_row.
// srk[p] = rank | (species << 16)
// ---------------------------------------------------------------------------
__global__ __launch_bounds__(256) void edge_pre_kernel(
    const float* __restrict__ vectors, const int* __restrict__ edge_ids,
    const int* __restrict__ senders, const int* __restrict__ rank,
    const int* __restrict__ species, const int* __restrict__ row_start,
    float* __restrict__ edata, int* __restrict__ srk, int* __restrict__ grp_row)
{
    int p = blockIdx.x * 256 + threadIdx.x;
    int e = edge_ids[p];
    int snd = senders[e];
    srk[p] = rank[snd] | (species[snd] << 16);
    float x = vectors[e * 3 + 0], y = vectors[e * 3 + 1], z = vectors[e * 3 + 2];
    float r2 = x * x + y * y + z * z + 1e-12f;
    float r = sqrtf(r2);
    float inv = 1.0f / r;
    float* d = edata + (size_t)p * 16;
    *(float4*)d = make_float4(x * inv, y * inv, z * inv, 0.0f);
    float rc = fmaxf(r, 1e-6f);
    float r6 = r2 * r2 * r2;
    float r7 = r6 * r;
    float r8 = r6 * r2;
    float env = (r < 1.0f) ? (1.0f - 28.0f * r6 + 48.0f * r7 - 21.0f * r8) : 0.0f;
    float sc = 1.41421356237309515f * env / rc;
#pragma unroll
    for (int j = 0; j < 8; ++j)
        d[4 + j] = sc * sinf((float)(j + 1) * 3.14159265358979323846f * rc);
    d[12] = 0.f; d[13] = 0.f; d[14] = 0.f; d[15] = 0.f;

    if (p < N_EDGES / 16) {
        int target = p * 16;
        int lo = 0, hi = N_NODES - 1;
        while (lo < hi) {
            int mid = (lo + hi + 1) >> 1;
            if (row_start[mid] <= target) lo = mid; else hi = mid - 1;
        }
        grp_row[p] = lo;
    }
}

// ---------------------------------------------------------------------------
// Merged prep: weight pack (blocks<448) + zero_bnd for interaction 0.
// ---------------------------------------------------------------------------
__global__ __launch_bounds__(256) void prep_kernel(
    const float* __restrict__ Wls, const float* __restrict__ Wlv,
    const float* __restrict__ Wps, const float* __restrict__ Wpv,
    const float* __restrict__ skip_s, const float* __restrict__ skip_v,
    short* __restrict__ packW,
    const int* __restrict__ row_start,
    float* __restrict__ agg_s, float* __restrict__ agg_v)
{
    int idx = blockIdx.x * 256 + threadIdx.x;
    if (blockIdx.x < 448 && idx < 28 * 4096) {
        int m = idx >> 12, e = idx & 4095;
        int t = e >> 10, h = (e >> 9) & 1, l = (e >> 3) & 63, j = e & 7;
        int fi = h * 32 + ((l >> 4) << 3) + j;
        int fo = t * 16 + (l & 15);
        const float* src;
        if      (m < 2)  src = Wls    + m * 4096;
        else if (m < 4)  src = Wlv    + (m - 2) * 4096;
        else if (m < 6)  src = Wps    + (m - 4) * 4096;
        else if (m < 8)  src = Wpv    + (m - 6) * 4096;
        else if (m < 18) src = skip_s + (m - 8) * 4096;
        else             src = skip_v + (m - 18) * 4096;
        packW[idx] = cvt2(src[fi * 64 + fo], 0.f).x;
    }
    const int wid = threadIdx.x >> 6;
    const int f = threadIdx.x & 63;
    const int base = (blockIdx.x * 4 + wid) * 4;
#pragma unroll
    for (int t = 0; t < 4; ++t) {
        int i = base + t;
        int beg = row_start[i], end = row_start[i + 1];
        bool need = (end == beg) || (end > (((beg >> 4) + 1) << 4));
        if (need) {
            agg_s[(size_t)i * 64 + f] = 0.f;
            agg_v[((size_t)i * 3 + 0) * 64 + f] = 0.f;
            agg_v[((size_t)i * 3 + 1) * 64 + f] = 0.f;
            agg_v[((size_t)i * 3 + 2) * 64 + f] = 0.f;
        }
    }
}

// ---------------------------------------------------------------------------
// Dual-chain edge-balanced gather, 1 wave/block, depth-2 software pipeline
// (raw bits staged, consume-time conversion, fully unrolled 16-iter loop).
// DO NOT use multi-wave workgroups here: tried 4-wave (r1) and 2-wave (r3);
// both regress badly (VGPR 52->64, scratch spills visible as +42MB
// WRITE_SIZE, occupancy unchanged ~33%). 1-wave/64-thread is the config.
// !VZERO reads the PACKED state svp[node][ch] = ushort4{s,v0,v1,v2}: ONE
// 8-B uint2 per edge per lane instead of 4 scattered line accesses.
// VZERO: s from 2.5KB embed table (L1-resident).
// NOTE r5: this exact kernel measured 307us total on a degraded node
// (137s acquire, 8% replay variance, 1.7TB/s where identical code had hit
// 2.8TB/s in r2). Re-measuring unchanged per rule-13 (same-kernel repeat
// required to separate node noise from code delta).
// ---------------------------------------------------------------------------
template<int VZERO>
__global__ __launch_bounds__(64, 4) void gather_kernel(
    const float* __restrict__ edata, const int* __restrict__ srk,
    const int* __restrict__ row_start, const int* __restrict__ grp_row,
    const float* __restrict__ embed_s,
    const unsigned short* __restrict__ svp,
    const float* __restrict__ Wr_i,
    float* __restrict__ agg_s, float* __restrict__ agg_v)
{
    const int f = threadIdx.x & 63;
    const int w = blockIdx.x;
    const int pA0 = w * 32;
    const int pB0 = pA0 + 16;

    float wr[5][8];
#pragma unroll
    for (int j = 0; j < 8; ++j)
#pragma unroll
        for (int p = 0; p < 5; ++p)
            wr[p][j] = (VZERO && (p == 1 || p == 3 || p == 4))
                       ? 0.f : Wr_i[j * 320 + p * 64 + f];

    int rA = grp_row[2 * w], rB = grp_row[2 * w + 1];
    int begA = row_start[rA], endA = row_start[rA + 1];
    int begB = row_start[rB], endB = row_start[rB + 1];
    float aA0 = 0.f, aA1 = 0.f, aA2 = 0.f, aA3 = 0.f;
    float aB0 = 0.f, aB1 = 0.f, aB2 = 0.f, aB3 = 0.f;

    // 3-stage pipeline. Stage0 = edge k (consumed this iter), stage1 = k+1
    // (in flight), stage2 = k+2 (issued this iter).
    int svA2 = srk[pA0 + 2], svB2 = srk[pB0 + 2];
    uint2 pkA0 = {0, 0}, pkB0 = {0, 0}, pkA1 = {0, 0}, pkB1 = {0, 0};
    float sA0f = 0.f, sB0f = 0.f, sA1f = 0.f, sB1f = 0.f;
    {
        int svA0 = srk[pA0], svB0 = srk[pB0];
        int svA1 = srk[pA0 + 1], svB1 = srk[pB0 + 1];
        if (VZERO) {
            sA0f = embed_s[(svA0 >> 16) * 64 + f];
            sB0f = embed_s[(svB0 >> 16) * 64 + f];
            sA1f = embed_s[(svA1 >> 16) * 64 + f];
            sB1f = embed_s[(svB1 >> 16) * 64 + f];
        } else {
            pkA0 = *(const uint2*)(svp + (((size_t)(svA0 & 0xFFFF)) * 64 + f) * 4);
            pkB0 = *(const uint2*)(svp + (((size_t)(svB0 & 0xFFFF)) * 64 + f) * 4);
            pkA1 = *(const uint2*)(svp + (((size_t)(svA1 & 0xFFFF)) * 64 + f) * 4);
            pkB1 = *(const uint2*)(svp + (((size_t)(svB1 & 0xFFFF)) * 64 + f) * 4);
        }
    }

#pragma unroll
    for (int k = 0; k < 16; ++k) {
        const int pA = pA0 + k, pB = pB0 + k;
        // srk prefetch for edge k+3 (A side always in-bounds; B clamps)
        int svA3 = srk[pA + 3];
        int iB3 = pB + 3;
        int svB3 = srk[iB3 < N_EDGES ? iB3 : N_EDGES - 1];

        // issue stage-2 state loads (edge k+2) — raw bits, no conversion
        uint2 pkA2 = {0, 0}, pkB2 = {0, 0};
        float sA2f = 0.f, sB2f = 0.f;
        if (VZERO) {
            sA2f = embed_s[(svA2 >> 16) * 64 + f];
            sB2f = embed_s[(svB2 >> 16) * 64 + f];
        } else {
            pkA2 = *(const uint2*)(svp + (((size_t)(svA2 & 0xFFFF)) * 64 + f) * 4);
            pkB2 = *(const uint2*)(svp + (((size_t)(svB2 & 0xFFFF)) * 64 + f) * 4);
        }

        const float* dA = edata + (size_t)pA * 16;
        const float* dB = edata + (size_t)pB * 16;
        float4 yA = *(const float4*)dA;
        float4 qA0 = *(const float4*)(dA + 4);
        float4 qA1 = *(const float4*)(dA + 8);
        float4 yB = *(const float4*)dB;
        float4 qB0 = *(const float4*)(dB + 4);
        float4 qB1 = *(const float4*)(dB + 8);

        float rbA[8] = {qA0.x, qA0.y, qA0.z, qA0.w, qA1.x, qA1.y, qA1.z, qA1.w};
        float rbB[8] = {qB0.x, qB0.y, qB0.z, qB0.w, qB1.x, qB1.y, qB1.z, qB1.w};
        float wA0 = 0.f, wA1 = 0.f, wA2 = 0.f, wA3 = 0.f, wA4 = 0.f;
        float wB0 = 0.f, wB1 = 0.f, wB2 = 0.f, wB3 = 0.f, wB4 = 0.f;
#pragma unroll
        for (int j = 0; j < 8; ++j) {
            wA0 = fmaf(rbA[j], wr[0][j], wA0);  wB0 = fmaf(rbB[j], wr[0][j], wB0);
            if (!VZERO) { wA1 = fmaf(rbA[j], wr[1][j], wA1);  wB1 = fmaf(rbB[j], wr[1][j], wB1); }
            wA2 = fmaf(rbA[j], wr[2][j], wA2);  wB2 = fmaf(rbB[j], wr[2][j], wB2);
            if (!VZERO) { wA3 = fmaf(rbA[j], wr[3][j], wA3);  wB3 = fmaf(rbB[j], wr[3][j], wB3); }
            if (!VZERO) { wA4 = fmaf(rbA[j], wr[4][j], wA4);  wB4 = fmaf(rbB[j], wr[4][j], wB4); }
        }

        // consume stage0 — conversion (exact shift/and) happens HERE, so the
        // s_waitcnt for these loads lands 2 iterations after issue.
        if (VZERO) {
            float ssA = sA0f, ssB = sB0f;
            aA0 += wA0 * ssA;
            float wsA = wA2 * ssA;
            aA1 += wsA * yA.x; aA2 += wsA * yA.y; aA3 += wsA * yA.z;
            aB0 += wB0 * ssB;
            float wsB = wB2 * ssB;
            aB1 += wsB * yB.x; aB2 += wsB * yB.y; aB3 += wsB * yB.z;
        } else {
            float ssA = __uint_as_float(pkA0.x << 16);
            float va0 = __uint_as_float(pkA0.x & 0xffff0000u);
            float va1 = __uint_as_float(pkA0.y << 16);
            float va2 = __uint_as_float(pkA0.y & 0xffff0000u);
            float ssB = __uint_as_float(pkB0.x << 16);
            float vb0 = __uint_as_float(pkB0.x & 0xffff0000u);
            float vb1 = __uint_as_float(pkB0.y << 16);
            float vb2 = __uint_as_float(pkB0.y & 0xffff0000u);
            float dotA = va0 * yA.x + va1 * yA.y + va2 * yA.z;
            aA0 += wA0 * ssA + wA1 * dotA;
            float cA0 = va1 * yA.z - va2 * yA.y;
            float cA1 = va2 * yA.x - va0 * yA.z;
            float cA2 = va0 * yA.y - va1 * yA.x;
            float wsA = wA2 * ssA;
            aA1 += wsA * yA.x + wA3 * va0 + wA4 * cA0;
            aA2 += wsA * yA.y + wA3 * va1 + wA4 * cA1;
            aA3 += wsA * yA.z + wA3 * va2 + wA4 * cA2;
            float dotB = vb0 * yB.x + vb1 * yB.y + vb2 * yB.z;
            aB0 += wB0 * ssB + wB1 * dotB;
            float cB0 = vb1 * yB.z - vb2 * yB.y;
            float cB1 = vb2 * yB.x - vb0 * yB.z;
            float cB2 = vb0 * yB.y - vb1 * yB.x;
            float wsB = wB2 * ssB;
            aB1 += wsB * yB.x + wB3 * vb0 + wB4 * cB0;
            aB2 += wsB * yB.y + wB3 * vb1 + wB4 * cB1;
            aB3 += wsB * yB.z + wB3 * vb2 + wB4 * cB2;
        }

        if (pA + 1 == endA || k == 15) {
            bool interior = (begA >= pA0) && (endA <= pA0 + 16);
            if (interior) {
                agg_s[(size_t)rA * 64 + f] = aA0;
                agg_v[((size_t)rA * 3 + 0) * 64 + f] = aA1;
                agg_v[((size_t)rA * 3 + 1) * 64 + f] = aA2;
                agg_v[((size_t)rA * 3 + 2) * 64 + f] = aA3;
            } else {
                unsafeAtomicAdd(&agg_s[(size_t)rA * 64 + f], aA0);
                unsafeAtomicAdd(&agg_v[((size_t)rA * 3 + 0) * 64 + f], aA1);
                unsafeAtomicAdd(&agg_v[((size_t)rA * 3 + 1) * 64 + f], aA2);
                unsafeAtomicAdd(&agg_v[((size_t)rA * 3 + 2) * 64 + f], aA3);
            }
            aA0 = aA1 = aA2 = aA3 = 0.f;
            if (pA + 1 == endA && k < 15) {
                begA = endA; ++rA; endA = row_start[rA + 1];
                while (endA == begA) { ++rA; endA = row_start[rA + 1]; }
            }
        }
        if (pB + 1 == endB || k == 15) {
            bool interior = (begB >= pB0) && (endB <= pB0 + 16);
            if (interior) {
                agg_s[(size_t)rB * 64 + f] = aB0;
                agg_v[((size_t)rB * 3 + 0) * 64 + f] = aB1;
                agg_v[((size_t)rB * 3 + 1) * 64 + f] = aB2;
                agg_v[((size_t)rB * 3 + 2) * 64 + f] = aB3;
            } else {
                unsafeAtomicAdd(&agg_s[(size_t)rB * 64 + f], aB0);
                unsafeAtomicAdd(&agg_v[((size_t)rB * 3 + 0) * 64 + f], aB1);
                unsafeAtomicAdd(&agg_v[((size_t)rB * 3 + 1) * 64 + f], aB2);
                unsafeAtomicAdd(&agg_v[((size_t)rB * 3 + 2) * 64 + f], aB3);
            }
            aB0 = aB1 = aB2 = aB3 = 0.f;
            if (pB + 1 == endB && k < 15) {
                begB = endB; ++rB; endB = row_start[rB + 1];
                while (endB == begB) { ++rB; endB = row_start[rB + 1]; }
            }
        }

        // rotate stages (SSA renames under full unroll — no movs, no waits)
        pkA0 = pkA1; pkB0 = pkB1; pkA1 = pkA2; pkB1 = pkB2;
        sA0f = sA1f; sB0f = sB1f; sA1f = sA2f; sB1f = sB2f;
        svA2 = svA3; svB2 = svB3;
    }
}

// ---------------------------------------------------------------------------
// MFMA node kernel. State lives ONLY in packed svp[node][ch]=ushort4
// {s,v0,v1,v2} (bf16 bits, RNE — bit-exact vs the old split s/v arrays).
// it==0 writes svp (16x 8-B stores/lane); it==1 reads svp for skip fragments
// and writes NOTHING (state is dead after the last interaction).
// Fused readout uses pre-rounded fp32 registers. wave = 16 sorted nodes.
// ---------------------------------------------------------------------------
__global__ __launch_bounds__(256) void node_mfma_kernel(
    const float* __restrict__ agg_s, const float* __restrict__ agg_v,
    unsigned short* svp,
    const short* __restrict__ packW, int it,
    const float* __restrict__ pw_i,
    const int* __restrict__ spec_srt,
    const int* __restrict__ row_start, const int* __restrict__ sidx,
    const float* __restrict__ Wread0, const float* __restrict__ Wr1a,
    const float* __restrict__ Wr1b,
    float* __restrict__ out,
    int has_skip)
{
    const int l = threadIdx.x & 63;
    const int wid = threadIdx.x >> 6;
    const int cl = l & 15;
    const int q = l >> 4;
    const int i16 = (blockIdx.x * 4 + wid) * 16;
    __shared__ float xls_all[4][16 * 65];
    float* xls = xls_all[wid];

    const short* pWls = packW + (size_t)(0 + it) * 4096;
    const short* pWlv = packW + (size_t)(2 + it) * 4096;
    const short* pWps = packW + (size_t)(4 + it) * 4096;
    const short* pWpv = packW + (size_t)(6 + it) * 4096;
    const short* pSkS = packW + (size_t)8 * 4096;
    const short* pSkV = packW + (size_t)18 * 4096;
    const short8 z8 = {0, 0, 0, 0, 0, 0, 0, 0};

    const float* ars = agg_s + (size_t)(i16 + cl) * 64;
    short8 As[2] = { loadArow(ars, 0, q), loadArow(ars, 1, q) };
    short8 Av[3][2];
#pragma unroll
    for (int k = 0; k < 3; ++k) {
        const float* r = agg_v + ((size_t)(i16 + cl) * 3 + k) * 64;
        Av[k][0] = loadArow(r, 0, q);
        Av[k][1] = loadArow(r, 1, q);
    }

    f32x4 sD[4];
#pragma unroll
    for (int t = 0; t < 4; ++t) {
        f32x4 acc = {0.f, 0.f, 0.f, 0.f};
        acc = MFMA16(As[0], loadB(pWls, t, 0, l), acc);
        acc = MFMA16(As[1], loadB(pWls, t, 1, l), acc);
        sD[t] = acc;
    }

    f32x4 vD[3][4];
#pragma unroll
    for (int k = 0; k < 3; ++k)
#pragma unroll
        for (int t = 0; t < 4; ++t) vD[k][t] = (f32x4){0.f, 0.f, 0.f, 0.f};
#pragma unroll
    for (int t = 0; t < 4; ++t)
#pragma unroll
        for (int h = 0; h < 2; ++h) {
            short8 b = loadB(pWlv, t, h, l);
#pragma unroll
            for (int k = 0; k < 3; ++k) vD[k][t] = MFMA16(Av[k][h], b, vD[k][t]);
        }

    int z0 = spec_srt[i16], z1 = spec_srt[i16 + 15];
    float psD[4][4], pvsD[4][4];
    if (z0 == z1) {
        const float* pb = pw_i + z0 * 576 + cl;
        float pc[9][4];
#pragma unroll
        for (int c = 0; c < 9; ++c)
#pragma unroll
            for (int t = 0; t < 4; ++t) pc[c][t] = pb[c * 64 + t * 16];
#pragma unroll
        for (int t = 0; t < 4; ++t)
#pragma unroll
            for (int r = 0; r < 4; ++r) {
                float x = sD[t][r] * EPS_C;
                float w0 = vD[0][t][r] * EPS_C;
                float w1 = vD[1][t][r] * EPS_C;
                float w2 = vD[2][t][r] * EPS_C;
                vD[0][t][r] = w0; vD[1][t][r] = w1; vD[2][t][r] = w2;
                float vv = w0 * w0 + w1 * w1 + w2 * w2;
                float x2 = x * x;
                psD[t][r] = pc[0][t] * x + pc[1][t] * x2 + pc[2][t] * vv
                          + pc[3][t] * x2 * x + pc[4][t] * x * vv;
                pvsD[t][r] = pc[5][t] + pc[6][t] * x + pc[7][t] * x2 + pc[8][t] * vv;
            }
    } else {
#pragma unroll
        for (int r = 0; r < 4; ++r) {
            int z = spec_srt[i16 + q * 4 + r];
            const float* pb = pw_i + z * 576 + cl;
#pragma unroll
            for (int t = 0; t < 4; ++t) {
                float p0 = pb[t*16], p1 = pb[64+t*16], p2 = pb[128+t*16];
                float p3 = pb[192+t*16], p4 = pb[256+t*16], p5 = pb[320+t*16];
                float p6 = pb[384+t*16], p7 = pb[448+t*16], p8 = pb[512+t*16];
                float x = sD[t][r] * EPS_C;
                float w0 = vD[0][t][r] * EPS_C;
                float w1 = vD[1][t][r] * EPS_C;
                float w2 = vD[2][t][r] * EPS_C;
                vD[0][t][r] = w0; vD[1][t][r] = w1; vD[2][t][r] = w2;
                float vv = w0 * w0 + w1 * w1 + w2 * w2;
                float x2 = x * x;
                psD[t][r] = p0 * x + p1 * x2 + p2 * vv + p3 * x2 * x + p4 * x * vv;
                pvsD[t][r] = p5 + p6 * x + p7 * x2 + p8 * vv;
            }
        }
    }

#pragma unroll
    for (int t = 0; t < 4; ++t)
#pragma unroll
        for (int r = 0; r < 4; ++r)
            xls[(q * 4 + r) * 65 + t * 16 + cl] = psD[t][r];
    short8 psA[2];
#pragma unroll
    for (int h = 0; h < 2; ++h) {
        const float* rp = xls + cl * 65 + h * 32 + q * 8;
        float t0 = rp[0], t1 = rp[1], t2 = rp[2], t3 = rp[3];
        float t4 = rp[4], t5 = rp[5], t6 = rp[6], t7 = rp[7];
        psA[h] = cvt8(make_float4(t0, t1, t2, t3), make_float4(t4, t5, t6, t7));
    }

    f32x4 snD[4];
#pragma unroll
    for (int t = 0; t < 4; ++t) {
        f32x4 acc = {0.f, 0.f, 0.f, 0.f};
        acc = MFMA16(psA[0], loadB(pWps, t, 0, l), acc);
        acc = MFMA16(psA[1], loadB(pWps, t, 1, l), acc);
        snD[t] = acc;
    }
    if (has_skip) {
        const unsigned short* prow = svp + (size_t)(i16 + cl) * 256;
        short8 Ai0 = unpack_s(prow, q * 8);
        short8 Ai1 = unpack_s(prow, 32 + q * 8);
        int myz = spec_srt[i16 + cl];
        for (int z = z0; z <= z1; ++z) {
            bool keep = (myz == z);
            short8 m0 = keep ? Ai0 : z8;
            short8 m1 = keep ? Ai1 : z8;
            const short* pz = pSkS + (size_t)z * 4096;
#pragma unroll
            for (int t = 0; t < 4; ++t) {
                snD[t] = MFMA16(m0, loadB(pz, t, 0, l), snD[t]);
                snD[t] = MFMA16(m1, loadB(pz, t, 1, l), snD[t]);
            }
        }
    }

    // ---- fused readout (pre-rounded fp32 registers)
    if (it == 0) {
        float w0c[4];
#pragma unroll
        for (int t = 0; t < 4; ++t) w0c[t] = Wread0[t * 16 + cl];
#pragma unroll
        for (int r = 0; r < 4; ++r) {
            float a = snD[0][r] * w0c[0] + snD[1][r] * w0c[1]
                    + snD[2][r] * w0c[2] + snD[3][r] * w0c[3];
            a += __shfl_down(a, 8);
            a += __shfl_down(a, 4);
            a += __shfl_down(a, 2);
            a += __shfl_down(a, 1);
            if (cl == 0) out[(size_t)sidx[i16 + q * 4 + r] * 2 + 0] = a;
        }
    } else {
#pragma unroll
        for (int t = 0; t < 4; ++t)
#pragma unroll
            for (int r = 0; r < 4; ++r)
                xls[(q * 4 + r) * 65 + t * 16 + cl] = snD[t][r];
        float acc4[4] = {0.f, 0.f, 0.f, 0.f};
        for (int g = 0; g < 64; ++g) {
            float wa = Wr1a[g * 16 + cl];
#pragma unroll
            for (int j = 0; j < 4; ++j)
                acc4[j] = fmaf(xls[(q + 4 * j) * 65 + g], wa, acc4[j]);
        }
        float wb = Wr1b[cl];
#pragma unroll
        for (int j = 0; j < 4; ++j) {
            float av = acc4[j];
            float rr = (av / (1.f + expf(-av))) * wb;
            rr += __shfl_down(rr, 8);
            rr += __shfl_down(rr, 4);
            rr += __shfl_down(rr, 2);
            rr += __shfl_down(rr, 1);
            if (cl == 0) out[(size_t)sidx[i16 + q + 4 * j] * 2 + 1] = rr;
        }
    }

    short8 pvA[3][2];
#pragma unroll
    for (int k = 0; k < 3; ++k) {
#pragma unroll
        for (int t = 0; t < 4; ++t)
#pragma unroll
            for (int r = 0; r < 4; ++r)
                xls[(q * 4 + r) * 65 + t * 16 + cl] = pvsD[t][r] * vD[k][t][r];
#pragma unroll
        for (int h = 0; h < 2; ++h) {
            const float* rp = xls + cl * 65 + h * 32 + q * 8;
            float t0 = rp[0], t1 = rp[1], t2 = rp[2], t3 = rp[3];
            float t4 = rp[4], t5 = rp[5], t6 = rp[6], t7 = rp[7];
            pvA[k][h] = cvt8(make_float4(t0, t1, t2, t3), make_float4(t4, t5, t6, t7));
        }
    }

    f32x4 vnD[3][4];
#pragma unroll
    for (int k = 0; k < 3; ++k)
#pragma unroll
        for (int t = 0; t < 4; ++t) vnD[k][t] = (f32x4){0.f, 0.f, 0.f, 0.f};
#pragma unroll
    for (int t = 0; t < 4; ++t)
#pragma unroll
        for (int h = 0; h < 2; ++h) {
            short8 b = loadB(pWpv, t, h, l);
#pragma unroll
            for (int k = 0; k < 3; ++k) vnD[k][t] = MFMA16(pvA[k][h], b, vnD[k][t]);
        }
    if (has_skip) {
        const unsigned short* prow = svp + (size_t)(i16 + cl) * 256;
        short8 Aiv[3][2];
        unpack_v(prow, q * 8, Aiv, 0);
        unpack_v(prow, 32 + q * 8, Aiv, 1);
        int myz = spec_srt[i16 + cl];
        for (int z = z0; z <= z1; ++z) {
            bool keep = (myz == z);
            const short* pz = pSkV + (size_t)z * 4096;
#pragma unroll
            for (int t = 0; t < 4; ++t)
#pragma unroll
                for (int h = 0; h < 2; ++h) {
                    short8 b = loadB(pz, t, h, l);
#pragma unroll
                    for (int k = 0; k < 3; ++k) {
                        short8 a = keep ? Aiv[k][h] : z8;
                        vnD[k][t] = MFMA16(a, b, vnD[k][t]);
                    }
                }
        }
    }

    // ---- state store: ONLY at it==0 (state is dead after last interaction).
    // Packed ushort4 {s,v0,v1,v2} per (node,channel): 16x 8-B stores/lane.
    if (it == 0) {
#pragma unroll
        for (int t = 0; t < 4; ++t)
#pragma unroll
            for (int r = 0; r < 4; ++r) {
                uint2 pk;
                pk.x = cvt2u(snD[t][r], vnD[0][t][r]);
                pk.y = cvt2u(vnD[1][t][r], vnD[2][t][r]);
                *(uint2*)(svp + ((size_t)(i16 + q * 4 + r) * 64 + t * 16 + cl) * 4) = pk;
            }
    }

    // ---- it==0: zero this wave's own agg boundary rows for interaction 1.
    if (it == 0) {
        for (int rr = 0; rr < 16; ++rr) {
            int i = i16 + rr;
            int beg = row_start[i], end = row_start[i + 1];
            bool need = (end == beg) || (end > (((beg >> 4) + 1) << 4));
            if (need) {
                float* as = (float*)agg_s;
                float* av = (float*)agg_v;
                as[(size_t)i * 64 + l] = 0.f;
                av[((size_t)i * 3 + 0) * 64 + l] = 0.f;
                av[((size_t)i * 3 + 1) * 64 + l] = 0.f;
                av[((size_t)i * 3 + 2) * 64 + l] = 0.f;
            }
        }
    }
}

// ---------------------------------------------------------------------------
extern "C" void kernel_launch(void* const* d_in, const int* in_sizes, int n_in,
                              void* d_out, int out_size, void* d_ws, size_t ws_size,
                              hipStream_t stream)
{
    const float* vectors = (const float*)d_in[0];
    const float* embed_s = (const float*)d_in[1];
    const float* Wr      = (const float*)d_in[2];   // [2,8,320]
    const float* Wls     = (const float*)d_in[3];   // [2,64,64]
    const float* Wlv     = (const float*)d_in[4];
    const float* skip_s  = (const float*)d_in[5];   // [10,64,64]
    const float* skip_v  = (const float*)d_in[6];
    const float* pw      = (const float*)d_in[7];   // [2,10,9,64]
    const float* Wps     = (const float*)d_in[8];
    const float* Wpv     = (const float*)d_in[9];
    const float* Wread0  = (const float*)d_in[10];  // [64,1]
    const float* Wr1a    = (const float*)d_in[11];  // [64,16]
    const float* Wr1b    = (const float*)d_in[12];  // [16,1]
    const int* senders   = (const int*)d_in[13];
    const int* receivers = (const int*)d_in[14];
    const int* species   = (const int*)d_in[15];
    float* out = (float*)d_out;

    float* ws = (float*)d_ws;
    float* edata = ws; ws += (size_t)N_EDGES * 16;  // 16 MB (slot-ordered)
    float* agg_s = ws; ws += (size_t)N_NODES * 64;  // 8 MB
    float* agg_v = ws; ws += (size_t)N_NODES * 192; // 24 MB
    unsigned short* svp = (unsigned short*)ws; ws += (size_t)N_NODES * 128; // 16 MB packed {s,v0,v1,v2} bf16
    int* counts    = (int*)ws; ws += N_NODES;
    int* row_start = (int*)ws; ws += N_NODES + 4;
    int* cursor    = (int*)ws; ws += N_NODES;
    int* edge_ids  = (int*)ws; ws += N_EDGES;
    int* srk       = (int*)ws; ws += N_EDGES;
    int* grp_row   = (int*)ws; ws += N_EDGES / 16;
    int* sidx      = (int*)ws; ws += N_NODES;
    int* rank      = (int*)ws; ws += N_NODES;
    int* spec_srt  = (int*)ws; ws += N_NODES;
    int* lrank_arr = (int*)ws; ws += N_NODES;
    int* counts_blk = (int*)ws; ws += 128 * NSPEC;
    int* off_blk    = (int*)ws; ws += 128 * NSPEC;
    short* packW   = (short*)ws;                    // 224 KB

    // species counting sort (sort1 also zeroes CSR counts)
    sort1_kernel<<<N_NODES / 256, 256, 0, stream>>>(
        species, counts_blk, lrank_arr, counts);
    sort2_kernel<<<1, 640, 0, stream>>>(counts_blk, off_blk);
    sort3_kernel<<<N_NODES / 256, 256, 0, stream>>>(
        species, lrank_arr, off_blk, sidx, rank, spec_srt);

    // receiver CSR in sorted space
    hist_kernel<<<N_EDGES / 256, 256, 0, stream>>>(receivers, rank, counts);
    scan_kernel<<<1, 1024, 0, stream>>>(counts, row_start, cursor);
    scatter_kernel<<<N_EDGES / 256, 256, 0, stream>>>(receivers, rank, cursor, edge_ids);

    // edge features + packed sender rank/species + grp_row (one pass)
    edge_pre_kernel<<<N_EDGES / 256, 256, 0, stream>>>(
        vectors, edge_ids, senders, rank, species, row_start, edata, srk, grp_row);

    // merged prep: weight pack + zero boundary agg rows (i0). No init_s.
    prep_kernel<<<2048, 256, 0, stream>>>(
        Wls, Wlv, Wps, Wpv, skip_s, skip_v, packW, row_start, agg_s, agg_v);

    // interaction 0 (gather reads embed table; node fuses read0 + re-zeroing
    // and writes the packed state for interaction 1's gather)
    gather_kernel<1><<<N_EDGES / 32, 64, 0, stream>>>(
        edata, srk, row_start, grp_row, embed_s, svp, Wr, agg_s, agg_v);
    node_mfma_kernel<<<N_NODES / 64, 256, 0, stream>>>(
        agg_s, agg_v, svp, packW, 0, pw, spec_srt,
        row_start, sidx, Wread0, Wr1a, Wr1b, out, 0);

    // interaction 1 (packed bf16 state: ONE 8-B random load per edge/lane)
    gather_kernel<0><<<N_EDGES / 32, 64, 0, stream>>>(
        edata, srk, row_start, grp_row, embed_s, svp, Wr + 2560, agg_s, agg_v);
    node_mfma_kernel<<<N_NODES / 64, 256, 0, stream>>>(
        agg_s, agg_v, svp, packW, 1, pw + 5760, spec_srt,
        row_start, sidx, Wread0, Wr1a, Wr1b, out, 1);
}

// Round 7
// 280.908 us; speedup vs baseline: 1.1892x; 1.0518x over previous
//
#include <hip/hip_runtime.h>
#include <hip/hip_bf16.h>
#include <math.h>

#define N_NODES 32768
#define N_EDGES 262144
#define EPS_C 0.24253562503633297f   // 1/sqrt(17)
#define NSPEC 10

typedef __attribute__((ext_vector_type(8))) short short8;   // 8 bf16
typedef __attribute__((ext_vector_type(4))) float f32x4;    // 4 fp32 acc

#define MFMA16(a, b, c) __builtin_amdgcn_mfma_f32_16x16x32_bf16(a, b, c, 0, 0, 0)

__device__ __forceinline__ short2 cvt2(float a, float b) {
    union { __hip_bfloat162 h; short2 s; } u;
    u.h = __float22bfloat162_rn(make_float2(a, b));
    return u.s;
}
__device__ __forceinline__ unsigned cvt2u(float a, float b) {
    union { __hip_bfloat162 h; unsigned u; } u;
    u.h = __float22bfloat162_rn(make_float2(a, b));
    return u.u;   // lo16 = bf(a), hi16 = bf(b)
}
__device__ __forceinline__ unsigned short f2bf(float a) {
    return (unsigned short)cvt2(a, 0.f).x;
}
__device__ __forceinline__ float bf2f(unsigned short u) {
    return __uint_as_float(((unsigned)u) << 16);
}
__device__ __forceinline__ short8 cvt8(float4 a, float4 b) {
    short2 p0 = cvt2(a.x, a.y), p1 = cvt2(a.z, a.w);
    short2 p2 = cvt2(b.x, b.y), p3 = cvt2(b.z, b.w);
    short8 r;
    r[0] = p0.x; r[1] = p0.y; r[2] = p1.x; r[3] = p1.y;
    r[4] = p2.x; r[5] = p2.y; r[6] = p3.x; r[7] = p3.y;
    return r;
}
__device__ __forceinline__ short8 loadArow(const float* rowp, int h, int q) {
    const float* p = rowp + h * 32 + q * 8;
    return cvt8(*(const float4*)p, *(const float4*)(p + 4));
}
__device__ __forceinline__ short8 loadB(const short* P, int t, int h, int l) {
    return *(const short8*)(P + (((t * 2 + h) * 64 + l) << 3));
}

// packed state svp[node][64 ch][4] = ushort4 {s, v0, v1, v2} (bf16 bits).
__device__ __forceinline__ short8 unpack_s(const unsigned short* prow, int ch0) {
    const uint4* p = (const uint4*)(prow + ch0 * 4);
    uint4 u0 = p[0], u1 = p[1], u2 = p[2], u3 = p[3];
    short8 r;
    r[0] = (short)(u0.x & 0xffff); r[1] = (short)(u0.z & 0xffff);
    r[2] = (short)(u1.x & 0xffff); r[3] = (short)(u1.z & 0xffff);
    r[4] = (short)(u2.x & 0xffff); r[5] = (short)(u2.z & 0xffff);
    r[6] = (short)(u3.x & 0xffff); r[7] = (short)(u3.z & 0xffff);
    return r;
}
__device__ __forceinline__ void unpack_v(const unsigned short* prow, int ch0,
                                         short8 (&Aiv)[3][2], int h) {
    const uint4* p = (const uint4*)(prow + ch0 * 4);
    uint4 u0 = p[0], u1 = p[1], u2 = p[2], u3 = p[3];
    Aiv[0][h][0] = (short)(u0.x >> 16); Aiv[0][h][1] = (short)(u0.z >> 16);
    Aiv[0][h][2] = (short)(u1.x >> 16); Aiv[0][h][3] = (short)(u1.z >> 16);
    Aiv[0][h][4] = (short)(u2.x >> 16); Aiv[0][h][5] = (short)(u2.z >> 16);
    Aiv[0][h][6] = (short)(u3.x >> 16); Aiv[0][h][7] = (short)(u3.z >> 16);
    Aiv[1][h][0] = (short)(u0.y & 0xffff); Aiv[1][h][1] = (short)(u0.w & 0xffff);
    Aiv[1][h][2] = (short)(u1.y & 0xffff); Aiv[1][h][3] = (short)(u1.w & 0xffff);
    Aiv[1][h][4] = (short)(u2.y & 0xffff); Aiv[1][h][5] = (short)(u2.w & 0xffff);
    Aiv[1][h][6] = (short)(u3.y & 0xffff); Aiv[1][h][7] = (short)(u3.w & 0xffff);
    Aiv[2][h][0] = (short)(u0.y >> 16); Aiv[2][h][1] = (short)(u0.w >> 16);
    Aiv[2][h][2] = (short)(u1.y >> 16); Aiv[2][h][3] = (short)(u1.w >> 16);
    Aiv[2][h][4] = (short)(u2.y >> 16); Aiv[2][h][5] = (short)(u2.w >> 16);
    Aiv[2][h][6] = (short)(u3.y >> 16); Aiv[2][h][7] = (short)(u3.w >> 16);
}

// ---------------------------------------------------------------------------
// Species counting sort — contention-free, deterministic. sort1 also zeroes
// the receiver-CSR counts array.
// ---------------------------------------------------------------------------
__global__ __launch_bounds__(256) void sort1_kernel(
    const int* __restrict__ species, int* __restrict__ counts_blk,
    int* __restrict__ lrank_arr, int* __restrict__ counts)
{
    __shared__ int wcnt[4][16];
    int n = blockIdx.x * 256 + threadIdx.x;
    counts[n] = 0;
    int sp = species[n];
    int lane = threadIdx.x & 63, wv = threadIdx.x >> 6;
    unsigned long long ltmask = (1ull << lane) - 1;
    int lrank_w = 0;
#pragma unroll
    for (int z = 0; z < NSPEC; ++z) {
        unsigned long long m = __ballot(sp == z);
        if (sp == z) lrank_w = __popcll(m & ltmask);
        if (lane == 0) wcnt[wv][z] = __popcll(m);
    }
    __syncthreads();
    int off = 0;
    for (int w = 0; w < wv; ++w) off += wcnt[w][sp];
    lrank_arr[n] = lrank_w + off;
    if (threadIdx.x < NSPEC)
        counts_blk[blockIdx.x * NSPEC + threadIdx.x] =
            wcnt[0][threadIdx.x] + wcnt[1][threadIdx.x] +
            wcnt[2][threadIdx.x] + wcnt[3][threadIdx.x];
}

// parallel block-offset scan: wave z shuffle-scans its 128 block counts
__global__ __launch_bounds__(640) void sort2_kernel(
    const int* __restrict__ counts_blk, int* __restrict__ off_blk)
{
    __shared__ int totals[16];
    int wv = threadIdx.x >> 6;        // 0..9 == species z
    int lane = threadIdx.x & 63;
    int c0 = counts_blk[lane * NSPEC + wv];
    int c1 = counts_blk[(64 + lane) * NSPEC + wv];
    int s0 = c0;
#pragma unroll
    for (int off = 1; off < 64; off <<= 1) {
        int y = __shfl_up(s0, off);
        if (lane >= off) s0 += y;
    }
    int tot0 = __shfl(s0, 63);
    int s1 = c1;
#pragma unroll
    for (int off = 1; off < 64; off <<= 1) {
        int y = __shfl_up(s1, off);
        if (lane >= off) s1 += y;
    }
    s1 += tot0;
    if (lane == 63) totals[wv] = s1;
    __syncthreads();
    int base = 0;
    for (int q = 0; q < wv; ++q) base += totals[q];
    off_blk[lane * NSPEC + wv] = base + s0 - c0;
    off_blk[(64 + lane) * NSPEC + wv] = base + s1 - c1;
}

__global__ __launch_bounds__(256) void sort3_kernel(
    const int* __restrict__ species, const int* __restrict__ lrank_arr,
    const int* __restrict__ off_blk,
    int* __restrict__ sidx, int* __restrict__ rank, int* __restrict__ spec_srt)
{
    int n = blockIdx.x * 256 + threadIdx.x;
    int sp = species[n];
    int slot = off_blk[blockIdx.x * NSPEC + sp] + lrank_arr[n];
    sidx[slot] = n;
    rank[n] = slot;
    spec_srt[slot] = sp;
}

// ---------------------------------------------------------------------------
// Receiver CSR in SORTED space
// ---------------------------------------------------------------------------
__global__ __launch_bounds__(256) void hist_kernel(
    const int* __restrict__ receivers, const int* __restrict__ rank,
    int* __restrict__ counts)
{
    int e = blockIdx.x * 256 + threadIdx.x;
    atomicAdd(&counts[rank[receivers[e]]], 1);
}

__global__ __launch_bounds__(1024) void scan_kernel(
    const int* __restrict__ counts, int* __restrict__ row_start, int* __restrict__ cursor)
{
    __shared__ int wave_tot[16];
    int tid = threadIdx.x;
    int c[32];
    int sum = 0;
#pragma unroll
    for (int i = 0; i < 32; ++i) { c[i] = counts[tid * 32 + i]; sum += c[i]; }
    int lane = tid & 63, wv = tid >> 6;
    int x = sum;
#pragma unroll
    for (int off = 1; off < 64; off <<= 1) {
        int y = __shfl_up(x, off);
        if (lane >= off) x += y;
    }
    if (lane == 63) wave_tot[wv] = x;
    __syncthreads();
    if (wv == 0 && lane < 16) {
        int t = wave_tot[lane];
#pragma unroll
        for (int off = 1; off < 16; off <<= 1) {
            int y = __shfl_up(t, off);
            if (lane >= off) t += y;
        }
        wave_tot[lane] = t;
    }
    __syncthreads();
    int excl = x - sum + (wv ? wave_tot[wv - 1] : 0);
    int run = excl;
#pragma unroll
    for (int i = 0; i < 32; ++i) {
        row_start[tid * 32 + i] = run;
        cursor[tid * 32 + i] = run;
        run += c[i];
    }
    if (tid == 1023) row_start[32768] = run;
}

__global__ __launch_bounds__(256) void scatter_kernel(
    const int* __restrict__ receivers, const int* __restrict__ rank,
    int* __restrict__ cursor, int* __restrict__ edge_ids)
{
    int e = blockIdx.x * 256 + threadIdx.x;
    int slot = atomicAdd(&cursor[rank[receivers[e]]], 1);
    edge_ids[slot] = e;
}

// ---------------------------------------------------------------------------
// Edge precompute in slot order + fused sender-rank/species stream + grp_row.
// srk[p] = rank | (species << 16)
// Bessel sines via Chebyshev recurrence: sin((n+1)x) = 2cos(x)sin(nx)
// - sin((n-1)x). 1 sincosf + 7 fma-pairs replaces 8 sinf (~3x VALU cut;
// deviation ~1e-6 rel, 3 orders below the pipeline's bf16 rounding).
// Pad d[12..15] is never read by gather -> not stored (-4MB writes).
// ---------------------------------------------------------------------------
__global__ __launch_bounds__(256) void edge_pre_kernel(
    const float* __restrict__ vectors, const int* __restrict__ edge_ids,
    const int* __restrict__ senders, const int* __restrict__ rank,
    const int* __restrict__ species, const int* __restrict__ row_start,
    float* __restrict__ edata, int* __restrict__ srk, int* __restrict__ grp_row)
{
    int p = blockIdx.x * 256 + threadIdx.x;
    int e = edge_ids[p];
    int snd = senders[e];
    srk[p] = rank[snd] | (species[snd] << 16);
    float x = vectors[e * 3 + 0], y = vectors[e * 3 + 1], z = vectors[e * 3 + 2];
    float r2 = x * x + y * y + z * z + 1e-12f;
    float r = sqrtf(r2);
    float inv = 1.0f / r;
    float* d = edata + (size_t)p * 16;
    *(float4*)d = make_float4(x * inv, y * inv, z * inv, 0.0f);
    float rc = fmaxf(r, 1e-6f);
    float r6 = r2 * r2 * r2;
    float r7 = r6 * r;
    float r8 = r6 * r2;
    float env = (r < 1.0f) ? (1.0f - 28.0f * r6 + 48.0f * r7 - 21.0f * r8) : 0.0f;
    float sc = 1.41421356237309515f * env / rc;
    float xr = 3.14159265358979323846f * rc;
    float s1, c1;
    sincosf(xr, &s1, &c1);
    float tc = 2.0f * c1;
    float s2 = tc * s1;              // s0 = sin(0) = 0
    float s3 = tc * s2 - s1;
    float s4 = tc * s3 - s2;
    float s5 = tc * s4 - s3;
    float s6 = tc * s5 - s4;
    float s7 = tc * s6 - s5;
    float s8 = tc * s7 - s6;
    *(float4*)(d + 4) = make_float4(sc * s1, sc * s2, sc * s3, sc * s4);
    *(float4*)(d + 8) = make_float4(sc * s5, sc * s6, sc * s7, sc * s8);

    if (p < N_EDGES / 16) {
        int target = p * 16;
        int lo = 0, hi = N_NODES - 1;
        while (lo < hi) {
            int mid = (lo + hi + 1) >> 1;
            if (row_start[mid] <= target) lo = mid; else hi = mid - 1;
        }
        grp_row[p] = lo;
    }
}

// ---------------------------------------------------------------------------
// Merged prep: weight pack (blocks<448) + zero_bnd for interaction 0.
// ---------------------------------------------------------------------------
__global__ __launch_bounds__(256) void prep_kernel(
    const float* __restrict__ Wls, const float* __restrict__ Wlv,
    const float* __restrict__ Wps, const float* __restrict__ Wpv,
    const float* __restrict__ skip_s, const float* __restrict__ skip_v,
    short* __restrict__ packW,
    const int* __restrict__ row_start,
    float* __restrict__ agg_s, float* __restrict__ agg_v)
{
    int idx = blockIdx.x * 256 + threadIdx.x;
    if (blockIdx.x < 448 && idx < 28 * 4096) {
        int m = idx >> 12, e = idx & 4095;
        int t = e >> 10, h = (e >> 9) & 1, l = (e >> 3) & 63, j = e & 7;
        int fi = h * 32 + ((l >> 4) << 3) + j;
        int fo = t * 16 + (l & 15);
        const float* src;
        if      (m < 2)  src = Wls    + m * 4096;
        else if (m < 4)  src = Wlv    + (m - 2) * 4096;
        else if (m < 6)  src = Wps    + (m - 4) * 4096;
        else if (m < 8)  src = Wpv    + (m - 6) * 4096;
        else if (m < 18) src = skip_s + (m - 8) * 4096;
        else             src = skip_v + (m - 18) * 4096;
        packW[idx] = cvt2(src[fi * 64 + fo], 0.f).x;
    }
    const int wid = threadIdx.x >> 6;
    const int f = threadIdx.x & 63;
    const int base = (blockIdx.x * 4 + wid) * 4;
#pragma unroll
    for (int t = 0; t < 4; ++t) {
        int i = base + t;
        int beg = row_start[i], end = row_start[i + 1];
        bool need = (end == beg) || (end > (((beg >> 4) + 1) << 4));
        if (need) {
            agg_s[(size_t)i * 64 + f] = 0.f;
            agg_v[((size_t)i * 3 + 0) * 64 + f] = 0.f;
            agg_v[((size_t)i * 3 + 1) * 64 + f] = 0.f;
            agg_v[((size_t)i * 3 + 2) * 64 + f] = 0.f;
        }
    }
}

// ---------------------------------------------------------------------------
// Dual-chain edge-balanced gather, 1 wave/block.
// DO NOT use multi-wave workgroups here: tried 4-wave (r1) and 2-wave (r3);
// both regress badly (spills visible as +42MB WRITE_SIZE, occupancy flat).
// r7: pipeline deepened — state staged depth-3 (issued at iter k for edge
// k+3; srk held 4 ahead), edata prefetched 1 iter ahead (sequential
// addresses, L2-resident; removes in-iteration latency). Tail issues are
// compile-time-guarded (full unroll), so no clamps needed and no wasted
// tail loads. Consume math order unchanged -> bit-exact vs r6.
// ---------------------------------------------------------------------------
template<int VZERO>
__global__ __launch_bounds__(64, 4) void gather_kernel(
    const float* __restrict__ edata, const int* __restrict__ srk,
    const int* __restrict__ row_start, const int* __restrict__ grp_row,
    const float* __restrict__ embed_s,
    const unsigned short* __restrict__ svp,
    const float* __restrict__ Wr_i,
    float* __restrict__ agg_s, float* __restrict__ agg_v)
{
    const int f = threadIdx.x & 63;
    const int w = blockIdx.x;
    const int pA0 = w * 32;
    const int pB0 = pA0 + 16;

    float wr[5][8];
#pragma unroll
    for (int j = 0; j < 8; ++j)
#pragma unroll
        for (int p = 0; p < 5; ++p)
            wr[p][j] = (VZERO && (p == 1 || p == 3 || p == 4))
                       ? 0.f : Wr_i[j * 320 + p * 64 + f];

    int rA = grp_row[2 * w], rB = grp_row[2 * w + 1];
    int begA = row_start[rA], endA = row_start[rA + 1];
    int begB = row_start[rB], endB = row_start[rB + 1];
    float aA0 = 0.f, aA1 = 0.f, aA2 = 0.f, aA3 = 0.f;
    float aB0 = 0.f, aB1 = 0.f, aB2 = 0.f, aB3 = 0.f;

    // state pipeline depth-3: stage0..2 = edges k..k+2; stage3 issued for
    // edge k+3 each iter (while k+3 <= 15). svH* holds srk for edge k+3.
    int svHA = srk[pA0 + 3], svHB = srk[pB0 + 3];
    uint2 pa0 = {0,0}, pa1 = {0,0}, pa2 = {0,0};
    uint2 pb0 = {0,0}, pb1 = {0,0}, pb2 = {0,0};
    float fa0 = 0.f, fa1 = 0.f, fa2 = 0.f, fb0 = 0.f, fb1 = 0.f, fb2 = 0.f;
    {
        int sA0 = srk[pA0], sA1 = srk[pA0 + 1], sA2 = srk[pA0 + 2];
        int sB0 = srk[pB0], sB1 = srk[pB0 + 1], sB2 = srk[pB0 + 2];
        if (VZERO) {
            fa0 = embed_s[(sA0 >> 16) * 64 + f];
            fa1 = embed_s[(sA1 >> 16) * 64 + f];
            fa2 = embed_s[(sA2 >> 16) * 64 + f];
            fb0 = embed_s[(sB0 >> 16) * 64 + f];
            fb1 = embed_s[(sB1 >> 16) * 64 + f];
            fb2 = embed_s[(sB2 >> 16) * 64 + f];
        } else {
            pa0 = *(const uint2*)(svp + (((size_t)(sA0 & 0xFFFF)) * 64 + f) * 4);
            pa1 = *(const uint2*)(svp + (((size_t)(sA1 & 0xFFFF)) * 64 + f) * 4);
            pa2 = *(const uint2*)(svp + (((size_t)(sA2 & 0xFFFF)) * 64 + f) * 4);
            pb0 = *(const uint2*)(svp + (((size_t)(sB0 & 0xFFFF)) * 64 + f) * 4);
            pb1 = *(const uint2*)(svp + (((size_t)(sB1 & 0xFFFF)) * 64 + f) * 4);
            pb2 = *(const uint2*)(svp + (((size_t)(sB2 & 0xFFFF)) * 64 + f) * 4);
        }
    }
    // edata regs for edge k (prologue loads k=0)
    const float* dA0p = edata + (size_t)pA0 * 16;
    const float* dB0p = edata + (size_t)pB0 * 16;
    float4 yA = *(const float4*)dA0p;
    float4 qA0 = *(const float4*)(dA0p + 4);
    float4 qA1 = *(const float4*)(dA0p + 8);
    float4 yB = *(const float4*)dB0p;
    float4 qB0 = *(const float4*)(dB0p + 4);
    float4 qB1 = *(const float4*)(dB0p + 8);

#pragma unroll
    for (int k = 0; k < 16; ++k) {
        const int pA = pA0 + k, pB = pB0 + k;

        // srk prefetch for edge k+4 (used next iter; only needed while
        // (k+1)+3 <= 15). Compile-time guard under full unroll.
        int svNA = svHA, svNB = svHB;
        if (k < 12) {
            svNA = srk[pA + 4];
            svNB = srk[pB + 4];
        }

        // issue stage-3 state loads (edge k+3) — raw bits, no conversion
        uint2 pa3 = {0, 0}, pb3 = {0, 0};
        float fa3 = 0.f, fb3 = 0.f;
        if (k < 13) {
            if (VZERO) {
                fa3 = embed_s[(svHA >> 16) * 64 + f];
                fb3 = embed_s[(svHB >> 16) * 64 + f];
            } else {
                pa3 = *(const uint2*)(svp + (((size_t)(svHA & 0xFFFF)) * 64 + f) * 4);
                pb3 = *(const uint2*)(svp + (((size_t)(svHB & 0xFFFF)) * 64 + f) * 4);
            }
        }

        // edata prefetch for edge k+1 (sequential, compile-time guarded)
        float4 yAn = yA, qA0n = qA0, qA1n = qA1;
        float4 yBn = yB, qB0n = qB0, qB1n = qB1;
        if (k < 15) {
            const float* dAn = edata + (size_t)(pA + 1) * 16;
            const float* dBn = edata + (size_t)(pB + 1) * 16;
            yAn  = *(const float4*)dAn;
            qA0n = *(const float4*)(dAn + 4);
            qA1n = *(const float4*)(dAn + 8);
            yBn  = *(const float4*)dBn;
            qB0n = *(const float4*)(dBn + 4);
            qB1n = *(const float4*)(dBn + 8);
        }

        float rbA[8] = {qA0.x, qA0.y, qA0.z, qA0.w, qA1.x, qA1.y, qA1.z, qA1.w};
        float rbB[8] = {qB0.x, qB0.y, qB0.z, qB0.w, qB1.x, qB1.y, qB1.z, qB1.w};
        float wA0 = 0.f, wA1 = 0.f, wA2 = 0.f, wA3 = 0.f, wA4 = 0.f;
        float wB0 = 0.f, wB1 = 0.f, wB2 = 0.f, wB3 = 0.f, wB4 = 0.f;
#pragma unroll
        for (int j = 0; j < 8; ++j) {
            wA0 = fmaf(rbA[j], wr[0][j], wA0);  wB0 = fmaf(rbB[j], wr[0][j], wB0);
            if (!VZERO) { wA1 = fmaf(rbA[j], wr[1][j], wA1);  wB1 = fmaf(rbB[j], wr[1][j], wB1); }
            wA2 = fmaf(rbA[j], wr[2][j], wA2);  wB2 = fmaf(rbB[j], wr[2][j], wB2);
            if (!VZERO) { wA3 = fmaf(rbA[j], wr[3][j], wA3);  wB3 = fmaf(rbB[j], wr[3][j], wB3); }
            if (!VZERO) { wA4 = fmaf(rbA[j], wr[4][j], wA4);  wB4 = fmaf(rbB[j], wr[4][j], wB4); }
        }

        // consume stage0 — conversion (exact shift/and) happens HERE; the
        // waits for these loads land 3 iterations after issue.
        if (VZERO) {
            float ssA = fa0, ssB = fb0;
            aA0 += wA0 * ssA;
            float wsA = wA2 * ssA;
            aA1 += wsA * yA.x; aA2 += wsA * yA.y; aA3 += wsA * yA.z;
            aB0 += wB0 * ssB;
            float wsB = wB2 * ssB;
            aB1 += wsB * yB.x; aB2 += wsB * yB.y; aB3 += wsB * yB.z;
        } else {
            float ssA = __uint_as_float(pa0.x << 16);
            float va0 = __uint_as_float(pa0.x & 0xffff0000u);
            float va1 = __uint_as_float(pa0.y << 16);
            float va2 = __uint_as_float(pa0.y & 0xffff0000u);
            float ssB = __uint_as_float(pb0.x << 16);
            float vb0 = __uint_as_float(pb0.x & 0xffff0000u);
            float vb1 = __uint_as_float(pb0.y << 16);
            float vb2 = __uint_as_float(pb0.y & 0xffff0000u);
            float dotA = va0 * yA.x + va1 * yA.y + va2 * yA.z;
            aA0 += wA0 * ssA + wA1 * dotA;
            float cA0 = va1 * yA.z - va2 * yA.y;
            float cA1 = va2 * yA.x - va0 * yA.z;
            float cA2 = va0 * yA.y - va1 * yA.x;
            float wsA = wA2 * ssA;
            aA1 += wsA * yA.x + wA3 * va0 + wA4 * cA0;
            aA2 += wsA * yA.y + wA3 * va1 + wA4 * cA1;
            aA3 += wsA * yA.z + wA3 * va2 + wA4 * cA2;
            float dotB = vb0 * yB.x + vb1 * yB.y + vb2 * yB.z;
            aB0 += wB0 * ssB + wB1 * dotB;
            float cB0 = vb1 * yB.z - vb2 * yB.y;
            float cB1 = vb2 * yB.x - vb0 * yB.z;
            float cB2 = vb0 * yB.y - vb1 * yB.x;
            float wsB = wB2 * ssB;
            aB1 += wsB * yB.x + wB3 * vb0 + wB4 * cB0;
            aB2 += wsB * yB.y + wB3 * vb1 + wB4 * cB1;
            aB3 += wsB * yB.z + wB3 * vb2 + wB4 * cB2;
        }

        if (pA + 1 == endA || k == 15) {
            bool interior = (begA >= pA0) && (endA <= pA0 + 16);
            if (interior) {
                agg_s[(size_t)rA * 64 + f] = aA0;
                agg_v[((size_t)rA * 3 + 0) * 64 + f] = aA1;
                agg_v[((size_t)rA * 3 + 1) * 64 + f] = aA2;
                agg_v[((size_t)rA * 3 + 2) * 64 + f] = aA3;
            } else {
                unsafeAtomicAdd(&agg_s[(size_t)rA * 64 + f], aA0);
                unsafeAtomicAdd(&agg_v[((size_t)rA * 3 + 0) * 64 + f], aA1);
                unsafeAtomicAdd(&agg_v[((size_t)rA * 3 + 1) * 64 + f], aA2);
                unsafeAtomicAdd(&agg_v[((size_t)rA * 3 + 2) * 64 + f], aA3);
            }
            aA0 = aA1 = aA2 = aA3 = 0.f;
            if (pA + 1 == endA && k < 15) {
                begA = endA; ++rA; endA = row_start[rA + 1];
                while (endA == begA) { ++rA; endA = row_start[rA + 1]; }
            }
        }
        if (pB + 1 == endB || k == 15) {
            bool interior = (begB >= pB0) && (endB <= pB0 + 16);
            if (interior) {
                agg_s[(size_t)rB * 64 + f] = aB0;
                agg_v[((size_t)rB * 3 + 0) * 64 + f] = aB1;
                agg_v[((size_t)rB * 3 + 1) * 64 + f] = aB2;
                agg_v[((size_t)rB * 3 + 2) * 64 + f] = aB3;
            } else {
                unsafeAtomicAdd(&agg_s[(size_t)rB * 64 + f], aB0);
                unsafeAtomicAdd(&agg_v[((size_t)rB * 3 + 0) * 64 + f], aB1);
                unsafeAtomicAdd(&agg_v[((size_t)rB * 3 + 1) * 64 + f], aB2);
                unsafeAtomicAdd(&agg_v[((size_t)rB * 3 + 2) * 64 + f], aB3);
            }
            aB0 = aB1 = aB2 = aB3 = 0.f;
            if (pB + 1 == endB && k < 15) {
                begB = endB; ++rB; endB = row_start[rB + 1];
                while (endB == begB) { ++rB; endB = row_start[rB + 1]; }
            }
        }

        // rotate stages (SSA renames under full unroll — no movs, no waits)
        pa0 = pa1; pa1 = pa2; pa2 = pa3;
        pb0 = pb1; pb1 = pb2; pb2 = pb3;
        fa0 = fa1; fa1 = fa2; fa2 = fa3;
        fb0 = fb1; fb1 = fb2; fb2 = fb3;
        svHA = svNA; svHB = svNB;
        yA = yAn; qA0 = qA0n; qA1 = qA1n;
        yB = yBn; qB0 = qB0n; qB1 = qB1n;
    }
}

// ---------------------------------------------------------------------------
// MFMA node kernel. State lives ONLY in packed svp[node][ch]=ushort4
// {s,v0,v1,v2} (bf16 bits, RNE). it==0 writes svp; it==1 reads svp for skip
// fragments and writes NOTHING (state dead after last interaction).
// ---------------------------------------------------------------------------
__global__ __launch_bounds__(256) void node_mfma_kernel(
    const float* __restrict__ agg_s, const float* __restrict__ agg_v,
    unsigned short* svp,
    const short* __restrict__ packW, int it,
    const float* __restrict__ pw_i,
    const int* __restrict__ spec_srt,
    const int* __restrict__ row_start, const int* __restrict__ sidx,
    const float* __restrict__ Wread0, const float* __restrict__ Wr1a,
    const float* __restrict__ Wr1b,
    float* __restrict__ out,
    int has_skip)
{
    const int l = threadIdx.x & 63;
    const int wid = threadIdx.x >> 6;
    const int cl = l & 15;
    const int q = l >> 4;
    const int i16 = (blockIdx.x * 4 + wid) * 16;
    __shared__ float xls_all[4][16 * 65];
    float* xls = xls_all[wid];

    const short* pWls = packW + (size_t)(0 + it) * 4096;
    const short* pWlv = packW + (size_t)(2 + it) * 4096;
    const short* pWps = packW + (size_t)(4 + it) * 4096;
    const short* pWpv = packW + (size_t)(6 + it) * 4096;
    const short* pSkS = packW + (size_t)8 * 4096;
    const short* pSkV = packW + (size_t)18 * 4096;
    const short8 z8 = {0, 0, 0, 0, 0, 0, 0, 0};

    const float* ars = agg_s + (size_t)(i16 + cl) * 64;
    short8 As[2] = { loadArow(ars, 0, q), loadArow(ars, 1, q) };
    short8 Av[3][2];
#pragma unroll
    for (int k = 0; k < 3; ++k) {
        const float* r = agg_v + ((size_t)(i16 + cl) * 3 + k) * 64;
        Av[k][0] = loadArow(r, 0, q);
        Av[k][1] = loadArow(r, 1, q);
    }

    f32x4 sD[4];
#pragma unroll
    for (int t = 0; t < 4; ++t) {
        f32x4 acc = {0.f, 0.f, 0.f, 0.f};
        acc = MFMA16(As[0], loadB(pWls, t, 0, l), acc);
        acc = MFMA16(As[1], loadB(pWls, t, 1, l), acc);
        sD[t] = acc;
    }

    f32x4 vD[3][4];
#pragma unroll
    for (int k = 0; k < 3; ++k)
#pragma unroll
        for (int t = 0; t < 4; ++t) vD[k][t] = (f32x4){0.f, 0.f, 0.f, 0.f};
#pragma unroll
    for (int t = 0; t < 4; ++t)
#pragma unroll
        for (int h = 0; h < 2; ++h) {
            short8 b = loadB(pWlv, t, h, l);
#pragma unroll
            for (int k = 0; k < 3; ++k) vD[k][t] = MFMA16(Av[k][h], b, vD[k][t]);
        }

    int z0 = spec_srt[i16], z1 = spec_srt[i16 + 15];
    float psD[4][4], pvsD[4][4];
    if (z0 == z1) {
        const float* pb = pw_i + z0 * 576 + cl;
        float pc[9][4];
#pragma unroll
        for (int c = 0; c < 9; ++c)
#pragma unroll
            for (int t = 0; t < 4; ++t) pc[c][t] = pb[c * 64 + t * 16];
#pragma unroll
        for (int t = 0; t < 4; ++t)
#pragma unroll
            for (int r = 0; r < 4; ++r) {
                float x = sD[t][r] * EPS_C;
                float w0 = vD[0][t][r] * EPS_C;
                float w1 = vD[1][t][r] * EPS_C;
                float w2 = vD[2][t][r] * EPS_C;
                vD[0][t][r] = w0; vD[1][t][r] = w1; vD[2][t][r] = w2;
                float vv = w0 * w0 + w1 * w1 + w2 * w2;
                float x2 = x * x;
                psD[t][r] = pc[0][t] * x + pc[1][t] * x2 + pc[2][t] * vv
                          + pc[3][t] * x2 * x + pc[4][t] * x * vv;
                pvsD[t][r] = pc[5][t] + pc[6][t] * x + pc[7][t] * x2 + pc[8][t] * vv;
            }
    } else {
#pragma unroll
        for (int r = 0; r < 4; ++r) {
            int z = spec_srt[i16 + q * 4 + r];
            const float* pb = pw_i + z * 576 + cl;
#pragma unroll
            for (int t = 0; t < 4; ++t) {
                float p0 = pb[t*16], p1 = pb[64+t*16], p2 = pb[128+t*16];
                float p3 = pb[192+t*16], p4 = pb[256+t*16], p5 = pb[320+t*16];
                float p6 = pb[384+t*16], p7 = pb[448+t*16], p8 = pb[512+t*16];
                float x = sD[t][r] * EPS_C;
                float w0 = vD[0][t][r] * EPS_C;
                float w1 = vD[1][t][r] * EPS_C;
                float w2 = vD[2][t][r] * EPS_C;
                vD[0][t][r] = w0; vD[1][t][r] = w1; vD[2][t][r] = w2;
                float vv = w0 * w0 + w1 * w1 + w2 * w2;
                float x2 = x * x;
                psD[t][r] = p0 * x + p1 * x2 + p2 * vv + p3 * x2 * x + p4 * x * vv;
                pvsD[t][r] = p5 + p6 * x + p7 * x2 + p8 * vv;
            }
        }
    }

#pragma unroll
    for (int t = 0; t < 4; ++t)
#pragma unroll
        for (int r = 0; r < 4; ++r)
            xls[(q * 4 + r) * 65 + t * 16 + cl] = psD[t][r];
    short8 psA[2];
#pragma unroll
    for (int h = 0; h < 2; ++h) {
        const float* rp = xls + cl * 65 + h * 32 + q * 8;
        float t0 = rp[0], t1 = rp[1], t2 = rp[2], t3 = rp[3];
        float t4 = rp[4], t5 = rp[5], t6 = rp[6], t7 = rp[7];
        psA[h] = cvt8(make_float4(t0, t1, t2, t3), make_float4(t4, t5, t6, t7));
    }

    f32x4 snD[4];
#pragma unroll
    for (int t = 0; t < 4; ++t) {
        f32x4 acc = {0.f, 0.f, 0.f, 0.f};
        acc = MFMA16(psA[0], loadB(pWps, t, 0, l), acc);
        acc = MFMA16(psA[1], loadB(pWps, t, 1, l), acc);
        snD[t] = acc;
    }
    if (has_skip) {
        const unsigned short* prow = svp + (size_t)(i16 + cl) * 256;
        short8 Ai0 = unpack_s(prow, q * 8);
        short8 Ai1 = unpack_s(prow, 32 + q * 8);
        int myz = spec_srt[i16 + cl];
        for (int z = z0; z <= z1; ++z) {
            bool keep = (myz == z);
            short8 m0 = keep ? Ai0 : z8;
            short8 m1 = keep ? Ai1 : z8;
            const short* pz = pSkS + (size_t)z * 4096;
#pragma unroll
            for (int t = 0; t < 4; ++t) {
                snD[t] = MFMA16(m0, loadB(pz, t, 0, l), snD[t]);
                snD[t] = MFMA16(m1, loadB(pz, t, 1, l), snD[t]);
            }
        }
    }

    // ---- fused readout (pre-rounded fp32 registers)
    if (it == 0) {
        float w0c[4];
#pragma unroll
        for (int t = 0; t < 4; ++t) w0c[t] = Wread0[t * 16 + cl];
#pragma unroll
        for (int r = 0; r < 4; ++r) {
            float a = snD[0][r] * w0c[0] + snD[1][r] * w0c[1]
                    + snD[2][r] * w0c[2] + snD[3][r] * w0c[3];
            a += __shfl_down(a, 8);
            a += __shfl_down(a, 4);
            a += __shfl_down(a, 2);
            a += __shfl_down(a, 1);
            if (cl == 0) out[(size_t)sidx[i16 + q * 4 + r] * 2 + 0] = a;
        }
    } else {
#pragma unroll
        for (int t = 0; t < 4; ++t)
#pragma unroll
            for (int r = 0; r < 4; ++r)
                xls[(q * 4 + r) * 65 + t * 16 + cl] = snD[t][r];
        float acc4[4] = {0.f, 0.f, 0.f, 0.f};
        for (int g = 0; g < 64; ++g) {
            float wa = Wr1a[g * 16 + cl];
#pragma unroll
            for (int j = 0; j < 4; ++j)
                acc4[j] = fmaf(xls[(q + 4 * j) * 65 + g], wa, acc4[j]);
        }
        float wb = Wr1b[cl];
#pragma unroll
        for (int j = 0; j < 4; ++j) {
            float av = acc4[j];
            float rr = (av / (1.f + expf(-av))) * wb;
            rr += __shfl_down(rr, 8);
            rr += __shfl_down(rr, 4);
            rr += __shfl_down(rr, 2);
            rr += __shfl_down(rr, 1);
            if (cl == 0) out[(size_t)sidx[i16 + q + 4 * j] * 2 + 1] = rr;
        }
    }

    short8 pvA[3][2];
#pragma unroll
    for (int k = 0; k < 3; ++k) {
#pragma unroll
        for (int t = 0; t < 4; ++t)
#pragma unroll
            for (int r = 0; r < 4; ++r)
                xls[(q * 4 + r) * 65 + t * 16 + cl] = pvsD[t][r] * vD[k][t][r];
#pragma unroll
        for (int h = 0; h < 2; ++h) {
            const float* rp = xls + cl * 65 + h * 32 + q * 8;
            float t0 = rp[0], t1 = rp[1], t2 = rp[2], t3 = rp[3];
            float t4 = rp[4], t5 = rp[5], t6 = rp[6], t7 = rp[7];
            pvA[k][h] = cvt8(make_float4(t0, t1, t2, t3), make_float4(t4, t5, t6, t7));
        }
    }

    f32x4 vnD[3][4];
#pragma unroll
    for (int k = 0; k < 3; ++k)
#pragma unroll
        for (int t = 0; t < 4; ++t) vnD[k][t] = (f32x4){0.f, 0.f, 0.f, 0.f};
#pragma unroll
    for (int t = 0; t < 4; ++t)
#pragma unroll
        for (int h = 0; h < 2; ++h) {
            short8 b = loadB(pWpv, t, h, l);
#pragma unroll
            for (int k = 0; k < 3; ++k) vnD[k][t] = MFMA16(pvA[k][h], b, vnD[k][t]);
        }
    if (has_skip) {
        const unsigned short* prow = svp + (size_t)(i16 + cl) * 256;
        short8 Aiv[3][2];
        unpack_v(prow, q * 8, Aiv, 0);
        unpack_v(prow, 32 + q * 8, Aiv, 1);
        int myz = spec_srt[i16 + cl];
        for (int z = z0; z <= z1; ++z) {
            bool keep = (myz == z);
            const short* pz = pSkV + (size_t)z * 4096;
#pragma unroll
            for (int t = 0; t < 4; ++t)
#pragma unroll
                for (int h = 0; h < 2; ++h) {
                    short8 b = loadB(pz, t, h, l);
#pragma unroll
                    for (int k = 0; k < 3; ++k) {
                        short8 a = keep ? Aiv[k][h] : z8;
                        vnD[k][t] = MFMA16(a, b, vnD[k][t]);
                    }
                }
        }
    }

    // ---- state store: ONLY at it==0 (state dead after last interaction).
    if (it == 0) {
#pragma unroll
        for (int t = 0; t < 4; ++t)
#pragma unroll
            for (int r = 0; r < 4; ++r) {
                uint2 pk;
                pk.x = cvt2u(snD[t][r], vnD[0][t][r]);
                pk.y = cvt2u(vnD[1][t][r], vnD[2][t][r]);
                *(uint2*)(svp + ((size_t)(i16 + q * 4 + r) * 64 + t * 16 + cl) * 4) = pk;
            }
    }

    // ---- it==0: zero this wave's own agg boundary rows for interaction 1.
    if (it == 0) {
        for (int rr = 0; rr < 16; ++rr) {
            int i = i16 + rr;
            int beg = row_start[i], end = row_start[i + 1];
            bool need = (end == beg) || (end > (((beg >> 4) + 1) << 4));
            if (need) {
                float* as = (float*)agg_s;
                float* av = (float*)agg_v;
                as[(size_t)i * 64 + l] = 0.f;
                av[((size_t)i * 3 + 0) * 64 + l] = 0.f;
                av[((size_t)i * 3 + 1) * 64 + l] = 0.f;
                av[((size_t)i * 3 + 2) * 64 + l] = 0.f;
            }
        }
    }
}

// ---------------------------------------------------------------------------
extern "C" void kernel_launch(void* const* d_in, const int* in_sizes, int n_in,
                              void* d_out, int out_size, void* d_ws, size_t ws_size,
                              hipStream_t stream)
{
    const float* vectors = (const float*)d_in[0];
    const float* embed_s = (const float*)d_in[1];
    const float* Wr      = (const float*)d_in[2];   // [2,8,320]
    const float* Wls     = (const float*)d_in[3];   // [2,64,64]
    const float* Wlv     = (const float*)d_in[4];
    const float* skip_s  = (const float*)d_in[5];   // [10,64,64]
    const float* skip_v  = (const float*)d_in[6];
    const float* pw      = (const float*)d_in[7];   // [2,10,9,64]
    const float* Wps     = (const float*)d_in[8];
    const float* Wpv     = (const float*)d_in[9];
    const float* Wread0  = (const float*)d_in[10];  // [64,1]
    const float* Wr1a    = (const float*)d_in[11];  // [64,16]
    const float* Wr1b    = (const float*)d_in[12];  // [16,1]
    const int* senders   = (const int*)d_in[13];
    const int* receivers = (const int*)d_in[14];
    const int* species   = (const int*)d_in[15];
    float* out = (float*)d_out;

    float* ws = (float*)d_ws;
    float* edata = ws; ws += (size_t)N_EDGES * 16;  // 16 MB (slot-ordered)
    float* agg_s = ws; ws += (size_t)N_NODES * 64;  // 8 MB
    float* agg_v = ws; ws += (size_t)N_NODES * 192; // 24 MB
    unsigned short* svp = (unsigned short*)ws; ws += (size_t)N_NODES * 128; // 16 MB packed {s,v0,v1,v2} bf16
    int* counts    = (int*)ws; ws += N_NODES;
    int* row_start = (int*)ws; ws += N_NODES + 4;
    int* cursor    = (int*)ws; ws += N_NODES;
    int* edge_ids  = (int*)ws; ws += N_EDGES;
    int* srk       = (int*)ws; ws += N_EDGES;
    int* grp_row   = (int*)ws; ws += N_EDGES / 16;
    int* sidx      = (int*)ws; ws += N_NODES;
    int* rank      = (int*)ws; ws += N_NODES;
    int* spec_srt  = (int*)ws; ws += N_NODES;
    int* lrank_arr = (int*)ws; ws += N_NODES;
    int* counts_blk = (int*)ws; ws += 128 * NSPEC;
    int* off_blk    = (int*)ws; ws += 128 * NSPEC;
    short* packW   = (short*)ws;                    // 224 KB

    // species counting sort (sort1 also zeroes CSR counts)
    sort1_kernel<<<N_NODES / 256, 256, 0, stream>>>(
        species, counts_blk, lrank_arr, counts);
    sort2_kernel<<<1, 640, 0, stream>>>(counts_blk, off_blk);
    sort3_kernel<<<N_NODES / 256, 256, 0, stream>>>(
        species, lrank_arr, off_blk, sidx, rank, spec_srt);

    // receiver CSR in sorted space
    hist_kernel<<<N_EDGES / 256, 256, 0, stream>>>(receivers, rank, counts);
    scan_kernel<<<1, 1024, 0, stream>>>(counts, row_start, cursor);
    scatter_kernel<<<N_EDGES / 256, 256, 0, stream>>>(receivers, rank, cursor, edge_ids);

    // edge features + packed sender rank/species + grp_row (one pass)
    edge_pre_kernel<<<N_EDGES / 256, 256, 0, stream>>>(
        vectors, edge_ids, senders, rank, species, row_start, edata, srk, grp_row);

    // merged prep: weight pack + zero boundary agg rows (i0). No init_s.
    prep_kernel<<<2048, 256, 0, stream>>>(
        Wls, Wlv, Wps, Wpv, skip_s, skip_v, packW, row_start, agg_s, agg_v);

    // interaction 0 (gather reads embed table; node fuses read0 + re-zeroing
    // and writes the packed state for interaction 1's gather)
    gather_kernel<1><<<N_EDGES / 32, 64, 0, stream>>>(
        edata, srk, row_start, grp_row, embed_s, svp, Wr, agg_s, agg_v);
    node_mfma_kernel<<<N_NODES / 64, 256, 0, stream>>>(
        agg_s, agg_v, svp, packW, 0, pw, spec_srt,
        row_start, sidx, Wread0, Wr1a, Wr1b, out, 0);

    // interaction 1 (packed bf16 state: ONE 8-B random load per edge/lane)
    gather_kernel<0><<<N_EDGES / 32, 64, 0, stream>>>(
        edata, srk, row_start, grp_row, embed_s, svp, Wr + 2560, agg_s, agg_v);
    node_mfma_kernel<<<N_NODES / 64, 256, 0, stream>>>(
        agg_s, agg_v, svp, packW, 1, pw + 5760, spec_srt,
        row_start, sidx, Wread0, Wr1a, Wr1b, out, 1);
}

// Round 8
// 277.252 us; speedup vs baseline: 1.2049x; 1.0132x over previous
//
#include <hip/hip_runtime.h>
#include <hip/hip_bf16.h>
#include <math.h>

#define N_NODES 32768
#define N_EDGES 262144
#define EPS_C 0.24253562503633297f   // 1/sqrt(17)
#define NSPEC 10

typedef __attribute__((ext_vector_type(8))) short short8;   // 8 bf16
typedef __attribute__((ext_vector_type(4))) float f32x4;    // 4 fp32 acc

#define MFMA16(a, b, c) __builtin_amdgcn_mfma_f32_16x16x32_bf16(a, b, c, 0, 0, 0)

__device__ __forceinline__ short2 cvt2(float a, float b) {
    union { __hip_bfloat162 h; short2 s; } u;
    u.h = __float22bfloat162_rn(make_float2(a, b));
    return u.s;
}
__device__ __forceinline__ unsigned cvt2u(float a, float b) {
    union { __hip_bfloat162 h; unsigned u; } u;
    u.h = __float22bfloat162_rn(make_float2(a, b));
    return u.u;   // lo16 = bf(a), hi16 = bf(b)
}
__device__ __forceinline__ unsigned short f2bf(float a) {
    return (unsigned short)cvt2(a, 0.f).x;
}
__device__ __forceinline__ float bf2f(unsigned short u) {
    return __uint_as_float(((unsigned)u) << 16);
}
__device__ __forceinline__ short8 cvt8(float4 a, float4 b) {
    short2 p0 = cvt2(a.x, a.y), p1 = cvt2(a.z, a.w);
    short2 p2 = cvt2(b.x, b.y), p3 = cvt2(b.z, b.w);
    short8 r;
    r[0] = p0.x; r[1] = p0.y; r[2] = p1.x; r[3] = p1.y;
    r[4] = p2.x; r[5] = p2.y; r[6] = p3.x; r[7] = p3.y;
    return r;
}
__device__ __forceinline__ short8 loadArow(const float* rowp, int h, int q) {
    const float* p = rowp + h * 32 + q * 8;
    return cvt8(*(const float4*)p, *(const float4*)(p + 4));
}
__device__ __forceinline__ short8 loadB(const short* P, int t, int h, int l) {
    return *(const short8*)(P + (((t * 2 + h) * 64 + l) << 3));
}

// packed state svp[node][64 ch][4] = ushort4 {s, v0, v1, v2} (bf16 bits).
__device__ __forceinline__ short8 unpack_s(const unsigned short* prow, int ch0) {
    const uint4* p = (const uint4*)(prow + ch0 * 4);
    uint4 u0 = p[0], u1 = p[1], u2 = p[2], u3 = p[3];
    short8 r;
    r[0] = (short)(u0.x & 0xffff); r[1] = (short)(u0.z & 0xffff);
    r[2] = (short)(u1.x & 0xffff); r[3] = (short)(u1.z & 0xffff);
    r[4] = (short)(u2.x & 0xffff); r[5] = (short)(u2.z & 0xffff);
    r[6] = (short)(u3.x & 0xffff); r[7] = (short)(u3.z & 0xffff);
    return r;
}
__device__ __forceinline__ void unpack_v(const unsigned short* prow, int ch0,
                                         short8 (&Aiv)[3][2], int h) {
    const uint4* p = (const uint4*)(prow + ch0 * 4);
    uint4 u0 = p[0], u1 = p[1], u2 = p[2], u3 = p[3];
    Aiv[0][h][0] = (short)(u0.x >> 16); Aiv[0][h][1] = (short)(u0.z >> 16);
    Aiv[0][h][2] = (short)(u1.x >> 16); Aiv[0][h][3] = (short)(u1.z >> 16);
    Aiv[0][h][4] = (short)(u2.x >> 16); Aiv[0][h][5] = (short)(u2.z >> 16);
    Aiv[0][h][6] = (short)(u3.x >> 16); Aiv[0][h][7] = (short)(u3.z >> 16);
    Aiv[1][h][0] = (short)(u0.y & 0xffff); Aiv[1][h][1] = (short)(u0.w & 0xffff);
    Aiv[1][h][2] = (short)(u1.y & 0xffff); Aiv[1][h][3] = (short)(u1.w & 0xffff);
    Aiv[1][h][4] = (short)(u2.y & 0xffff); Aiv[1][h][5] = (short)(u2.w & 0xffff);
    Aiv[1][h][6] = (short)(u3.y & 0xffff); Aiv[1][h][7] = (short)(u3.w & 0xffff);
    Aiv[2][h][0] = (short)(u0.y >> 16); Aiv[2][h][1] = (short)(u0.w >> 16);
    Aiv[2][h][2] = (short)(u1.y >> 16); Aiv[2][h][3] = (short)(u1.w >> 16);
    Aiv[2][h][4] = (short)(u2.y >> 16); Aiv[2][h][5] = (short)(u2.w >> 16);
    Aiv[2][h][6] = (short)(u3.y >> 16); Aiv[2][h][7] = (short)(u3.w >> 16);
}

// ---------------------------------------------------------------------------
// Species counting sort — contention-free, deterministic. sort1 also zeroes
// the receiver-CSR counts array.
// ---------------------------------------------------------------------------
__global__ __launch_bounds__(256) void sort1_kernel(
    const int* __restrict__ species, int* __restrict__ counts_blk,
    int* __restrict__ lrank_arr, int* __restrict__ counts)
{
    __shared__ int wcnt[4][16];
    int n = blockIdx.x * 256 + threadIdx.x;
    counts[n] = 0;
    int sp = species[n];
    int lane = threadIdx.x & 63, wv = threadIdx.x >> 6;
    unsigned long long ltmask = (1ull << lane) - 1;
    int lrank_w = 0;
#pragma unroll
    for (int z = 0; z < NSPEC; ++z) {
        unsigned long long m = __ballot(sp == z);
        if (sp == z) lrank_w = __popcll(m & ltmask);
        if (lane == 0) wcnt[wv][z] = __popcll(m);
    }
    __syncthreads();
    int off = 0;
    for (int w = 0; w < wv; ++w) off += wcnt[w][sp];
    lrank_arr[n] = lrank_w + off;
    if (threadIdx.x < NSPEC)
        counts_blk[blockIdx.x * NSPEC + threadIdx.x] =
            wcnt[0][threadIdx.x] + wcnt[1][threadIdx.x] +
            wcnt[2][threadIdx.x] + wcnt[3][threadIdx.x];
}

// parallel block-offset scan: wave z shuffle-scans its 128 block counts
__global__ __launch_bounds__(640) void sort2_kernel(
    const int* __restrict__ counts_blk, int* __restrict__ off_blk)
{
    __shared__ int totals[16];
    int wv = threadIdx.x >> 6;        // 0..9 == species z
    int lane = threadIdx.x & 63;
    int c0 = counts_blk[lane * NSPEC + wv];
    int c1 = counts_blk[(64 + lane) * NSPEC + wv];
    int s0 = c0;
#pragma unroll
    for (int off = 1; off < 64; off <<= 1) {
        int y = __shfl_up(s0, off);
        if (lane >= off) s0 += y;
    }
    int tot0 = __shfl(s0, 63);
    int s1 = c1;
#pragma unroll
    for (int off = 1; off < 64; off <<= 1) {
        int y = __shfl_up(s1, off);
        if (lane >= off) s1 += y;
    }
    s1 += tot0;
    if (lane == 63) totals[wv] = s1;
    __syncthreads();
    int base = 0;
    for (int q = 0; q < wv; ++q) base += totals[q];
    off_blk[lane * NSPEC + wv] = base + s0 - c0;
    off_blk[(64 + lane) * NSPEC + wv] = base + s1 - c1;
}

__global__ __launch_bounds__(256) void sort3_kernel(
    const int* __restrict__ species, const int* __restrict__ lrank_arr,
    const int* __restrict__ off_blk,
    int* __restrict__ sidx, int* __restrict__ rank, int* __restrict__ spec_srt)
{
    int n = blockIdx.x * 256 + threadIdx.x;
    int sp = species[n];
    int slot = off_blk[blockIdx.x * NSPEC + sp] + lrank_arr[n];
    sidx[slot] = n;
    rank[n] = slot;
    spec_srt[slot] = sp;
}

// ---------------------------------------------------------------------------
// Receiver CSR in SORTED space. hist also caches rrank[e] (the random
// rank[receivers[e]] lookup) so the mega kernel re-reads it COALESCED
// instead of repeating the random load (r8: -14MB effective L2-miss).
// ---------------------------------------------------------------------------
__global__ __launch_bounds__(256) void hist_kernel(
    const int* __restrict__ receivers, const int* __restrict__ rank,
    int* __restrict__ counts, int* __restrict__ rrank)
{
    int e = blockIdx.x * 256 + threadIdx.x;
    int rr = rank[receivers[e]];
    atomicAdd(&counts[rr], 1);
    rrank[e] = rr;
}

__global__ __launch_bounds__(1024) void scan_kernel(
    const int* __restrict__ counts, int* __restrict__ row_start, int* __restrict__ cursor)
{
    __shared__ int wave_tot[16];
    int tid = threadIdx.x;
    int c[32];
    int sum = 0;
#pragma unroll
    for (int i = 0; i < 32; ++i) { c[i] = counts[tid * 32 + i]; sum += c[i]; }
    int lane = tid & 63, wv = tid >> 6;
    int x = sum;
#pragma unroll
    for (int off = 1; off < 64; off <<= 1) {
        int y = __shfl_up(x, off);
        if (lane >= off) x += y;
    }
    if (lane == 63) wave_tot[wv] = x;
    __syncthreads();
    if (wv == 0 && lane < 16) {
        int t = wave_tot[lane];
#pragma unroll
        for (int off = 1; off < 16; off <<= 1) {
            int y = __shfl_up(t, off);
            if (lane >= off) t += y;
        }
        wave_tot[lane] = t;
    }
    __syncthreads();
    int excl = x - sum + (wv ? wave_tot[wv - 1] : 0);
    int run = excl;
#pragma unroll
    for (int i = 0; i < 32; ++i) {
        row_start[tid * 32 + i] = run;
        cursor[tid * 32 + i] = run;
        run += c[i];
    }
    if (tid == 1023) row_start[32768] = run;
}

// ---------------------------------------------------------------------------
// MEGA kernel (r8): fuses scatter + edge_pre + prep (weight pack, zero_bnd,
// grp_row) into one launch. Independencies: all parts need only row_start/
// cursor (from scan), rrank (from hist), rank (from sort3) and inputs.
//  - edge part: slot via cursor atomic; vectors[e] read COALESCED (was
//    random via edge_ids in edge_pre); features written to edata[slot]
//    (random 48-B stores -> partial-line RMW, L3-served; cheaper than the
//    random 12-B vector reads they replace). edge_ids array eliminated.
//  - Bessel sines via Chebyshev recurrence (see r7 note; ~1e-6 rel dev).
//  - weight pack: idx<28*4096, identical mapping to old prep.
//  - zero_bnd: 8 nodes per wave (4096 waves cover 32768 nodes).
//  - grp_row: first 16384 threads binary-search row_start.
// ---------------------------------------------------------------------------
__global__ __launch_bounds__(256) void mega_kernel(
    const float* __restrict__ vectors, const int* __restrict__ senders,
    const int* __restrict__ rank, const int* __restrict__ species,
    const int* __restrict__ rrank, int* __restrict__ cursor,
    const int* __restrict__ row_start,
    float* __restrict__ edata, int* __restrict__ srk, int* __restrict__ grp_row,
    const float* __restrict__ Wls, const float* __restrict__ Wlv,
    const float* __restrict__ Wps, const float* __restrict__ Wpv,
    const float* __restrict__ skip_s, const float* __restrict__ skip_v,
    short* __restrict__ packW,
    float* __restrict__ agg_s, float* __restrict__ agg_v)
{
    const int idx = blockIdx.x * 256 + threadIdx.x;   // == edge id e
    const int e = idx;

    // ---- edge: slot assignment + features (vectors read coalesced)
    int rr = rrank[e];
    int slot = atomicAdd(&cursor[rr], 1);
    int snd = senders[e];
    srk[slot] = rank[snd] | (species[snd] << 16);
    float x = vectors[e * 3 + 0], y = vectors[e * 3 + 1], z = vectors[e * 3 + 2];
    float r2 = x * x + y * y + z * z + 1e-12f;
    float r = sqrtf(r2);
    float inv = 1.0f / r;
    float* d = edata + (size_t)slot * 16;
    *(float4*)d = make_float4(x * inv, y * inv, z * inv, 0.0f);
    float rc = fmaxf(r, 1e-6f);
    float r6 = r2 * r2 * r2;
    float r7 = r6 * r;
    float r8 = r6 * r2;
    float env = (r < 1.0f) ? (1.0f - 28.0f * r6 + 48.0f * r7 - 21.0f * r8) : 0.0f;
    float sc = 1.41421356237309515f * env / rc;
    float xr = 3.14159265358979323846f * rc;
    float s1, c1;
    sincosf(xr, &s1, &c1);
    float tc = 2.0f * c1;
    float s2 = tc * s1;              // s0 = sin(0) = 0
    float s3 = tc * s2 - s1;
    float s4 = tc * s3 - s2;
    float s5 = tc * s4 - s3;
    float s6 = tc * s5 - s4;
    float s7 = tc * s6 - s5;
    float s8 = tc * s7 - s6;
    *(float4*)(d + 4) = make_float4(sc * s1, sc * s2, sc * s3, sc * s4);
    *(float4*)(d + 8) = make_float4(sc * s5, sc * s6, sc * s7, sc * s8);

    // ---- weight pack (identical mapping to old prep_kernel)
    if (idx < 28 * 4096) {
        int m = idx >> 12, ee = idx & 4095;
        int t = ee >> 10, h = (ee >> 9) & 1, l = (ee >> 3) & 63, j = ee & 7;
        int fi = h * 32 + ((l >> 4) << 3) + j;
        int fo = t * 16 + (l & 15);
        const float* src;
        if      (m < 2)  src = Wls    + m * 4096;
        else if (m < 4)  src = Wlv    + (m - 2) * 4096;
        else if (m < 6)  src = Wps    + (m - 4) * 4096;
        else if (m < 8)  src = Wpv    + (m - 6) * 4096;
        else if (m < 18) src = skip_s + (m - 8) * 4096;
        else             src = skip_v + (m - 18) * 4096;
        packW[idx] = cvt2(src[fi * 64 + fo], 0.f).x;
    }

    // ---- zero boundary agg rows for interaction 0 (8 nodes per wave)
    {
        const int wid = threadIdx.x >> 6;
        const int f = threadIdx.x & 63;
        const int gw = blockIdx.x * 4 + wid;      // 0..4095
#pragma unroll
        for (int t = 0; t < 8; ++t) {
            int i = gw * 8 + t;
            int beg = row_start[i], end = row_start[i + 1];
            bool need = (end == beg) || (end > (((beg >> 4) + 1) << 4));
            if (need) {
                agg_s[(size_t)i * 64 + f] = 0.f;
                agg_v[((size_t)i * 3 + 0) * 64 + f] = 0.f;
                agg_v[((size_t)i * 3 + 1) * 64 + f] = 0.f;
                agg_v[((size_t)i * 3 + 2) * 64 + f] = 0.f;
            }
        }
    }

    // ---- grp_row binary search (first 16384 threads)
    if (idx < N_EDGES / 16) {
        int target = idx * 16;
        int lo = 0, hi = N_NODES - 1;
        while (lo < hi) {
            int mid = (lo + hi + 1) >> 1;
            if (row_start[mid] <= target) lo = mid; else hi = mid - 1;
        }
        grp_row[idx] = lo;
    }
}

// ---------------------------------------------------------------------------
// Dual-chain edge-balanced gather, 1 wave/block.
// DO NOT use multi-wave workgroups here: tried 4-wave (r1) and 2-wave (r3);
// both regress badly (spills visible as +42MB WRITE_SIZE, occupancy flat).
// Depth-3 state pipeline + depth-1 edata prefetch (r7). Unchanged in r8.
// ---------------------------------------------------------------------------
template<int VZERO>
__global__ __launch_bounds__(64, 4) void gather_kernel(
    const float* __restrict__ edata, const int* __restrict__ srk,
    const int* __restrict__ row_start, const int* __restrict__ grp_row,
    const float* __restrict__ embed_s,
    const unsigned short* __restrict__ svp,
    const float* __restrict__ Wr_i,
    float* __restrict__ agg_s, float* __restrict__ agg_v)
{
    const int f = threadIdx.x & 63;
    const int w = blockIdx.x;
    const int pA0 = w * 32;
    const int pB0 = pA0 + 16;

    float wr[5][8];
#pragma unroll
    for (int j = 0; j < 8; ++j)
#pragma unroll
        for (int p = 0; p < 5; ++p)
            wr[p][j] = (VZERO && (p == 1 || p == 3 || p == 4))
                       ? 0.f : Wr_i[j * 320 + p * 64 + f];

    int rA = grp_row[2 * w], rB = grp_row[2 * w + 1];
    int begA = row_start[rA], endA = row_start[rA + 1];
    int begB = row_start[rB], endB = row_start[rB + 1];
    float aA0 = 0.f, aA1 = 0.f, aA2 = 0.f, aA3 = 0.f;
    float aB0 = 0.f, aB1 = 0.f, aB2 = 0.f, aB3 = 0.f;

    int svHA = srk[pA0 + 3], svHB = srk[pB0 + 3];
    uint2 pa0 = {0,0}, pa1 = {0,0}, pa2 = {0,0};
    uint2 pb0 = {0,0}, pb1 = {0,0}, pb2 = {0,0};
    float fa0 = 0.f, fa1 = 0.f, fa2 = 0.f, fb0 = 0.f, fb1 = 0.f, fb2 = 0.f;
    {
        int sA0 = srk[pA0], sA1 = srk[pA0 + 1], sA2 = srk[pA0 + 2];
        int sB0 = srk[pB0], sB1 = srk[pB0 + 1], sB2 = srk[pB0 + 2];
        if (VZERO) {
            fa0 = embed_s[(sA0 >> 16) * 64 + f];
            fa1 = embed_s[(sA1 >> 16) * 64 + f];
            fa2 = embed_s[(sA2 >> 16) * 64 + f];
            fb0 = embed_s[(sB0 >> 16) * 64 + f];
            fb1 = embed_s[(sB1 >> 16) * 64 + f];
            fb2 = embed_s[(sB2 >> 16) * 64 + f];
        } else {
            pa0 = *(const uint2*)(svp + (((size_t)(sA0 & 0xFFFF)) * 64 + f) * 4);
            pa1 = *(const uint2*)(svp + (((size_t)(sA1 & 0xFFFF)) * 64 + f) * 4);
            pa2 = *(const uint2*)(svp + (((size_t)(sA2 & 0xFFFF)) * 64 + f) * 4);
            pb0 = *(const uint2*)(svp + (((size_t)(sB0 & 0xFFFF)) * 64 + f) * 4);
            pb1 = *(const uint2*)(svp + (((size_t)(sB1 & 0xFFFF)) * 64 + f) * 4);
            pb2 = *(const uint2*)(svp + (((size_t)(sB2 & 0xFFFF)) * 64 + f) * 4);
        }
    }
    const float* dA0p = edata + (size_t)pA0 * 16;
    const float* dB0p = edata + (size_t)pB0 * 16;
    float4 yA = *(const float4*)dA0p;
    float4 qA0 = *(const float4*)(dA0p + 4);
    float4 qA1 = *(const float4*)(dA0p + 8);
    float4 yB = *(const float4*)dB0p;
    float4 qB0 = *(const float4*)(dB0p + 4);
    float4 qB1 = *(const float4*)(dB0p + 8);

#pragma unroll
    for (int k = 0; k < 16; ++k) {
        const int pA = pA0 + k, pB = pB0 + k;

        int svNA = svHA, svNB = svHB;
        if (k < 12) {
            svNA = srk[pA + 4];
            svNB = srk[pB + 4];
        }

        uint2 pa3 = {0, 0}, pb3 = {0, 0};
        float fa3 = 0.f, fb3 = 0.f;
        if (k < 13) {
            if (VZERO) {
                fa3 = embed_s[(svHA >> 16) * 64 + f];
                fb3 = embed_s[(svHB >> 16) * 64 + f];
            } else {
                pa3 = *(const uint2*)(svp + (((size_t)(svHA & 0xFFFF)) * 64 + f) * 4);
                pb3 = *(const uint2*)(svp + (((size_t)(svHB & 0xFFFF)) * 64 + f) * 4);
            }
        }

        float4 yAn = yA, qA0n = qA0, qA1n = qA1;
        float4 yBn = yB, qB0n = qB0, qB1n = qB1;
        if (k < 15) {
            const float* dAn = edata + (size_t)(pA + 1) * 16;
            const float* dBn = edata + (size_t)(pB + 1) * 16;
            yAn  = *(const float4*)dAn;
            qA0n = *(const float4*)(dAn + 4);
            qA1n = *(const float4*)(dAn + 8);
            yBn  = *(const float4*)dBn;
            qB0n = *(const float4*)(dBn + 4);
            qB1n = *(const float4*)(dBn + 8);
        }

        float rbA[8] = {qA0.x, qA0.y, qA0.z, qA0.w, qA1.x, qA1.y, qA1.z, qA1.w};
        float rbB[8] = {qB0.x, qB0.y, qB0.z, qB0.w, qB1.x, qB1.y, qB1.z, qB1.w};
        float wA0 = 0.f, wA1 = 0.f, wA2 = 0.f, wA3 = 0.f, wA4 = 0.f;
        float wB0 = 0.f, wB1 = 0.f, wB2 = 0.f, wB3 = 0.f, wB4 = 0.f;
#pragma unroll
        for (int j = 0; j < 8; ++j) {
            wA0 = fmaf(rbA[j], wr[0][j], wA0);  wB0 = fmaf(rbB[j], wr[0][j], wB0);
            if (!VZERO) { wA1 = fmaf(rbA[j], wr[1][j], wA1);  wB1 = fmaf(rbB[j], wr[1][j], wB1); }
            wA2 = fmaf(rbA[j], wr[2][j], wA2);  wB2 = fmaf(rbB[j], wr[2][j], wB2);
            if (!VZERO) { wA3 = fmaf(rbA[j], wr[3][j], wA3);  wB3 = fmaf(rbB[j], wr[3][j], wB3); }
            if (!VZERO) { wA4 = fmaf(rbA[j], wr[4][j], wA4);  wB4 = fmaf(rbB[j], wr[4][j], wB4); }
        }

        if (VZERO) {
            float ssA = fa0, ssB = fb0;
            aA0 += wA0 * ssA;
            float wsA = wA2 * ssA;
            aA1 += wsA * yA.x; aA2 += wsA * yA.y; aA3 += wsA * yA.z;
            aB0 += wB0 * ssB;
            float wsB = wB2 * ssB;
            aB1 += wsB * yB.x; aB2 += wsB * yB.y; aB3 += wsB * yB.z;
        } else {
            float ssA = __uint_as_float(pa0.x << 16);
            float va0 = __uint_as_float(pa0.x & 0xffff0000u);
            float va1 = __uint_as_float(pa0.y << 16);
            float va2 = __uint_as_float(pa0.y & 0xffff0000u);
            float ssB = __uint_as_float(pb0.x << 16);
            float vb0 = __uint_as_float(pb0.x & 0xffff0000u);
            float vb1 = __uint_as_float(pb0.y << 16);
            float vb2 = __uint_as_float(pb0.y & 0xffff0000u);
            float dotA = va0 * yA.x + va1 * yA.y + va2 * yA.z;
            aA0 += wA0 * ssA + wA1 * dotA;
            float cA0 = va1 * yA.z - va2 * yA.y;
            float cA1 = va2 * yA.x - va0 * yA.z;
            float cA2 = va0 * yA.y - va1 * yA.x;
            float wsA = wA2 * ssA;
            aA1 += wsA * yA.x + wA3 * va0 + wA4 * cA0;
            aA2 += wsA * yA.y + wA3 * va1 + wA4 * cA1;
            aA3 += wsA * yA.z + wA3 * va2 + wA4 * cA2;
            float dotB = vb0 * yB.x + vb1 * yB.y + vb2 * yB.z;
            aB0 += wB0 * ssB + wB1 * dotB;
            float cB0 = vb1 * yB.z - vb2 * yB.y;
            float cB1 = vb2 * yB.x - vb0 * yB.z;
            float cB2 = vb0 * yB.y - vb1 * yB.x;
            float wsB = wB2 * ssB;
            aB1 += wsB * yB.x + wB3 * vb0 + wB4 * cB0;
            aB2 += wsB * yB.y + wB3 * vb1 + wB4 * cB1;
            aB3 += wsB * yB.z + wB3 * vb2 + wB4 * cB2;
        }

        if (pA + 1 == endA || k == 15) {
            bool interior = (begA >= pA0) && (endA <= pA0 + 16);
            if (interior) {
                agg_s[(size_t)rA * 64 + f] = aA0;
                agg_v[((size_t)rA * 3 + 0) * 64 + f] = aA1;
                agg_v[((size_t)rA * 3 + 1) * 64 + f] = aA2;
                agg_v[((size_t)rA * 3 + 2) * 64 + f] = aA3;
            } else {
                unsafeAtomicAdd(&agg_s[(size_t)rA * 64 + f], aA0);
                unsafeAtomicAdd(&agg_v[((size_t)rA * 3 + 0) * 64 + f], aA1);
                unsafeAtomicAdd(&agg_v[((size_t)rA * 3 + 1) * 64 + f], aA2);
                unsafeAtomicAdd(&agg_v[((size_t)rA * 3 + 2) * 64 + f], aA3);
            }
            aA0 = aA1 = aA2 = aA3 = 0.f;
            if (pA + 1 == endA && k < 15) {
                begA = endA; ++rA; endA = row_start[rA + 1];
                while (endA == begA) { ++rA; endA = row_start[rA + 1]; }
            }
        }
        if (pB + 1 == endB || k == 15) {
            bool interior = (begB >= pB0) && (endB <= pB0 + 16);
            if (interior) {
                agg_s[(size_t)rB * 64 + f] = aB0;
                agg_v[((size_t)rB * 3 + 0) * 64 + f] = aB1;
                agg_v[((size_t)rB * 3 + 1) * 64 + f] = aB2;
                agg_v[((size_t)rB * 3 + 2) * 64 + f] = aB3;
            } else {
                unsafeAtomicAdd(&agg_s[(size_t)rB * 64 + f], aB0);
                unsafeAtomicAdd(&agg_v[((size_t)rB * 3 + 0) * 64 + f], aB1);
                unsafeAtomicAdd(&agg_v[((size_t)rB * 3 + 1) * 64 + f], aB2);
                unsafeAtomicAdd(&agg_v[((size_t)rB * 3 + 2) * 64 + f], aB3);
            }
            aB0 = aB1 = aB2 = aB3 = 0.f;
            if (pB + 1 == endB && k < 15) {
                begB = endB; ++rB; endB = row_start[rB + 1];
                while (endB == begB) { ++rB; endB = row_start[rB + 1]; }
            }
        }

        pa0 = pa1; pa1 = pa2; pa2 = pa3;
        pb0 = pb1; pb1 = pb2; pb2 = pb3;
        fa0 = fa1; fa1 = fa2; fa2 = fa3;
        fb0 = fb1; fb1 = fb2; fb2 = fb3;
        svHA = svNA; svHB = svNB;
        yA = yAn; qA0 = qA0n; qA1 = qA1n;
        yB = yBn; qB0 = qB0n; qB1 = qB1n;
    }
}

// ---------------------------------------------------------------------------
// MFMA node kernel. State lives ONLY in packed svp[node][ch]=ushort4
// {s,v0,v1,v2} (bf16 bits, RNE). it==0 writes svp; it==1 reads svp for skip
// fragments and writes NOTHING (state dead after last interaction).
// ---------------------------------------------------------------------------
__global__ __launch_bounds__(256) void node_mfma_kernel(
    const float* __restrict__ agg_s, const float* __restrict__ agg_v,
    unsigned short* svp,
    const short* __restrict__ packW, int it,
    const float* __restrict__ pw_i,
    const int* __restrict__ spec_srt,
    const int* __restrict__ row_start, const int* __restrict__ sidx,
    const float* __restrict__ Wread0, const float* __restrict__ Wr1a,
    const float* __restrict__ Wr1b,
    float* __restrict__ out,
    int has_skip)
{
    const int l = threadIdx.x & 63;
    const int wid = threadIdx.x >> 6;
    const int cl = l & 15;
    const int q = l >> 4;
    const int i16 = (blockIdx.x * 4 + wid) * 16;
    __shared__ float xls_all[4][16 * 65];
    float* xls = xls_all[wid];

    const short* pWls = packW + (size_t)(0 + it) * 4096;
    const short* pWlv = packW + (size_t)(2 + it) * 4096;
    const short* pWps = packW + (size_t)(4 + it) * 4096;
    const short* pWpv = packW + (size_t)(6 + it) * 4096;
    const short* pSkS = packW + (size_t)8 * 4096;
    const short* pSkV = packW + (size_t)18 * 4096;
    const short8 z8 = {0, 0, 0, 0, 0, 0, 0, 0};

    const float* ars = agg_s + (size_t)(i16 + cl) * 64;
    short8 As[2] = { loadArow(ars, 0, q), loadArow(ars, 1, q) };
    short8 Av[3][2];
#pragma unroll
    for (int k = 0; k < 3; ++k) {
        const float* r = agg_v + ((size_t)(i16 + cl) * 3 + k) * 64;
        Av[k][0] = loadArow(r, 0, q);
        Av[k][1] = loadArow(r, 1, q);
    }

    f32x4 sD[4];
#pragma unroll
    for (int t = 0; t < 4; ++t) {
        f32x4 acc = {0.f, 0.f, 0.f, 0.f};
        acc = MFMA16(As[0], loadB(pWls, t, 0, l), acc);
        acc = MFMA16(As[1], loadB(pWls, t, 1, l), acc);
        sD[t] = acc;
    }

    f32x4 vD[3][4];
#pragma unroll
    for (int k = 0; k < 3; ++k)
#pragma unroll
        for (int t = 0; t < 4; ++t) vD[k][t] = (f32x4){0.f, 0.f, 0.f, 0.f};
#pragma unroll
    for (int t = 0; t < 4; ++t)
#pragma unroll
        for (int h = 0; h < 2; ++h) {
            short8 b = loadB(pWlv, t, h, l);
#pragma unroll
            for (int k = 0; k < 3; ++k) vD[k][t] = MFMA16(Av[k][h], b, vD[k][t]);
        }

    int z0 = spec_srt[i16], z1 = spec_srt[i16 + 15];
    float psD[4][4], pvsD[4][4];
    if (z0 == z1) {
        const float* pb = pw_i + z0 * 576 + cl;
        float pc[9][4];
#pragma unroll
        for (int c = 0; c < 9; ++c)
#pragma unroll
            for (int t = 0; t < 4; ++t) pc[c][t] = pb[c * 64 + t * 16];
#pragma unroll
        for (int t = 0; t < 4; ++t)
#pragma unroll
            for (int r = 0; r < 4; ++r) {
                float x = sD[t][r] * EPS_C;
                float w0 = vD[0][t][r] * EPS_C;
                float w1 = vD[1][t][r] * EPS_C;
                float w2 = vD[2][t][r] * EPS_C;
                vD[0][t][r] = w0; vD[1][t][r] = w1; vD[2][t][r] = w2;
                float vv = w0 * w0 + w1 * w1 + w2 * w2;
                float x2 = x * x;
                psD[t][r] = pc[0][t] * x + pc[1][t] * x2 + pc[2][t] * vv
                          + pc[3][t] * x2 * x + pc[4][t] * x * vv;
                pvsD[t][r] = pc[5][t] + pc[6][t] * x + pc[7][t] * x2 + pc[8][t] * vv;
            }
    } else {
#pragma unroll
        for (int r = 0; r < 4; ++r) {
            int z = spec_srt[i16 + q * 4 + r];
            const float* pb = pw_i + z * 576 + cl;
#pragma unroll
            for (int t = 0; t < 4; ++t) {
                float p0 = pb[t*16], p1 = pb[64+t*16], p2 = pb[128+t*16];
                float p3 = pb[192+t*16], p4 = pb[256+t*16], p5 = pb[320+t*16];
                float p6 = pb[384+t*16], p7 = pb[448+t*16], p8 = pb[512+t*16];
                float x = sD[t][r] * EPS_C;
                float w0 = vD[0][t][r] * EPS_C;
                float w1 = vD[1][t][r] * EPS_C;
                float w2 = vD[2][t][r] * EPS_C;
                vD[0][t][r] = w0; vD[1][t][r] = w1; vD[2][t][r] = w2;
                float vv = w0 * w0 + w1 * w1 + w2 * w2;
                float x2 = x * x;
                psD[t][r] = p0 * x + p1 * x2 + p2 * vv + p3 * x2 * x + p4 * x * vv;
                pvsD[t][r] = p5 + p6 * x + p7 * x2 + p8 * vv;
            }
        }
    }

#pragma unroll
    for (int t = 0; t < 4; ++t)
#pragma unroll
        for (int r = 0; r < 4; ++r)
            xls[(q * 4 + r) * 65 + t * 16 + cl] = psD[t][r];
    short8 psA[2];
#pragma unroll
    for (int h = 0; h < 2; ++h) {
        const float* rp = xls + cl * 65 + h * 32 + q * 8;
        float t0 = rp[0], t1 = rp[1], t2 = rp[2], t3 = rp[3];
        float t4 = rp[4], t5 = rp[5], t6 = rp[6], t7 = rp[7];
        psA[h] = cvt8(make_float4(t0, t1, t2, t3), make_float4(t4, t5, t6, t7));
    }

    f32x4 snD[4];
#pragma unroll
    for (int t = 0; t < 4; ++t) {
        f32x4 acc = {0.f, 0.f, 0.f, 0.f};
        acc = MFMA16(psA[0], loadB(pWps, t, 0, l), acc);
        acc = MFMA16(psA[1], loadB(pWps, t, 1, l), acc);
        snD[t] = acc;
    }
    if (has_skip) {
        const unsigned short* prow = svp + (size_t)(i16 + cl) * 256;
        short8 Ai0 = unpack_s(prow, q * 8);
        short8 Ai1 = unpack_s(prow, 32 + q * 8);
        int myz = spec_srt[i16 + cl];
        for (int z = z0; z <= z1; ++z) {
            bool keep = (myz == z);
            short8 m0 = keep ? Ai0 : z8;
            short8 m1 = keep ? Ai1 : z8;
            const short* pz = pSkS + (size_t)z * 4096;
#pragma unroll
            for (int t = 0; t < 4; ++t) {
                snD[t] = MFMA16(m0, loadB(pz, t, 0, l), snD[t]);
                snD[t] = MFMA16(m1, loadB(pz, t, 1, l), snD[t]);
            }
        }
    }

    // ---- fused readout (pre-rounded fp32 registers)
    if (it == 0) {
        float w0c[4];
#pragma unroll
        for (int t = 0; t < 4; ++t) w0c[t] = Wread0[t * 16 + cl];
#pragma unroll
        for (int r = 0; r < 4; ++r) {
            float a = snD[0][r] * w0c[0] + snD[1][r] * w0c[1]
                    + snD[2][r] * w0c[2] + snD[3][r] * w0c[3];
            a += __shfl_down(a, 8);
            a += __shfl_down(a, 4);
            a += __shfl_down(a, 2);
            a += __shfl_down(a, 1);
            if (cl == 0) out[(size_t)sidx[i16 + q * 4 + r] * 2 + 0] = a;
        }
    } else {
#pragma unroll
        for (int t = 0; t < 4; ++t)
#pragma unroll
            for (int r = 0; r < 4; ++r)
                xls[(q * 4 + r) * 65 + t * 16 + cl] = snD[t][r];
        float acc4[4] = {0.f, 0.f, 0.f, 0.f};
        for (int g = 0; g < 64; ++g) {
            float wa = Wr1a[g * 16 + cl];
#pragma unroll
            for (int j = 0; j < 4; ++j)
                acc4[j] = fmaf(xls[(q + 4 * j) * 65 + g], wa, acc4[j]);
        }
        float wb = Wr1b[cl];
#pragma unroll
        for (int j = 0; j < 4; ++j) {
            float av = acc4[j];
            float rr = (av / (1.f + expf(-av))) * wb;
            rr += __shfl_down(rr, 8);
            rr += __shfl_down(rr, 4);
            rr += __shfl_down(rr, 2);
            rr += __shfl_down(rr, 1);
            if (cl == 0) out[(size_t)sidx[i16 + q + 4 * j] * 2 + 1] = rr;
        }
    }

    short8 pvA[3][2];
#pragma unroll
    for (int k = 0; k < 3; ++k) {
#pragma unroll
        for (int t = 0; t < 4; ++t)
#pragma unroll
            for (int r = 0; r < 4; ++r)
                xls[(q * 4 + r) * 65 + t * 16 + cl] = pvsD[t][r] * vD[k][t][r];
#pragma unroll
        for (int h = 0; h < 2; ++h) {
            const float* rp = xls + cl * 65 + h * 32 + q * 8;
            float t0 = rp[0], t1 = rp[1], t2 = rp[2], t3 = rp[3];
            float t4 = rp[4], t5 = rp[5], t6 = rp[6], t7 = rp[7];
            pvA[k][h] = cvt8(make_float4(t0, t1, t2, t3), make_float4(t4, t5, t6, t7));
        }
    }

    f32x4 vnD[3][4];
#pragma unroll
    for (int k = 0; k < 3; ++k)
#pragma unroll
        for (int t = 0; t < 4; ++t) vnD[k][t] = (f32x4){0.f, 0.f, 0.f, 0.f};
#pragma unroll
    for (int t = 0; t < 4; ++t)
#pragma unroll
        for (int h = 0; h < 2; ++h) {
            short8 b = loadB(pWpv, t, h, l);
#pragma unroll
            for (int k = 0; k < 3; ++k) vnD[k][t] = MFMA16(pvA[k][h], b, vnD[k][t]);
        }
    if (has_skip) {
        const unsigned short* prow = svp + (size_t)(i16 + cl) * 256;
        short8 Aiv[3][2];
        unpack_v(prow, q * 8, Aiv, 0);
        unpack_v(prow, 32 + q * 8, Aiv, 1);
        int myz = spec_srt[i16 + cl];
        for (int z = z0; z <= z1; ++z) {
            bool keep = (myz == z);
            const short* pz = pSkV + (size_t)z * 4096;
#pragma unroll
            for (int t = 0; t < 4; ++t)
#pragma unroll
                for (int h = 0; h < 2; ++h) {
                    short8 b = loadB(pz, t, h, l);
#pragma unroll
                    for (int k = 0; k < 3; ++k) {
                        short8 a = keep ? Aiv[k][h] : z8;
                        vnD[k][t] = MFMA16(a, b, vnD[k][t]);
                    }
                }
        }
    }

    // ---- state store: ONLY at it==0 (state dead after last interaction).
    if (it == 0) {
#pragma unroll
        for (int t = 0; t < 4; ++t)
#pragma unroll
            for (int r = 0; r < 4; ++r) {
                uint2 pk;
                pk.x = cvt2u(snD[t][r], vnD[0][t][r]);
                pk.y = cvt2u(vnD[1][t][r], vnD[2][t][r]);
                *(uint2*)(svp + ((size_t)(i16 + q * 4 + r) * 64 + t * 16 + cl) * 4) = pk;
            }
    }

    // ---- it==0: zero this wave's own agg boundary rows for interaction 1.
    if (it == 0) {
        for (int rr = 0; rr < 16; ++rr) {
            int i = i16 + rr;
            int beg = row_start[i], end = row_start[i + 1];
            bool need = (end == beg) || (end > (((beg >> 4) + 1) << 4));
            if (need) {
                float* as = (float*)agg_s;
                float* av = (float*)agg_v;
                as[(size_t)i * 64 + l] = 0.f;
                av[((size_t)i * 3 + 0) * 64 + l] = 0.f;
                av[((size_t)i * 3 + 1) * 64 + l] = 0.f;
                av[((size_t)i * 3 + 2) * 64 + l] = 0.f;
            }
        }
    }
}

// ---------------------------------------------------------------------------
extern "C" void kernel_launch(void* const* d_in, const int* in_sizes, int n_in,
                              void* d_out, int out_size, void* d_ws, size_t ws_size,
                              hipStream_t stream)
{
    const float* vectors = (const float*)d_in[0];
    const float* embed_s = (const float*)d_in[1];
    const float* Wr      = (const float*)d_in[2];   // [2,8,320]
    const float* Wls     = (const float*)d_in[3];   // [2,64,64]
    const float* Wlv     = (const float*)d_in[4];
    const float* skip_s  = (const float*)d_in[5];   // [10,64,64]
    const float* skip_v  = (const float*)d_in[6];
    const float* pw      = (const float*)d_in[7];   // [2,10,9,64]
    const float* Wps     = (const float*)d_in[8];
    const float* Wpv     = (const float*)d_in[9];
    const float* Wread0  = (const float*)d_in[10];  // [64,1]
    const float* Wr1a    = (const float*)d_in[11];  // [64,16]
    const float* Wr1b    = (const float*)d_in[12];  // [16,1]
    const int* senders   = (const int*)d_in[13];
    const int* receivers = (const int*)d_in[14];
    const int* species   = (const int*)d_in[15];
    float* out = (float*)d_out;

    float* ws = (float*)d_ws;
    float* edata = ws; ws += (size_t)N_EDGES * 16;  // 16 MB (slot-ordered)
    float* agg_s = ws; ws += (size_t)N_NODES * 64;  // 8 MB
    float* agg_v = ws; ws += (size_t)N_NODES * 192; // 24 MB
    unsigned short* svp = (unsigned short*)ws; ws += (size_t)N_NODES * 128; // 16 MB packed {s,v0,v1,v2} bf16
    int* counts    = (int*)ws; ws += N_NODES;
    int* row_start = (int*)ws; ws += N_NODES + 4;
    int* cursor    = (int*)ws; ws += N_NODES;
    int* rrank     = (int*)ws; ws += N_EDGES;       // cached rank[receivers[e]]
    int* srk       = (int*)ws; ws += N_EDGES;
    int* grp_row   = (int*)ws; ws += N_EDGES / 16;
    int* sidx      = (int*)ws; ws += N_NODES;
    int* rank      = (int*)ws; ws += N_NODES;
    int* spec_srt  = (int*)ws; ws += N_NODES;
    int* lrank_arr = (int*)ws; ws += N_NODES;
    int* counts_blk = (int*)ws; ws += 128 * NSPEC;
    int* off_blk    = (int*)ws; ws += 128 * NSPEC;
    short* packW   = (short*)ws;                    // 224 KB

    // species counting sort (sort1 also zeroes CSR counts)
    sort1_kernel<<<N_NODES / 256, 256, 0, stream>>>(
        species, counts_blk, lrank_arr, counts);
    sort2_kernel<<<1, 640, 0, stream>>>(counts_blk, off_blk);
    sort3_kernel<<<N_NODES / 256, 256, 0, stream>>>(
        species, lrank_arr, off_blk, sidx, rank, spec_srt);

    // receiver CSR in sorted space (hist caches rrank for the mega kernel)
    hist_kernel<<<N_EDGES / 256, 256, 0, stream>>>(receivers, rank, counts, rrank);
    scan_kernel<<<1, 1024, 0, stream>>>(counts, row_start, cursor);

    // MEGA: edge scatter + features + srk + weight pack + zero_bnd + grp_row
    mega_kernel<<<N_EDGES / 256, 256, 0, stream>>>(
        vectors, senders, rank, species, rrank, cursor, row_start,
        edata, srk, grp_row,
        Wls, Wlv, Wps, Wpv, skip_s, skip_v, packW, agg_s, agg_v);

    // interaction 0 (gather reads embed table; node fuses read0 + re-zeroing
    // and writes the packed state for interaction 1's gather)
    gather_kernel<1><<<N_EDGES / 32, 64, 0, stream>>>(
        edata, srk, row_start, grp_row, embed_s, svp, Wr, agg_s, agg_v);
    node_mfma_kernel<<<N_NODES / 64, 256, 0, stream>>>(
        agg_s, agg_v, svp, packW, 0, pw, spec_srt,
        row_start, sidx, Wread0, Wr1a, Wr1b, out, 0);

    // interaction 1 (packed bf16 state: ONE 8-B random load per edge/lane)
    gather_kernel<0><<<N_EDGES / 32, 64, 0, stream>>>(
        edata, srk, row_start, grp_row, embed_s, svp, Wr + 2560, agg_s, agg_v);
    node_mfma_kernel<<<N_NODES / 64, 256, 0, stream>>>(
        agg_s, agg_v, svp, packW, 1, pw + 5760, spec_srt,
        row_start, sidx, Wread0, Wr1a, Wr1b, out, 1);
}

// Round 9
// 273.414 us; speedup vs baseline: 1.2218x; 1.0140x over previous
//
#include <hip/hip_runtime.h>
#include <hip/hip_bf16.h>
#include <math.h>

#define N_NODES 32768
#define N_EDGES 262144
#define EPS_C 0.24253562503633297f   // 1/sqrt(17)
#define NSPEC 10

typedef __attribute__((ext_vector_type(8))) short short8;   // 8 bf16
typedef __attribute__((ext_vector_type(4))) float f32x4;    // 4 fp32 acc

#define MFMA16(a, b, c) __builtin_amdgcn_mfma_f32_16x16x32_bf16(a, b, c, 0, 0, 0)

__device__ __forceinline__ short2 cvt2(float a, float b) {
    union { __hip_bfloat162 h; short2 s; } u;
    u.h = __float22bfloat162_rn(make_float2(a, b));
    return u.s;
}
__device__ __forceinline__ unsigned cvt2u(float a, float b) {
    union { __hip_bfloat162 h; unsigned u; } u;
    u.h = __float22bfloat162_rn(make_float2(a, b));
    return u.u;   // lo16 = bf(a), hi16 = bf(b)
}
__device__ __forceinline__ unsigned short f2bf(float a) {
    return (unsigned short)cvt2(a, 0.f).x;
}
__device__ __forceinline__ float bf2f(unsigned short u) {
    return __uint_as_float(((unsigned)u) << 16);
}
__device__ __forceinline__ short8 cvt8(float4 a, float4 b) {
    short2 p0 = cvt2(a.x, a.y), p1 = cvt2(a.z, a.w);
    short2 p2 = cvt2(b.x, b.y), p3 = cvt2(b.z, b.w);
    short8 r;
    r[0] = p0.x; r[1] = p0.y; r[2] = p1.x; r[3] = p1.y;
    r[4] = p2.x; r[5] = p2.y; r[6] = p3.x; r[7] = p3.y;
    return r;
}
__device__ __forceinline__ short8 loadArow(const float* rowp, int h, int q) {
    const float* p = rowp + h * 32 + q * 8;
    return cvt8(*(const float4*)p, *(const float4*)(p + 4));
}
__device__ __forceinline__ short8 loadB(const short* P, int t, int h, int l) {
    return *(const short8*)(P + (((t * 2 + h) * 64 + l) << 3));
}

// packed state svp[node][64 ch][4] = ushort4 {s, v0, v1, v2} (bf16 bits).
__device__ __forceinline__ short8 unpack_s(const unsigned short* prow, int ch0) {
    const uint4* p = (const uint4*)(prow + ch0 * 4);
    uint4 u0 = p[0], u1 = p[1], u2 = p[2], u3 = p[3];
    short8 r;
    r[0] = (short)(u0.x & 0xffff); r[1] = (short)(u0.z & 0xffff);
    r[2] = (short)(u1.x & 0xffff); r[3] = (short)(u1.z & 0xffff);
    r[4] = (short)(u2.x & 0xffff); r[5] = (short)(u2.z & 0xffff);
    r[6] = (short)(u3.x & 0xffff); r[7] = (short)(u3.z & 0xffff);
    return r;
}
__device__ __forceinline__ void unpack_v(const unsigned short* prow, int ch0,
                                         short8 (&Aiv)[3][2], int h) {
    const uint4* p = (const uint4*)(prow + ch0 * 4);
    uint4 u0 = p[0], u1 = p[1], u2 = p[2], u3 = p[3];
    Aiv[0][h][0] = (short)(u0.x >> 16); Aiv[0][h][1] = (short)(u0.z >> 16);
    Aiv[0][h][2] = (short)(u1.x >> 16); Aiv[0][h][3] = (short)(u1.z >> 16);
    Aiv[0][h][4] = (short)(u2.x >> 16); Aiv[0][h][5] = (short)(u2.z >> 16);
    Aiv[0][h][6] = (short)(u3.x >> 16); Aiv[0][h][7] = (short)(u3.z >> 16);
    Aiv[1][h][0] = (short)(u0.y & 0xffff); Aiv[1][h][1] = (short)(u0.w & 0xffff);
    Aiv[1][h][2] = (short)(u1.y & 0xffff); Aiv[1][h][3] = (short)(u1.w & 0xffff);
    Aiv[1][h][4] = (short)(u2.y & 0xffff); Aiv[1][h][5] = (short)(u2.w & 0xffff);
    Aiv[1][h][6] = (short)(u3.y & 0xffff); Aiv[1][h][7] = (short)(u3.w & 0xffff);
    Aiv[2][h][0] = (short)(u0.y >> 16); Aiv[2][h][1] = (short)(u0.w >> 16);
    Aiv[2][h][2] = (short)(u1.y >> 16); Aiv[2][h][3] = (short)(u1.w >> 16);
    Aiv[2][h][4] = (short)(u2.y >> 16); Aiv[2][h][5] = (short)(u2.w >> 16);
    Aiv[2][h][6] = (short)(u3.y >> 16); Aiv[2][h][7] = (short)(u3.w >> 16);
}

// ---------------------------------------------------------------------------
// Species counting sort — contention-free, deterministic. sort1 also zeroes
// the receiver-CSR counts array.
// ---------------------------------------------------------------------------
__global__ __launch_bounds__(256) void sort1_kernel(
    const int* __restrict__ species, int* __restrict__ counts_blk,
    int* __restrict__ lrank_arr, int* __restrict__ counts)
{
    __shared__ int wcnt[4][16];
    int n = blockIdx.x * 256 + threadIdx.x;
    counts[n] = 0;
    int sp = species[n];
    int lane = threadIdx.x & 63, wv = threadIdx.x >> 6;
    unsigned long long ltmask = (1ull << lane) - 1;
    int lrank_w = 0;
#pragma unroll
    for (int z = 0; z < NSPEC; ++z) {
        unsigned long long m = __ballot(sp == z);
        if (sp == z) lrank_w = __popcll(m & ltmask);
        if (lane == 0) wcnt[wv][z] = __popcll(m);
    }
    __syncthreads();
    int off = 0;
    for (int w = 0; w < wv; ++w) off += wcnt[w][sp];
    lrank_arr[n] = lrank_w + off;
    if (threadIdx.x < NSPEC)
        counts_blk[blockIdx.x * NSPEC + threadIdx.x] =
            wcnt[0][threadIdx.x] + wcnt[1][threadIdx.x] +
            wcnt[2][threadIdx.x] + wcnt[3][threadIdx.x];
}

// parallel block-offset scan: wave z shuffle-scans its 128 block counts
__global__ __launch_bounds__(640) void sort2_kernel(
    const int* __restrict__ counts_blk, int* __restrict__ off_blk)
{
    __shared__ int totals[16];
    int wv = threadIdx.x >> 6;        // 0..9 == species z
    int lane = threadIdx.x & 63;
    int c0 = counts_blk[lane * NSPEC + wv];
    int c1 = counts_blk[(64 + lane) * NSPEC + wv];
    int s0 = c0;
#pragma unroll
    for (int off = 1; off < 64; off <<= 1) {
        int y = __shfl_up(s0, off);
        if (lane >= off) s0 += y;
    }
    int tot0 = __shfl(s0, 63);
    int s1 = c1;
#pragma unroll
    for (int off = 1; off < 64; off <<= 1) {
        int y = __shfl_up(s1, off);
        if (lane >= off) s1 += y;
    }
    s1 += tot0;
    if (lane == 63) totals[wv] = s1;
    __syncthreads();
    int base = 0;
    for (int q = 0; q < wv; ++q) base += totals[q];
    off_blk[lane * NSPEC + wv] = base + s0 - c0;
    off_blk[(64 + lane) * NSPEC + wv] = base + s1 - c1;
}

// sort3 also fuses rsp[n] = rank | species<<16 (written into the retired
// lrank_arr buffer) so mega's srk build needs ONE random read, not two.
__global__ __launch_bounds__(256) void sort3_kernel(
    const int* __restrict__ species, int* __restrict__ lrank_arr,
    const int* __restrict__ off_blk,
    int* __restrict__ sidx, int* __restrict__ rank, int* __restrict__ spec_srt)
{
    int n = blockIdx.x * 256 + threadIdx.x;
    int sp = species[n];
    int slot = off_blk[blockIdx.x * NSPEC + sp] + lrank_arr[n];
    sidx[slot] = n;
    rank[n] = slot;
    spec_srt[slot] = sp;
    lrank_arr[n] = slot | (sp << 16);   // rsp (each thread owns index n)
}

// ---------------------------------------------------------------------------
// Receiver CSR in SORTED space. hist also caches rrank[e] so the mega kernel
// re-reads it COALESCED instead of repeating the random load.
// ---------------------------------------------------------------------------
__global__ __launch_bounds__(256) void hist_kernel(
    const int* __restrict__ receivers, const int* __restrict__ rank,
    int* __restrict__ counts, int* __restrict__ rrank)
{
    int e = blockIdx.x * 256 + threadIdx.x;
    int rr = rank[receivers[e]];
    atomicAdd(&counts[rr], 1);
    rrank[e] = rr;
}

__global__ __launch_bounds__(1024) void scan_kernel(
    const int* __restrict__ counts, int* __restrict__ row_start, int* __restrict__ cursor)
{
    __shared__ int wave_tot[16];
    int tid = threadIdx.x;
    int c[32];
    int sum = 0;
#pragma unroll
    for (int i = 0; i < 32; ++i) { c[i] = counts[tid * 32 + i]; sum += c[i]; }
    int lane = tid & 63, wv = tid >> 6;
    int x = sum;
#pragma unroll
    for (int off = 1; off < 64; off <<= 1) {
        int y = __shfl_up(x, off);
        if (lane >= off) x += y;
    }
    if (lane == 63) wave_tot[wv] = x;
    __syncthreads();
    if (wv == 0 && lane < 16) {
        int t = wave_tot[lane];
#pragma unroll
        for (int off = 1; off < 16; off <<= 1) {
            int y = __shfl_up(t, off);
            if (lane >= off) t += y;
        }
        wave_tot[lane] = t;
    }
    __syncthreads();
    int excl = x - sum + (wv ? wave_tot[wv - 1] : 0);
    int run = excl;
#pragma unroll
    for (int i = 0; i < 32; ++i) {
        row_start[tid * 32 + i] = run;
        cursor[tid * 32 + i] = run;
        run += c[i];
    }
    if (tid == 1023) row_start[32768] = run;
}

// ---------------------------------------------------------------------------
// MEGA kernel: scatter + edge features + weight pack + zero_bnd + grp_row.
// r9: srk built from fused rsp[senders[e]] (one random read, was two).
// ---------------------------------------------------------------------------
__global__ __launch_bounds__(256) void mega_kernel(
    const float* __restrict__ vectors, const int* __restrict__ senders,
    const int* __restrict__ rsp,
    const int* __restrict__ rrank, int* __restrict__ cursor,
    const int* __restrict__ row_start,
    float* __restrict__ edata, int* __restrict__ srk, int* __restrict__ grp_row,
    const float* __restrict__ Wls, const float* __restrict__ Wlv,
    const float* __restrict__ Wps, const float* __restrict__ Wpv,
    const float* __restrict__ skip_s, const float* __restrict__ skip_v,
    short* __restrict__ packW,
    float* __restrict__ agg_s, float* __restrict__ agg_v)
{
    const int idx = blockIdx.x * 256 + threadIdx.x;   // == edge id e
    const int e = idx;

    // ---- edge: slot assignment + features (vectors read coalesced)
    int rr = rrank[e];
    int slot = atomicAdd(&cursor[rr], 1);
    srk[slot] = rsp[senders[e]];
    float x = vectors[e * 3 + 0], y = vectors[e * 3 + 1], z = vectors[e * 3 + 2];
    float r2 = x * x + y * y + z * z + 1e-12f;
    float r = sqrtf(r2);
    float inv = 1.0f / r;
    float* d = edata + (size_t)slot * 16;
    *(float4*)d = make_float4(x * inv, y * inv, z * inv, 0.0f);
    float rc = fmaxf(r, 1e-6f);
    float r6 = r2 * r2 * r2;
    float r7 = r6 * r;
    float r8 = r6 * r2;
    float env = (r < 1.0f) ? (1.0f - 28.0f * r6 + 48.0f * r7 - 21.0f * r8) : 0.0f;
    float sc = 1.41421356237309515f * env / rc;
    float xr = 3.14159265358979323846f * rc;
    float s1, c1;
    sincosf(xr, &s1, &c1);
    float tc = 2.0f * c1;
    float s2 = tc * s1;              // s0 = sin(0) = 0
    float s3 = tc * s2 - s1;
    float s4 = tc * s3 - s2;
    float s5 = tc * s4 - s3;
    float s6 = tc * s5 - s4;
    float s7 = tc * s6 - s5;
    float s8 = tc * s7 - s6;
    *(float4*)(d + 4) = make_float4(sc * s1, sc * s2, sc * s3, sc * s4);
    *(float4*)(d + 8) = make_float4(sc * s5, sc * s6, sc * s7, sc * s8);

    // ---- weight pack (identical mapping to original prep_kernel)
    if (idx < 28 * 4096) {
        int m = idx >> 12, ee = idx & 4095;
        int t = ee >> 10, h = (ee >> 9) & 1, l = (ee >> 3) & 63, j = ee & 7;
        int fi = h * 32 + ((l >> 4) << 3) + j;
        int fo = t * 16 + (l & 15);
        const float* src;
        if      (m < 2)  src = Wls    + m * 4096;
        else if (m < 4)  src = Wlv    + (m - 2) * 4096;
        else if (m < 6)  src = Wps    + (m - 4) * 4096;
        else if (m < 8)  src = Wpv    + (m - 6) * 4096;
        else if (m < 18) src = skip_s + (m - 8) * 4096;
        else             src = skip_v + (m - 18) * 4096;
        packW[idx] = cvt2(src[fi * 64 + fo], 0.f).x;
    }

    // ---- zero boundary agg rows for interaction 0 (8 nodes per wave)
    {
        const int wid = threadIdx.x >> 6;
        const int f = threadIdx.x & 63;
        const int gw = blockIdx.x * 4 + wid;      // 0..4095
#pragma unroll
        for (int t = 0; t < 8; ++t) {
            int i = gw * 8 + t;
            int beg = row_start[i], end = row_start[i + 1];
            bool need = (end == beg) || (end > (((beg >> 4) + 1) << 4));
            if (need) {
                agg_s[(size_t)i * 64 + f] = 0.f;
                agg_v[((size_t)i * 3 + 0) * 64 + f] = 0.f;
                agg_v[((size_t)i * 3 + 1) * 64 + f] = 0.f;
                agg_v[((size_t)i * 3 + 2) * 64 + f] = 0.f;
            }
        }
    }

    // ---- grp_row binary search (first 16384 threads)
    if (idx < N_EDGES / 16) {
        int target = idx * 16;
        int lo = 0, hi = N_NODES - 1;
        while (lo < hi) {
            int mid = (lo + hi + 1) >> 1;
            if (row_start[mid] <= target) lo = mid; else hi = mid - 1;
        }
        grp_row[idx] = lo;
    }
}

// ---------------------------------------------------------------------------
// Dual-chain edge-balanced gather, 1 wave/block.
// DO NOT use multi-wave workgroups here (r1/r3: spills, occupancy flat).
// r9: sched_barrier(0) per iteration pins the stage-3 random-state issue
// BEFORE iteration k's compute. r8 showed VGPR=48 — the compiler had sunk
// the staged loads to their consume sites (collapsing the pipeline to ~2-3
// loads in flight; Little's law matches the measured 2-2.8 TB/s). The
// barrier forces the staging registers live (>=6 random loads in flight).
// edata prefetch stays AFTER the barrier so the allocator can still shade
// it if registers get tight (cap 128 via launch_bounds(64,4)).
// Spill tripwire: WRITE_SIZE > 47MB -> revert.
// ---------------------------------------------------------------------------
template<int VZERO>
__global__ __launch_bounds__(64, 4) void gather_kernel(
    const float* __restrict__ edata, const int* __restrict__ srk,
    const int* __restrict__ row_start, const int* __restrict__ grp_row,
    const float* __restrict__ embed_s,
    const unsigned short* __restrict__ svp,
    const float* __restrict__ Wr_i,
    float* __restrict__ agg_s, float* __restrict__ agg_v)
{
    const int f = threadIdx.x & 63;
    const int w = blockIdx.x;
    const int pA0 = w * 32;
    const int pB0 = pA0 + 16;

    float wr[5][8];
#pragma unroll
    for (int j = 0; j < 8; ++j)
#pragma unroll
        for (int p = 0; p < 5; ++p)
            wr[p][j] = (VZERO && (p == 1 || p == 3 || p == 4))
                       ? 0.f : Wr_i[j * 320 + p * 64 + f];

    int rA = grp_row[2 * w], rB = grp_row[2 * w + 1];
    int begA = row_start[rA], endA = row_start[rA + 1];
    int begB = row_start[rB], endB = row_start[rB + 1];
    float aA0 = 0.f, aA1 = 0.f, aA2 = 0.f, aA3 = 0.f;
    float aB0 = 0.f, aB1 = 0.f, aB2 = 0.f, aB3 = 0.f;

    int svHA = srk[pA0 + 3], svHB = srk[pB0 + 3];
    uint2 pa0 = {0,0}, pa1 = {0,0}, pa2 = {0,0};
    uint2 pb0 = {0,0}, pb1 = {0,0}, pb2 = {0,0};
    float fa0 = 0.f, fa1 = 0.f, fa2 = 0.f, fb0 = 0.f, fb1 = 0.f, fb2 = 0.f;
    {
        int sA0 = srk[pA0], sA1 = srk[pA0 + 1], sA2 = srk[pA0 + 2];
        int sB0 = srk[pB0], sB1 = srk[pB0 + 1], sB2 = srk[pB0 + 2];
        if (VZERO) {
            fa0 = embed_s[(sA0 >> 16) * 64 + f];
            fa1 = embed_s[(sA1 >> 16) * 64 + f];
            fa2 = embed_s[(sA2 >> 16) * 64 + f];
            fb0 = embed_s[(sB0 >> 16) * 64 + f];
            fb1 = embed_s[(sB1 >> 16) * 64 + f];
            fb2 = embed_s[(sB2 >> 16) * 64 + f];
        } else {
            pa0 = *(const uint2*)(svp + (((size_t)(sA0 & 0xFFFF)) * 64 + f) * 4);
            pa1 = *(const uint2*)(svp + (((size_t)(sA1 & 0xFFFF)) * 64 + f) * 4);
            pa2 = *(const uint2*)(svp + (((size_t)(sA2 & 0xFFFF)) * 64 + f) * 4);
            pb0 = *(const uint2*)(svp + (((size_t)(sB0 & 0xFFFF)) * 64 + f) * 4);
            pb1 = *(const uint2*)(svp + (((size_t)(sB1 & 0xFFFF)) * 64 + f) * 4);
            pb2 = *(const uint2*)(svp + (((size_t)(sB2 & 0xFFFF)) * 64 + f) * 4);
        }
    }
    const float* dA0p = edata + (size_t)pA0 * 16;
    const float* dB0p = edata + (size_t)pB0 * 16;
    float4 yA = *(const float4*)dA0p;
    float4 qA0 = *(const float4*)(dA0p + 4);
    float4 qA1 = *(const float4*)(dA0p + 8);
    float4 yB = *(const float4*)dB0p;
    float4 qB0 = *(const float4*)(dB0p + 4);
    float4 qB1 = *(const float4*)(dB0p + 8);

#pragma unroll
    for (int k = 0; k < 16; ++k) {
        const int pA = pA0 + k, pB = pB0 + k;

        int svNA = svHA, svNB = svHB;
        if (k < 12) {
            svNA = srk[pA + 4];
            svNB = srk[pB + 4];
        }

        // issue stage-3 state loads (edge k+3) — raw bits, no conversion
        uint2 pa3 = {0, 0}, pb3 = {0, 0};
        float fa3 = 0.f, fb3 = 0.f;
        if (k < 13) {
            if (VZERO) {
                fa3 = embed_s[(svHA >> 16) * 64 + f];
                fb3 = embed_s[(svHB >> 16) * 64 + f];
            } else {
                pa3 = *(const uint2*)(svp + (((size_t)(svHA & 0xFFFF)) * 64 + f) * 4);
                pb3 = *(const uint2*)(svp + (((size_t)(svHB & 0xFFFF)) * 64 + f) * 4);
            }
        }

        // pin: stage-3 issues may not sink below this point (r9)
        __builtin_amdgcn_sched_barrier(0);

        // edata prefetch for edge k+1 (after the barrier: allocator-flexible)
        float4 yAn = yA, qA0n = qA0, qA1n = qA1;
        float4 yBn = yB, qB0n = qB0, qB1n = qB1;
        if (k < 15) {
            const float* dAn = edata + (size_t)(pA + 1) * 16;
            const float* dBn = edata + (size_t)(pB + 1) * 16;
            yAn  = *(const float4*)dAn;
            qA0n = *(const float4*)(dAn + 4);
            qA1n = *(const float4*)(dAn + 8);
            yBn  = *(const float4*)dBn;
            qB0n = *(const float4*)(dBn + 4);
            qB1n = *(const float4*)(dBn + 8);
        }

        float rbA[8] = {qA0.x, qA0.y, qA0.z, qA0.w, qA1.x, qA1.y, qA1.z, qA1.w};
        float rbB[8] = {qB0.x, qB0.y, qB0.z, qB0.w, qB1.x, qB1.y, qB1.z, qB1.w};
        float wA0 = 0.f, wA1 = 0.f, wA2 = 0.f, wA3 = 0.f, wA4 = 0.f;
        float wB0 = 0.f, wB1 = 0.f, wB2 = 0.f, wB3 = 0.f, wB4 = 0.f;
#pragma unroll
        for (int j = 0; j < 8; ++j) {
            wA0 = fmaf(rbA[j], wr[0][j], wA0);  wB0 = fmaf(rbB[j], wr[0][j], wB0);
            if (!VZERO) { wA1 = fmaf(rbA[j], wr[1][j], wA1);  wB1 = fmaf(rbB[j], wr[1][j], wB1); }
            wA2 = fmaf(rbA[j], wr[2][j], wA2);  wB2 = fmaf(rbB[j], wr[2][j], wB2);
            if (!VZERO) { wA3 = fmaf(rbA[j], wr[3][j], wA3);  wB3 = fmaf(rbB[j], wr[3][j], wB3); }
            if (!VZERO) { wA4 = fmaf(rbA[j], wr[4][j], wA4);  wB4 = fmaf(rbB[j], wr[4][j], wB4); }
        }

        if (VZERO) {
            float ssA = fa0, ssB = fb0;
            aA0 += wA0 * ssA;
            float wsA = wA2 * ssA;
            aA1 += wsA * yA.x; aA2 += wsA * yA.y; aA3 += wsA * yA.z;
            aB0 += wB0 * ssB;
            float wsB = wB2 * ssB;
            aB1 += wsB * yB.x; aB2 += wsB * yB.y; aB3 += wsB * yB.z;
        } else {
            float ssA = __uint_as_float(pa0.x << 16);
            float va0 = __uint_as_float(pa0.x & 0xffff0000u);
            float va1 = __uint_as_float(pa0.y << 16);
            float va2 = __uint_as_float(pa0.y & 0xffff0000u);
            float ssB = __uint_as_float(pb0.x << 16);
            float vb0 = __uint_as_float(pb0.x & 0xffff0000u);
            float vb1 = __uint_as_float(pb0.y << 16);
            float vb2 = __uint_as_float(pb0.y & 0xffff0000u);
            float dotA = va0 * yA.x + va1 * yA.y + va2 * yA.z;
            aA0 += wA0 * ssA + wA1 * dotA;
            float cA0 = va1 * yA.z - va2 * yA.y;
            float cA1 = va2 * yA.x - va0 * yA.z;
            float cA2 = va0 * yA.y - va1 * yA.x;
            float wsA = wA2 * ssA;
            aA1 += wsA * yA.x + wA3 * va0 + wA4 * cA0;
            aA2 += wsA * yA.y + wA3 * va1 + wA4 * cA1;
            aA3 += wsA * yA.z + wA3 * va2 + wA4 * cA2;
            float dotB = vb0 * yB.x + vb1 * yB.y + vb2 * yB.z;
            aB0 += wB0 * ssB + wB1 * dotB;
            float cB0 = vb1 * yB.z - vb2 * yB.y;
            float cB1 = vb2 * yB.x - vb0 * yB.z;
            float cB2 = vb0 * yB.y - vb1 * yB.x;
            float wsB = wB2 * ssB;
            aB1 += wsB * yB.x + wB3 * vb0 + wB4 * cB0;
            aB2 += wsB * yB.y + wB3 * vb1 + wB4 * cB1;
            aB3 += wsB * yB.z + wB3 * vb2 + wB4 * cB2;
        }

        if (pA + 1 == endA || k == 15) {
            bool interior = (begA >= pA0) && (endA <= pA0 + 16);
            if (interior) {
                agg_s[(size_t)rA * 64 + f] = aA0;
                agg_v[((size_t)rA * 3 + 0) * 64 + f] = aA1;
                agg_v[((size_t)rA * 3 + 1) * 64 + f] = aA2;
                agg_v[((size_t)rA * 3 + 2) * 64 + f] = aA3;
            } else {
                unsafeAtomicAdd(&agg_s[(size_t)rA * 64 + f], aA0);
                unsafeAtomicAdd(&agg_v[((size_t)rA * 3 + 0) * 64 + f], aA1);
                unsafeAtomicAdd(&agg_v[((size_t)rA * 3 + 1) * 64 + f], aA2);
                unsafeAtomicAdd(&agg_v[((size_t)rA * 3 + 2) * 64 + f], aA3);
            }
            aA0 = aA1 = aA2 = aA3 = 0.f;
            if (pA + 1 == endA && k < 15) {
                begA = endA; ++rA; endA = row_start[rA + 1];
                while (endA == begA) { ++rA; endA = row_start[rA + 1]; }
            }
        }
        if (pB + 1 == endB || k == 15) {
            bool interior = (begB >= pB0) && (endB <= pB0 + 16);
            if (interior) {
                agg_s[(size_t)rB * 64 + f] = aB0;
                agg_v[((size_t)rB * 3 + 0) * 64 + f] = aB1;
                agg_v[((size_t)rB * 3 + 1) * 64 + f] = aB2;
                agg_v[((size_t)rB * 3 + 2) * 64 + f] = aB3;
            } else {
                unsafeAtomicAdd(&agg_s[(size_t)rB * 64 + f], aB0);
                unsafeAtomicAdd(&agg_v[((size_t)rB * 3 + 0) * 64 + f], aB1);
                unsafeAtomicAdd(&agg_v[((size_t)rB * 3 + 1) * 64 + f], aB2);
                unsafeAtomicAdd(&agg_v[((size_t)rB * 3 + 2) * 64 + f], aB3);
            }
            aB0 = aB1 = aB2 = aB3 = 0.f;
            if (pB + 1 == endB && k < 15) {
                begB = endB; ++rB; endB = row_start[rB + 1];
                while (endB == begB) { ++rB; endB = row_start[rB + 1]; }
            }
        }

        pa0 = pa1; pa1 = pa2; pa2 = pa3;
        pb0 = pb1; pb1 = pb2; pb2 = pb3;
        fa0 = fa1; fa1 = fa2; fa2 = fa3;
        fb0 = fb1; fb1 = fb2; fb2 = fb3;
        svHA = svNA; svHB = svNB;
        yA = yAn; qA0 = qA0n; qA1 = qA1n;
        yB = yBn; qB0 = qB0n; qB1 = qB1n;
    }
}

// ---------------------------------------------------------------------------
// MFMA node kernel. State lives ONLY in packed svp[node][ch]=ushort4
// {s,v0,v1,v2} (bf16 bits, RNE). it==0 writes svp; it==1 reads svp for skip
// fragments and writes NOTHING (state dead after last interaction).
// ---------------------------------------------------------------------------
__global__ __launch_bounds__(256) void node_mfma_kernel(
    const float* __restrict__ agg_s, const float* __restrict__ agg_v,
    unsigned short* svp,
    const short* __restrict__ packW, int it,
    const float* __restrict__ pw_i,
    const int* __restrict__ spec_srt,
    const int* __restrict__ row_start, const int* __restrict__ sidx,
    const float* __restrict__ Wread0, const float* __restrict__ Wr1a,
    const float* __restrict__ Wr1b,
    float* __restrict__ out,
    int has_skip)
{
    const int l = threadIdx.x & 63;
    const int wid = threadIdx.x >> 6;
    const int cl = l & 15;
    const int q = l >> 4;
    const int i16 = (blockIdx.x * 4 + wid) * 16;
    __shared__ float xls_all[4][16 * 65];
    float* xls = xls_all[wid];

    const short* pWls = packW + (size_t)(0 + it) * 4096;
    const short* pWlv = packW + (size_t)(2 + it) * 4096;
    const short* pWps = packW + (size_t)(4 + it) * 4096;
    const short* pWpv = packW + (size_t)(6 + it) * 4096;
    const short* pSkS = packW + (size_t)8 * 4096;
    const short* pSkV = packW + (size_t)18 * 4096;
    const short8 z8 = {0, 0, 0, 0, 0, 0, 0, 0};

    const float* ars = agg_s + (size_t)(i16 + cl) * 64;
    short8 As[2] = { loadArow(ars, 0, q), loadArow(ars, 1, q) };
    short8 Av[3][2];
#pragma unroll
    for (int k = 0; k < 3; ++k) {
        const float* r = agg_v + ((size_t)(i16 + cl) * 3 + k) * 64;
        Av[k][0] = loadArow(r, 0, q);
        Av[k][1] = loadArow(r, 1, q);
    }

    f32x4 sD[4];
#pragma unroll
    for (int t = 0; t < 4; ++t) {
        f32x4 acc = {0.f, 0.f, 0.f, 0.f};
        acc = MFMA16(As[0], loadB(pWls, t, 0, l), acc);
        acc = MFMA16(As[1], loadB(pWls, t, 1, l), acc);
        sD[t] = acc;
    }

    f32x4 vD[3][4];
#pragma unroll
    for (int k = 0; k < 3; ++k)
#pragma unroll
        for (int t = 0; t < 4; ++t) vD[k][t] = (f32x4){0.f, 0.f, 0.f, 0.f};
#pragma unroll
    for (int t = 0; t < 4; ++t)
#pragma unroll
        for (int h = 0; h < 2; ++h) {
            short8 b = loadB(pWlv, t, h, l);
#pragma unroll
            for (int k = 0; k < 3; ++k) vD[k][t] = MFMA16(Av[k][h], b, vD[k][t]);
        }

    int z0 = spec_srt[i16], z1 = spec_srt[i16 + 15];
    float psD[4][4], pvsD[4][4];
    if (z0 == z1) {
        const float* pb = pw_i + z0 * 576 + cl;
        float pc[9][4];
#pragma unroll
        for (int c = 0; c < 9; ++c)
#pragma unroll
            for (int t = 0; t < 4; ++t) pc[c][t] = pb[c * 64 + t * 16];
#pragma unroll
        for (int t = 0; t < 4; ++t)
#pragma unroll
            for (int r = 0; r < 4; ++r) {
                float x = sD[t][r] * EPS_C;
                float w0 = vD[0][t][r] * EPS_C;
                float w1 = vD[1][t][r] * EPS_C;
                float w2 = vD[2][t][r] * EPS_C;
                vD[0][t][r] = w0; vD[1][t][r] = w1; vD[2][t][r] = w2;
                float vv = w0 * w0 + w1 * w1 + w2 * w2;
                float x2 = x * x;
                psD[t][r] = pc[0][t] * x + pc[1][t] * x2 + pc[2][t] * vv
                          + pc[3][t] * x2 * x + pc[4][t] * x * vv;
                pvsD[t][r] = pc[5][t] + pc[6][t] * x + pc[7][t] * x2 + pc[8][t] * vv;
            }
    } else {
#pragma unroll
        for (int r = 0; r < 4; ++r) {
            int z = spec_srt[i16 + q * 4 + r];
            const float* pb = pw_i + z * 576 + cl;
#pragma unroll
            for (int t = 0; t < 4; ++t) {
                float p0 = pb[t*16], p1 = pb[64+t*16], p2 = pb[128+t*16];
                float p3 = pb[192+t*16], p4 = pb[256+t*16], p5 = pb[320+t*16];
                float p6 = pb[384+t*16], p7 = pb[448+t*16], p8 = pb[512+t*16];
                float x = sD[t][r] * EPS_C;
                float w0 = vD[0][t][r] * EPS_C;
                float w1 = vD[1][t][r] * EPS_C;
                float w2 = vD[2][t][r] * EPS_C;
                vD[0][t][r] = w0; vD[1][t][r] = w1; vD[2][t][r] = w2;
                float vv = w0 * w0 + w1 * w1 + w2 * w2;
                float x2 = x * x;
                psD[t][r] = p0 * x + p1 * x2 + p2 * vv + p3 * x2 * x + p4 * x * vv;
                pvsD[t][r] = p5 + p6 * x + p7 * x2 + p8 * vv;
            }
        }
    }

#pragma unroll
    for (int t = 0; t < 4; ++t)
#pragma unroll
        for (int r = 0; r < 4; ++r)
            xls[(q * 4 + r) * 65 + t * 16 + cl] = psD[t][r];
    short8 psA[2];
#pragma unroll
    for (int h = 0; h < 2; ++h) {
        const float* rp = xls + cl * 65 + h * 32 + q * 8;
        float t0 = rp[0], t1 = rp[1], t2 = rp[2], t3 = rp[3];
        float t4 = rp[4], t5 = rp[5], t6 = rp[6], t7 = rp[7];
        psA[h] = cvt8(make_float4(t0, t1, t2, t3), make_float4(t4, t5, t6, t7));
    }

    f32x4 snD[4];
#pragma unroll
    for (int t = 0; t < 4; ++t) {
        f32x4 acc = {0.f, 0.f, 0.f, 0.f};
        acc = MFMA16(psA[0], loadB(pWps, t, 0, l), acc);
        acc = MFMA16(psA[1], loadB(pWps, t, 1, l), acc);
        snD[t] = acc;
    }
    if (has_skip) {
        const unsigned short* prow = svp + (size_t)(i16 + cl) * 256;
        short8 Ai0 = unpack_s(prow, q * 8);
        short8 Ai1 = unpack_s(prow, 32 + q * 8);
        int myz = spec_srt[i16 + cl];
        for (int z = z0; z <= z1; ++z) {
            bool keep = (myz == z);
            short8 m0 = keep ? Ai0 : z8;
            short8 m1 = keep ? Ai1 : z8;
            const short* pz = pSkS + (size_t)z * 4096;
#pragma unroll
            for (int t = 0; t < 4; ++t) {
                snD[t] = MFMA16(m0, loadB(pz, t, 0, l), snD[t]);
                snD[t] = MFMA16(m1, loadB(pz, t, 1, l), snD[t]);
            }
        }
    }

    // ---- fused readout (pre-rounded fp32 registers)
    if (it == 0) {
        float w0c[4];
#pragma unroll
        for (int t = 0; t < 4; ++t) w0c[t] = Wread0[t * 16 + cl];
#pragma unroll
        for (int r = 0; r < 4; ++r) {
            float a = snD[0][r] * w0c[0] + snD[1][r] * w0c[1]
                    + snD[2][r] * w0c[2] + snD[3][r] * w0c[3];
            a += __shfl_down(a, 8);
            a += __shfl_down(a, 4);
            a += __shfl_down(a, 2);
            a += __shfl_down(a, 1);
            if (cl == 0) out[(size_t)sidx[i16 + q * 4 + r] * 2 + 0] = a;
        }
    } else {
#pragma unroll
        for (int t = 0; t < 4; ++t)
#pragma unroll
            for (int r = 0; r < 4; ++r)
                xls[(q * 4 + r) * 65 + t * 16 + cl] = snD[t][r];
        float acc4[4] = {0.f, 0.f, 0.f, 0.f};
        for (int g = 0; g < 64; ++g) {
            float wa = Wr1a[g * 16 + cl];
#pragma unroll
            for (int j = 0; j < 4; ++j)
                acc4[j] = fmaf(xls[(q + 4 * j) * 65 + g], wa, acc4[j]);
        }
        float wb = Wr1b[cl];
#pragma unroll
        for (int j = 0; j < 4; ++j) {
            float av = acc4[j];
            float rr = (av / (1.f + expf(-av))) * wb;
            rr += __shfl_down(rr, 8);
            rr += __shfl_down(rr, 4);
            rr += __shfl_down(rr, 2);
            rr += __shfl_down(rr, 1);
            if (cl == 0) out[(size_t)sidx[i16 + q + 4 * j] * 2 + 1] = rr;
        }
    }

    short8 pvA[3][2];
#pragma unroll
    for (int k = 0; k < 3; ++k) {
#pragma unroll
        for (int t = 0; t < 4; ++t)
#pragma unroll
            for (int r = 0; r < 4; ++r)
                xls[(q * 4 + r) * 65 + t * 16 + cl] = pvsD[t][r] * vD[k][t][r];
#pragma unroll
        for (int h = 0; h < 2; ++h) {
            const float* rp = xls + cl * 65 + h * 32 + q * 8;
            float t0 = rp[0], t1 = rp[1], t2 = rp[2], t3 = rp[3];
            float t4 = rp[4], t5 = rp[5], t6 = rp[6], t7 = rp[7];
            pvA[k][h] = cvt8(make_float4(t0, t1, t2, t3), make_float4(t4, t5, t6, t7));
        }
    }

    f32x4 vnD[3][4];
#pragma unroll
    for (int k = 0; k < 3; ++k)
#pragma unroll
        for (int t = 0; t < 4; ++t) vnD[k][t] = (f32x4){0.f, 0.f, 0.f, 0.f};
#pragma unroll
    for (int t = 0; t < 4; ++t)
#pragma unroll
        for (int h = 0; h < 2; ++h) {
            short8 b = loadB(pWpv, t, h, l);
#pragma unroll
            for (int k = 0; k < 3; ++k) vnD[k][t] = MFMA16(pvA[k][h], b, vnD[k][t]);
        }
    if (has_skip) {
        const unsigned short* prow = svp + (size_t)(i16 + cl) * 256;
        short8 Aiv[3][2];
        unpack_v(prow, q * 8, Aiv, 0);
        unpack_v(prow, 32 + q * 8, Aiv, 1);
        int myz = spec_srt[i16 + cl];
        for (int z = z0; z <= z1; ++z) {
            bool keep = (myz == z);
            const short* pz = pSkV + (size_t)z * 4096;
#pragma unroll
            for (int t = 0; t < 4; ++t)
#pragma unroll
                for (int h = 0; h < 2; ++h) {
                    short8 b = loadB(pz, t, h, l);
#pragma unroll
                    for (int k = 0; k < 3; ++k) {
                        short8 a = keep ? Aiv[k][h] : z8;
                        vnD[k][t] = MFMA16(a, b, vnD[k][t]);
                    }
                }
        }
    }

    // ---- state store: ONLY at it==0 (state dead after last interaction).
    if (it == 0) {
#pragma unroll
        for (int t = 0; t < 4; ++t)
#pragma unroll
            for (int r = 0; r < 4; ++r) {
                uint2 pk;
                pk.x = cvt2u(snD[t][r], vnD[0][t][r]);
                pk.y = cvt2u(vnD[1][t][r], vnD[2][t][r]);
                *(uint2*)(svp + ((size_t)(i16 + q * 4 + r) * 64 + t * 16 + cl) * 4) = pk;
            }
    }

    // ---- it==0: zero this wave's own agg boundary rows for interaction 1.
    if (it == 0) {
        for (int rr = 0; rr < 16; ++rr) {
            int i = i16 + rr;
            int beg = row_start[i], end = row_start[i + 1];
            bool need = (end == beg) || (end > (((beg >> 4) + 1) << 4));
            if (need) {
                float* as = (float*)agg_s;
                float* av = (float*)agg_v;
                as[(size_t)i * 64 + l] = 0.f;
                av[((size_t)i * 3 + 0) * 64 + l] = 0.f;
                av[((size_t)i * 3 + 1) * 64 + l] = 0.f;
                av[((size_t)i * 3 + 2) * 64 + l] = 0.f;
            }
        }
    }
}

// ---------------------------------------------------------------------------
extern "C" void kernel_launch(void* const* d_in, const int* in_sizes, int n_in,
                              void* d_out, int out_size, void* d_ws, size_t ws_size,
                              hipStream_t stream)
{
    const float* vectors = (const float*)d_in[0];
    const float* embed_s = (const float*)d_in[1];
    const float* Wr      = (const float*)d_in[2];   // [2,8,320]
    const float* Wls     = (const float*)d_in[3];   // [2,64,64]
    const float* Wlv     = (const float*)d_in[4];
    const float* skip_s  = (const float*)d_in[5];   // [10,64,64]
    const float* skip_v  = (const float*)d_in[6];
    const float* pw      = (const float*)d_in[7];   // [2,10,9,64]
    const float* Wps     = (const float*)d_in[8];
    const float* Wpv     = (const float*)d_in[9];
    const float* Wread0  = (const float*)d_in[10];  // [64,1]
    const float* Wr1a    = (const float*)d_in[11];  // [64,16]
    const float* Wr1b    = (const float*)d_in[12];  // [16,1]
    const int* senders   = (const int*)d_in[13];
    const int* receivers = (const int*)d_in[14];
    const int* species   = (const int*)d_in[15];
    float* out = (float*)d_out;

    float* ws = (float*)d_ws;
    float* edata = ws; ws += (size_t)N_EDGES * 16;  // 16 MB (slot-ordered)
    float* agg_s = ws; ws += (size_t)N_NODES * 64;  // 8 MB
    float* agg_v = ws; ws += (size_t)N_NODES * 192; // 24 MB
    unsigned short* svp = (unsigned short*)ws; ws += (size_t)N_NODES * 128; // 16 MB packed {s,v0,v1,v2} bf16
    int* counts    = (int*)ws; ws += N_NODES;
    int* row_start = (int*)ws; ws += N_NODES + 4;
    int* cursor    = (int*)ws; ws += N_NODES;
    int* rrank     = (int*)ws; ws += N_EDGES;       // cached rank[receivers[e]]
    int* srk       = (int*)ws; ws += N_EDGES;
    int* grp_row   = (int*)ws; ws += N_EDGES / 16;
    int* sidx      = (int*)ws; ws += N_NODES;
    int* rank      = (int*)ws; ws += N_NODES;
    int* spec_srt  = (int*)ws; ws += N_NODES;
    int* lrank_arr = (int*)ws; ws += N_NODES;       // reused as rsp after sort3
    int* counts_blk = (int*)ws; ws += 128 * NSPEC;
    int* off_blk    = (int*)ws; ws += 128 * NSPEC;
    short* packW   = (short*)ws;                    // 224 KB

    // species counting sort (sort1 also zeroes CSR counts; sort3 fuses rsp)
    sort1_kernel<<<N_NODES / 256, 256, 0, stream>>>(
        species, counts_blk, lrank_arr, counts);
    sort2_kernel<<<1, 640, 0, stream>>>(counts_blk, off_blk);
    sort3_kernel<<<N_NODES / 256, 256, 0, stream>>>(
        species, lrank_arr, off_blk, sidx, rank, spec_srt);

    // receiver CSR in sorted space (hist caches rrank for the mega kernel)
    hist_kernel<<<N_EDGES / 256, 256, 0, stream>>>(receivers, rank, counts, rrank);
    scan_kernel<<<1, 1024, 0, stream>>>(counts, row_start, cursor);

    // MEGA: edge scatter + features + srk + weight pack + zero_bnd + grp_row
    mega_kernel<<<N_EDGES / 256, 256, 0, stream>>>(
        vectors, senders, lrank_arr /*rsp*/, rrank, cursor, row_start,
        edata, srk, grp_row,
        Wls, Wlv, Wps, Wpv, skip_s, skip_v, packW, agg_s, agg_v);

    // interaction 0 (gather reads embed table; node fuses read0 + re-zeroing
    // and writes the packed state for interaction 1's gather)
    gather_kernel<1><<<N_EDGES / 32, 64, 0, stream>>>(
        edata, srk, row_start, grp_row, embed_s, svp, Wr, agg_s, agg_v);
    node_mfma_kernel<<<N_NODES / 64, 256, 0, stream>>>(
        agg_s, agg_v, svp, packW, 0, pw, spec_srt,
        row_start, sidx, Wread0, Wr1a, Wr1b, out, 0);

    // interaction 1 (packed bf16 state: ONE 8-B random load per edge/lane)
    gather_kernel<0><<<N_EDGES / 32, 64, 0, stream>>>(
        edata, srk, row_start, grp_row, embed_s, svp, Wr + 2560, agg_s, agg_v);
    node_mfma_kernel<<<N_NODES / 64, 256, 0, stream>>>(
        agg_s, agg_v, svp, packW, 1, pw + 5760, spec_srt,
        row_start, sidx, Wread0, Wr1a, Wr1b, out, 1);
}

// Round 10
// 268.559 us; speedup vs baseline: 1.2439x; 1.0181x over previous
//
#include <hip/hip_runtime.h>
#include <hip/hip_bf16.h>
#include <math.h>

#define N_NODES 32768
#define N_EDGES 262144
#define EPS_C 0.24253562503633297f   // 1/sqrt(17)
#define NSPEC 10

typedef __attribute__((ext_vector_type(8))) short short8;   // 8 bf16
typedef __attribute__((ext_vector_type(4))) float f32x4;    // 4 fp32 acc

#define MFMA16(a, b, c) __builtin_amdgcn_mfma_f32_16x16x32_bf16(a, b, c, 0, 0, 0)

__device__ __forceinline__ short2 cvt2(float a, float b) {
    union { __hip_bfloat162 h; short2 s; } u;
    u.h = __float22bfloat162_rn(make_float2(a, b));
    return u.s;
}
__device__ __forceinline__ unsigned cvt2u(float a, float b) {
    union { __hip_bfloat162 h; unsigned u; } u;
    u.h = __float22bfloat162_rn(make_float2(a, b));
    return u.u;   // lo16 = bf(a), hi16 = bf(b)
}
__device__ __forceinline__ unsigned short f2bf(float a) {
    return (unsigned short)cvt2(a, 0.f).x;
}
__device__ __forceinline__ float bf2f(unsigned short u) {
    return __uint_as_float(((unsigned)u) << 16);
}
__device__ __forceinline__ short8 cvt8(float4 a, float4 b) {
    short2 p0 = cvt2(a.x, a.y), p1 = cvt2(a.z, a.w);
    short2 p2 = cvt2(b.x, b.y), p3 = cvt2(b.z, b.w);
    short8 r;
    r[0] = p0.x; r[1] = p0.y; r[2] = p1.x; r[3] = p1.y;
    r[4] = p2.x; r[5] = p2.y; r[6] = p3.x; r[7] = p3.y;
    return r;
}
__device__ __forceinline__ short8 loadArow(const float* rowp, int h, int q) {
    const float* p = rowp + h * 32 + q * 8;
    return cvt8(*(const float4*)p, *(const float4*)(p + 4));
}
__device__ __forceinline__ short8 loadB(const short* P, int t, int h, int l) {
    return *(const short8*)(P + (((t * 2 + h) * 64 + l) << 3));
}

// packed state svp[node][64 ch][4] = ushort4 {s, v0, v1, v2} (bf16 bits).
__device__ __forceinline__ short8 unpack_s(const unsigned short* prow, int ch0) {
    const uint4* p = (const uint4*)(prow + ch0 * 4);
    uint4 u0 = p[0], u1 = p[1], u2 = p[2], u3 = p[3];
    short8 r;
    r[0] = (short)(u0.x & 0xffff); r[1] = (short)(u0.z & 0xffff);
    r[2] = (short)(u1.x & 0xffff); r[3] = (short)(u1.z & 0xffff);
    r[4] = (short)(u2.x & 0xffff); r[5] = (short)(u2.z & 0xffff);
    r[6] = (short)(u3.x & 0xffff); r[7] = (short)(u3.z & 0xffff);
    return r;
}
__device__ __forceinline__ void unpack_v(const unsigned short* prow, int ch0,
                                         short8 (&Aiv)[3][2], int h) {
    const uint4* p = (const uint4*)(prow + ch0 * 4);
    uint4 u0 = p[0], u1 = p[1], u2 = p[2], u3 = p[3];
    Aiv[0][h][0] = (short)(u0.x >> 16); Aiv[0][h][1] = (short)(u0.z >> 16);
    Aiv[0][h][2] = (short)(u1.x >> 16); Aiv[0][h][3] = (short)(u1.z >> 16);
    Aiv[0][h][4] = (short)(u2.x >> 16); Aiv[0][h][5] = (short)(u2.z >> 16);
    Aiv[0][h][6] = (short)(u3.x >> 16); Aiv[0][h][7] = (short)(u3.z >> 16);
    Aiv[1][h][0] = (short)(u0.y & 0xffff); Aiv[1][h][1] = (short)(u0.w & 0xffff);
    Aiv[1][h][2] = (short)(u1.y & 0xffff); Aiv[1][h][3] = (short)(u1.w & 0xffff);
    Aiv[1][h][4] = (short)(u2.y & 0xffff); Aiv[1][h][5] = (short)(u2.w & 0xffff);
    Aiv[1][h][6] = (short)(u3.y & 0xffff); Aiv[1][h][7] = (short)(u3.w & 0xffff);
    Aiv[2][h][0] = (short)(u0.y >> 16); Aiv[2][h][1] = (short)(u0.w >> 16);
    Aiv[2][h][2] = (short)(u1.y >> 16); Aiv[2][h][3] = (short)(u1.w >> 16);
    Aiv[2][h][4] = (short)(u2.y >> 16); Aiv[2][h][5] = (short)(u2.w >> 16);
    Aiv[2][h][6] = (short)(u3.y >> 16); Aiv[2][h][7] = (short)(u3.w >> 16);
}

// ---------------------------------------------------------------------------
// Species counting sort — contention-free, deterministic. sort1 also zeroes
// the receiver-CSR counts array.
// ---------------------------------------------------------------------------
__global__ __launch_bounds__(256) void sort1_kernel(
    const int* __restrict__ species, int* __restrict__ counts_blk,
    int* __restrict__ lrank_arr, int* __restrict__ counts)
{
    __shared__ int wcnt[4][16];
    int n = blockIdx.x * 256 + threadIdx.x;
    counts[n] = 0;
    int sp = species[n];
    int lane = threadIdx.x & 63, wv = threadIdx.x >> 6;
    unsigned long long ltmask = (1ull << lane) - 1;
    int lrank_w = 0;
#pragma unroll
    for (int z = 0; z < NSPEC; ++z) {
        unsigned long long m = __ballot(sp == z);
        if (sp == z) lrank_w = __popcll(m & ltmask);
        if (lane == 0) wcnt[wv][z] = __popcll(m);
    }
    __syncthreads();
    int off = 0;
    for (int w = 0; w < wv; ++w) off += wcnt[w][sp];
    lrank_arr[n] = lrank_w + off;
    if (threadIdx.x < NSPEC)
        counts_blk[blockIdx.x * NSPEC + threadIdx.x] =
            wcnt[0][threadIdx.x] + wcnt[1][threadIdx.x] +
            wcnt[2][threadIdx.x] + wcnt[3][threadIdx.x];
}

// parallel block-offset scan: wave z shuffle-scans its 128 block counts
__global__ __launch_bounds__(640) void sort2_kernel(
    const int* __restrict__ counts_blk, int* __restrict__ off_blk)
{
    __shared__ int totals[16];
    int wv = threadIdx.x >> 6;        // 0..9 == species z
    int lane = threadIdx.x & 63;
    int c0 = counts_blk[lane * NSPEC + wv];
    int c1 = counts_blk[(64 + lane) * NSPEC + wv];
    int s0 = c0;
#pragma unroll
    for (int off = 1; off < 64; off <<= 1) {
        int y = __shfl_up(s0, off);
        if (lane >= off) s0 += y;
    }
    int tot0 = __shfl(s0, 63);
    int s1 = c1;
#pragma unroll
    for (int off = 1; off < 64; off <<= 1) {
        int y = __shfl_up(s1, off);
        if (lane >= off) s1 += y;
    }
    s1 += tot0;
    if (lane == 63) totals[wv] = s1;
    __syncthreads();
    int base = 0;
    for (int q = 0; q < wv; ++q) base += totals[q];
    off_blk[lane * NSPEC + wv] = base + s0 - c0;
    off_blk[(64 + lane) * NSPEC + wv] = base + s1 - c1;
}

// sort3 also fuses rsp[n] = rank | species<<16 (written into the retired
// lrank_arr buffer) so mega's srk build needs ONE random read, not two.
__global__ __launch_bounds__(256) void sort3_kernel(
    const int* __restrict__ species, int* __restrict__ lrank_arr,
    const int* __restrict__ off_blk,
    int* __restrict__ sidx, int* __restrict__ rank, int* __restrict__ spec_srt)
{
    int n = blockIdx.x * 256 + threadIdx.x;
    int sp = species[n];
    int slot = off_blk[blockIdx.x * NSPEC + sp] + lrank_arr[n];
    sidx[slot] = n;
    rank[n] = slot;
    spec_srt[slot] = sp;
    lrank_arr[n] = slot | (sp << 16);   // rsp (each thread owns index n)
}

// ---------------------------------------------------------------------------
// Receiver CSR in SORTED space. hist also caches rrank[e] so the mega kernel
// re-reads it COALESCED instead of repeating the random load.
// ---------------------------------------------------------------------------
__global__ __launch_bounds__(256) void hist_kernel(
    const int* __restrict__ receivers, const int* __restrict__ rank,
    int* __restrict__ counts, int* __restrict__ rrank)
{
    int e = blockIdx.x * 256 + threadIdx.x;
    int rr = rank[receivers[e]];
    atomicAdd(&counts[rr], 1);
    rrank[e] = rr;
}

__global__ __launch_bounds__(1024) void scan_kernel(
    const int* __restrict__ counts, int* __restrict__ row_start, int* __restrict__ cursor)
{
    __shared__ int wave_tot[16];
    int tid = threadIdx.x;
    int c[32];
    int sum = 0;
#pragma unroll
    for (int i = 0; i < 32; ++i) { c[i] = counts[tid * 32 + i]; sum += c[i]; }
    int lane = tid & 63, wv = tid >> 6;
    int x = sum;
#pragma unroll
    for (int off = 1; off < 64; off <<= 1) {
        int y = __shfl_up(x, off);
        if (lane >= off) x += y;
    }
    if (lane == 63) wave_tot[wv] = x;
    __syncthreads();
    if (wv == 0 && lane < 16) {
        int t = wave_tot[lane];
#pragma unroll
        for (int off = 1; off < 16; off <<= 1) {
            int y = __shfl_up(t, off);
            if (lane >= off) t += y;
        }
        wave_tot[lane] = t;
    }
    __syncthreads();
    int excl = x - sum + (wv ? wave_tot[wv - 1] : 0);
    int run = excl;
#pragma unroll
    for (int i = 0; i < 32; ++i) {
        row_start[tid * 32 + i] = run;
        cursor[tid * 32 + i] = run;
        run += c[i];
    }
    if (tid == 1023) row_start[32768] = run;
}

// ---------------------------------------------------------------------------
// MEGA kernel: scatter + edge features + weight pack + zero_bnd + grp_row.
// r10: edata compressed 64B -> 32B/edge: {f32 y0,y1,y2, 8x bf16 rbf, pad}.
// y stays exact fp32; rbf rounds to bf16 (RNE) — same error class as the
// bf16 state rounding already in the pipeline (everything downstream of rbf
// is multiplied into bf16-rounded quantities anyway).
// ---------------------------------------------------------------------------
__global__ __launch_bounds__(256) void mega_kernel(
    const float* __restrict__ vectors, const int* __restrict__ senders,
    const int* __restrict__ rsp,
    const int* __restrict__ rrank, int* __restrict__ cursor,
    const int* __restrict__ row_start,
    float* __restrict__ edata, int* __restrict__ srk, int* __restrict__ grp_row,
    const float* __restrict__ Wls, const float* __restrict__ Wlv,
    const float* __restrict__ Wps, const float* __restrict__ Wpv,
    const float* __restrict__ skip_s, const float* __restrict__ skip_v,
    short* __restrict__ packW,
    float* __restrict__ agg_s, float* __restrict__ agg_v)
{
    const int idx = blockIdx.x * 256 + threadIdx.x;   // == edge id e
    const int e = idx;

    // ---- edge: slot assignment + features (vectors read coalesced)
    int rr = rrank[e];
    int slot = atomicAdd(&cursor[rr], 1);
    srk[slot] = rsp[senders[e]];
    float x = vectors[e * 3 + 0], y = vectors[e * 3 + 1], z = vectors[e * 3 + 2];
    float r2 = x * x + y * y + z * z + 1e-12f;
    float r = sqrtf(r2);
    float inv = 1.0f / r;
    float rc = fmaxf(r, 1e-6f);
    float r6 = r2 * r2 * r2;
    float r7 = r6 * r;
    float r8 = r6 * r2;
    float env = (r < 1.0f) ? (1.0f - 28.0f * r6 + 48.0f * r7 - 21.0f * r8) : 0.0f;
    float sc = 1.41421356237309515f * env / rc;
    float xr = 3.14159265358979323846f * rc;
    float s1, c1;
    sincosf(xr, &s1, &c1);
    float tc = 2.0f * c1;
    float s2 = tc * s1;              // s0 = sin(0) = 0
    float s3 = tc * s2 - s1;
    float s4 = tc * s3 - s2;
    float s5 = tc * s4 - s3;
    float s6 = tc * s5 - s4;
    float s7 = tc * s6 - s5;
    float s8 = tc * s7 - s6;
    unsigned rb01 = cvt2u(sc * s1, sc * s2);
    unsigned rb23 = cvt2u(sc * s3, sc * s4);
    unsigned rb45 = cvt2u(sc * s5, sc * s6);
    unsigned rb67 = cvt2u(sc * s7, sc * s8);
    float* d = edata + (size_t)slot * 8;   // 32 B/edge
    *(float4*)d = make_float4(x * inv, y * inv, z * inv, __uint_as_float(rb01));
    *(float4*)(d + 4) = make_float4(__uint_as_float(rb23), __uint_as_float(rb45),
                                    __uint_as_float(rb67), 0.f);

    // ---- weight pack (identical mapping to original prep_kernel)
    if (idx < 28 * 4096) {
        int m = idx >> 12, ee = idx & 4095;
        int t = ee >> 10, h = (ee >> 9) & 1, l = (ee >> 3) & 63, j = ee & 7;
        int fi = h * 32 + ((l >> 4) << 3) + j;
        int fo = t * 16 + (l & 15);
        const float* src;
        if      (m < 2)  src = Wls    + m * 4096;
        else if (m < 4)  src = Wlv    + (m - 2) * 4096;
        else if (m < 6)  src = Wps    + (m - 4) * 4096;
        else if (m < 8)  src = Wpv    + (m - 6) * 4096;
        else if (m < 18) src = skip_s + (m - 8) * 4096;
        else             src = skip_v + (m - 18) * 4096;
        packW[idx] = cvt2(src[fi * 64 + fo], 0.f).x;
    }

    // ---- zero boundary agg rows for interaction 0 (8 nodes per wave)
    {
        const int wid = threadIdx.x >> 6;
        const int f = threadIdx.x & 63;
        const int gw = blockIdx.x * 4 + wid;      // 0..4095
#pragma unroll
        for (int t = 0; t < 8; ++t) {
            int i = gw * 8 + t;
            int beg = row_start[i], end = row_start[i + 1];
            bool need = (end == beg) || (end > (((beg >> 4) + 1) << 4));
            if (need) {
                agg_s[(size_t)i * 64 + f] = 0.f;
                agg_v[((size_t)i * 3 + 0) * 64 + f] = 0.f;
                agg_v[((size_t)i * 3 + 1) * 64 + f] = 0.f;
                agg_v[((size_t)i * 3 + 2) * 64 + f] = 0.f;
            }
        }
    }

    // ---- grp_row binary search (first 16384 threads)
    if (idx < N_EDGES / 16) {
        int target = idx * 16;
        int lo = 0, hi = N_NODES - 1;
        while (lo < hi) {
            int mid = (lo + hi + 1) >> 1;
            if (row_start[mid] <= target) lo = mid; else hi = mid - 1;
        }
        grp_row[idx] = lo;
    }
}

// unpack 8 bf16 rbf values from the packed edata words
__device__ __forceinline__ void unpack_rb(float4 e0, float4 e1, float (&rb)[8]) {
    unsigned u0 = __float_as_uint(e0.w);
    unsigned u1 = __float_as_uint(e1.x);
    unsigned u2 = __float_as_uint(e1.y);
    unsigned u3 = __float_as_uint(e1.z);
    rb[0] = __uint_as_float(u0 << 16); rb[1] = __uint_as_float(u0 & 0xffff0000u);
    rb[2] = __uint_as_float(u1 << 16); rb[3] = __uint_as_float(u1 & 0xffff0000u);
    rb[4] = __uint_as_float(u2 << 16); rb[5] = __uint_as_float(u2 & 0xffff0000u);
    rb[6] = __uint_as_float(u3 << 16); rb[7] = __uint_as_float(u3 & 0xffff0000u);
}

// ---------------------------------------------------------------------------
// Dual-chain edge-balanced gather, 1 wave/block.
// DO NOT use multi-wave workgroups here (r1/r3: spills, occupancy flat).
// sched_barrier(0) per iteration pins the stage-3 random-state issue before
// iteration k's compute (r9; r8's VGPR=48 showed the compiler sinking the
// staged loads to consume sites, collapsing the pipeline to ~2-3 loads in
// flight — Little's law matched the measured 2-2.8 TB/s).
// r10: edata is 32B/edge {f32 y, 8x bf16 rbf} — 2 loads/edge (was 3),
// half the streaming FETCH. Spill tripwire: WRITE_SIZE > 47MB -> revert.
// ---------------------------------------------------------------------------
template<int VZERO>
__global__ __launch_bounds__(64, 4) void gather_kernel(
    const float* __restrict__ edata, const int* __restrict__ srk,
    const int* __restrict__ row_start, const int* __restrict__ grp_row,
    const float* __restrict__ embed_s,
    const unsigned short* __restrict__ svp,
    const float* __restrict__ Wr_i,
    float* __restrict__ agg_s, float* __restrict__ agg_v)
{
    const int f = threadIdx.x & 63;
    const int w = blockIdx.x;
    const int pA0 = w * 32;
    const int pB0 = pA0 + 16;

    float wr[5][8];
#pragma unroll
    for (int j = 0; j < 8; ++j)
#pragma unroll
        for (int p = 0; p < 5; ++p)
            wr[p][j] = (VZERO && (p == 1 || p == 3 || p == 4))
                       ? 0.f : Wr_i[j * 320 + p * 64 + f];

    int rA = grp_row[2 * w], rB = grp_row[2 * w + 1];
    int begA = row_start[rA], endA = row_start[rA + 1];
    int begB = row_start[rB], endB = row_start[rB + 1];
    float aA0 = 0.f, aA1 = 0.f, aA2 = 0.f, aA3 = 0.f;
    float aB0 = 0.f, aB1 = 0.f, aB2 = 0.f, aB3 = 0.f;

    int svHA = srk[pA0 + 3], svHB = srk[pB0 + 3];
    uint2 pa0 = {0,0}, pa1 = {0,0}, pa2 = {0,0};
    uint2 pb0 = {0,0}, pb1 = {0,0}, pb2 = {0,0};
    float fa0 = 0.f, fa1 = 0.f, fa2 = 0.f, fb0 = 0.f, fb1 = 0.f, fb2 = 0.f;
    {
        int sA0 = srk[pA0], sA1 = srk[pA0 + 1], sA2 = srk[pA0 + 2];
        int sB0 = srk[pB0], sB1 = srk[pB0 + 1], sB2 = srk[pB0 + 2];
        if (VZERO) {
            fa0 = embed_s[(sA0 >> 16) * 64 + f];
            fa1 = embed_s[(sA1 >> 16) * 64 + f];
            fa2 = embed_s[(sA2 >> 16) * 64 + f];
            fb0 = embed_s[(sB0 >> 16) * 64 + f];
            fb1 = embed_s[(sB1 >> 16) * 64 + f];
            fb2 = embed_s[(sB2 >> 16) * 64 + f];
        } else {
            pa0 = *(const uint2*)(svp + (((size_t)(sA0 & 0xFFFF)) * 64 + f) * 4);
            pa1 = *(const uint2*)(svp + (((size_t)(sA1 & 0xFFFF)) * 64 + f) * 4);
            pa2 = *(const uint2*)(svp + (((size_t)(sA2 & 0xFFFF)) * 64 + f) * 4);
            pb0 = *(const uint2*)(svp + (((size_t)(sB0 & 0xFFFF)) * 64 + f) * 4);
            pb1 = *(const uint2*)(svp + (((size_t)(sB1 & 0xFFFF)) * 64 + f) * 4);
            pb2 = *(const uint2*)(svp + (((size_t)(sB2 & 0xFFFF)) * 64 + f) * 4);
        }
    }
    const float* dA0p = edata + (size_t)pA0 * 8;
    const float* dB0p = edata + (size_t)pB0 * 8;
    float4 eA0 = *(const float4*)dA0p;
    float4 eA1 = *(const float4*)(dA0p + 4);
    float4 eB0 = *(const float4*)dB0p;
    float4 eB1 = *(const float4*)(dB0p + 4);

#pragma unroll
    for (int k = 0; k < 16; ++k) {
        const int pA = pA0 + k, pB = pB0 + k;

        int svNA = svHA, svNB = svHB;
        if (k < 12) {
            svNA = srk[pA + 4];
            svNB = srk[pB + 4];
        }

        // issue stage-3 state loads (edge k+3) — raw bits, no conversion
        uint2 pa3 = {0, 0}, pb3 = {0, 0};
        float fa3 = 0.f, fb3 = 0.f;
        if (k < 13) {
            if (VZERO) {
                fa3 = embed_s[(svHA >> 16) * 64 + f];
                fb3 = embed_s[(svHB >> 16) * 64 + f];
            } else {
                pa3 = *(const uint2*)(svp + (((size_t)(svHA & 0xFFFF)) * 64 + f) * 4);
                pb3 = *(const uint2*)(svp + (((size_t)(svHB & 0xFFFF)) * 64 + f) * 4);
            }
        }

        // pin: stage-3 issues may not sink below this point (r9)
        __builtin_amdgcn_sched_barrier(0);

        // edata prefetch for edge k+1 (after the barrier: allocator-flexible)
        float4 eA0n = eA0, eA1n = eA1, eB0n = eB0, eB1n = eB1;
        if (k < 15) {
            const float* dAn = edata + (size_t)(pA + 1) * 8;
            const float* dBn = edata + (size_t)(pB + 1) * 8;
            eA0n = *(const float4*)dAn;
            eA1n = *(const float4*)(dAn + 4);
            eB0n = *(const float4*)dBn;
            eB1n = *(const float4*)(dBn + 4);
        }

        float rbA[8], rbB[8];
        unpack_rb(eA0, eA1, rbA);
        unpack_rb(eB0, eB1, rbB);
        const float yAx = eA0.x, yAy = eA0.y, yAz = eA0.z;
        const float yBx = eB0.x, yBy = eB0.y, yBz = eB0.z;
        float wA0 = 0.f, wA1 = 0.f, wA2 = 0.f, wA3 = 0.f, wA4 = 0.f;
        float wB0 = 0.f, wB1 = 0.f, wB2 = 0.f, wB3 = 0.f, wB4 = 0.f;
#pragma unroll
        for (int j = 0; j < 8; ++j) {
            wA0 = fmaf(rbA[j], wr[0][j], wA0);  wB0 = fmaf(rbB[j], wr[0][j], wB0);
            if (!VZERO) { wA1 = fmaf(rbA[j], wr[1][j], wA1);  wB1 = fmaf(rbB[j], wr[1][j], wB1); }
            wA2 = fmaf(rbA[j], wr[2][j], wA2);  wB2 = fmaf(rbB[j], wr[2][j], wB2);
            if (!VZERO) { wA3 = fmaf(rbA[j], wr[3][j], wA3);  wB3 = fmaf(rbB[j], wr[3][j], wB3); }
            if (!VZERO) { wA4 = fmaf(rbA[j], wr[4][j], wA4);  wB4 = fmaf(rbB[j], wr[4][j], wB4); }
        }

        if (VZERO) {
            float ssA = fa0, ssB = fb0;
            aA0 += wA0 * ssA;
            float wsA = wA2 * ssA;
            aA1 += wsA * yAx; aA2 += wsA * yAy; aA3 += wsA * yAz;
            aB0 += wB0 * ssB;
            float wsB = wB2 * ssB;
            aB1 += wsB * yBx; aB2 += wsB * yBy; aB3 += wsB * yBz;
        } else {
            float ssA = __uint_as_float(pa0.x << 16);
            float va0 = __uint_as_float(pa0.x & 0xffff0000u);
            float va1 = __uint_as_float(pa0.y << 16);
            float va2 = __uint_as_float(pa0.y & 0xffff0000u);
            float ssB = __uint_as_float(pb0.x << 16);
            float vb0 = __uint_as_float(pb0.x & 0xffff0000u);
            float vb1 = __uint_as_float(pb0.y << 16);
            float vb2 = __uint_as_float(pb0.y & 0xffff0000u);
            float dotA = va0 * yAx + va1 * yAy + va2 * yAz;
            aA0 += wA0 * ssA + wA1 * dotA;
            float cA0 = va1 * yAz - va2 * yAy;
            float cA1 = va2 * yAx - va0 * yAz;
            float cA2 = va0 * yAy - va1 * yAx;
            float wsA = wA2 * ssA;
            aA1 += wsA * yAx + wA3 * va0 + wA4 * cA0;
            aA2 += wsA * yAy + wA3 * va1 + wA4 * cA1;
            aA3 += wsA * yAz + wA3 * va2 + wA4 * cA2;
            float dotB = vb0 * yBx + vb1 * yBy + vb2 * yBz;
            aB0 += wB0 * ssB + wB1 * dotB;
            float cB0 = vb1 * yBz - vb2 * yBy;
            float cB1 = vb2 * yBx - vb0 * yBz;
            float cB2 = vb0 * yBy - vb1 * yBx;
            float wsB = wB2 * ssB;
            aB1 += wsB * yBx + wB3 * vb0 + wB4 * cB0;
            aB2 += wsB * yBy + wB3 * vb1 + wB4 * cB1;
            aB3 += wsB * yBz + wB3 * vb2 + wB4 * cB2;
        }

        if (pA + 1 == endA || k == 15) {
            bool interior = (begA >= pA0) && (endA <= pA0 + 16);
            if (interior) {
                agg_s[(size_t)rA * 64 + f] = aA0;
                agg_v[((size_t)rA * 3 + 0) * 64 + f] = aA1;
                agg_v[((size_t)rA * 3 + 1) * 64 + f] = aA2;
                agg_v[((size_t)rA * 3 + 2) * 64 + f] = aA3;
            } else {
                unsafeAtomicAdd(&agg_s[(size_t)rA * 64 + f], aA0);
                unsafeAtomicAdd(&agg_v[((size_t)rA * 3 + 0) * 64 + f], aA1);
                unsafeAtomicAdd(&agg_v[((size_t)rA * 3 + 1) * 64 + f], aA2);
                unsafeAtomicAdd(&agg_v[((size_t)rA * 3 + 2) * 64 + f], aA3);
            }
            aA0 = aA1 = aA2 = aA3 = 0.f;
            if (pA + 1 == endA && k < 15) {
                begA = endA; ++rA; endA = row_start[rA + 1];
                while (endA == begA) { ++rA; endA = row_start[rA + 1]; }
            }
        }
        if (pB + 1 == endB || k == 15) {
            bool interior = (begB >= pB0) && (endB <= pB0 + 16);
            if (interior) {
                agg_s[(size_t)rB * 64 + f] = aB0;
                agg_v[((size_t)rB * 3 + 0) * 64 + f] = aB1;
                agg_v[((size_t)rB * 3 + 1) * 64 + f] = aB2;
                agg_v[((size_t)rB * 3 + 2) * 64 + f] = aB3;
            } else {
                unsafeAtomicAdd(&agg_s[(size_t)rB * 64 + f], aB0);
                unsafeAtomicAdd(&agg_v[((size_t)rB * 3 + 0) * 64 + f], aB1);
                unsafeAtomicAdd(&agg_v[((size_t)rB * 3 + 1) * 64 + f], aB2);
                unsafeAtomicAdd(&agg_v[((size_t)rB * 3 + 2) * 64 + f], aB3);
            }
            aB0 = aB1 = aB2 = aB3 = 0.f;
            if (pB + 1 == endB && k < 15) {
                begB = endB; ++rB; endB = row_start[rB + 1];
                while (endB == begB) { ++rB; endB = row_start[rB + 1]; }
            }
        }

        pa0 = pa1; pa1 = pa2; pa2 = pa3;
        pb0 = pb1; pb1 = pb2; pb2 = pb3;
        fa0 = fa1; fa1 = fa2; fa2 = fa3;
        fb0 = fb1; fb1 = fb2; fb2 = fb3;
        svHA = svNA; svHB = svNB;
        eA0 = eA0n; eA1 = eA1n; eB0 = eB0n; eB1 = eB1n;
    }
}

// ---------------------------------------------------------------------------
// MFMA node kernel. State lives ONLY in packed svp[node][ch]=ushort4
// {s,v0,v1,v2} (bf16 bits, RNE). it==0 writes svp; it==1 reads svp for skip
// fragments and writes NOTHING (state dead after last interaction).
// ---------------------------------------------------------------------------
__global__ __launch_bounds__(256) void node_mfma_kernel(
    const float* __restrict__ agg_s, const float* __restrict__ agg_v,
    unsigned short* svp,
    const short* __restrict__ packW, int it,
    const float* __restrict__ pw_i,
    const int* __restrict__ spec_srt,
    const int* __restrict__ row_start, const int* __restrict__ sidx,
    const float* __restrict__ Wread0, const float* __restrict__ Wr1a,
    const float* __restrict__ Wr1b,
    float* __restrict__ out,
    int has_skip)
{
    const int l = threadIdx.x & 63;
    const int wid = threadIdx.x >> 6;
    const int cl = l & 15;
    const int q = l >> 4;
    const int i16 = (blockIdx.x * 4 + wid) * 16;
    __shared__ float xls_all[4][16 * 65];
    float* xls = xls_all[wid];

    const short* pWls = packW + (size_t)(0 + it) * 4096;
    const short* pWlv = packW + (size_t)(2 + it) * 4096;
    const short* pWps = packW + (size_t)(4 + it) * 4096;
    const short* pWpv = packW + (size_t)(6 + it) * 4096;
    const short* pSkS = packW + (size_t)8 * 4096;
    const short* pSkV = packW + (size_t)18 * 4096;
    const short8 z8 = {0, 0, 0, 0, 0, 0, 0, 0};

    const float* ars = agg_s + (size_t)(i16 + cl) * 64;
    short8 As[2] = { loadArow(ars, 0, q), loadArow(ars, 1, q) };
    short8 Av[3][2];
#pragma unroll
    for (int k = 0; k < 3; ++k) {
        const float* r = agg_v + ((size_t)(i16 + cl) * 3 + k) * 64;
        Av[k][0] = loadArow(r, 0, q);
        Av[k][1] = loadArow(r, 1, q);
    }

    f32x4 sD[4];
#pragma unroll
    for (int t = 0; t < 4; ++t) {
        f32x4 acc = {0.f, 0.f, 0.f, 0.f};
        acc = MFMA16(As[0], loadB(pWls, t, 0, l), acc);
        acc = MFMA16(As[1], loadB(pWls, t, 1, l), acc);
        sD[t] = acc;
    }

    f32x4 vD[3][4];
#pragma unroll
    for (int k = 0; k < 3; ++k)
#pragma unroll
        for (int t = 0; t < 4; ++t) vD[k][t] = (f32x4){0.f, 0.f, 0.f, 0.f};
#pragma unroll
    for (int t = 0; t < 4; ++t)
#pragma unroll
        for (int h = 0; h < 2; ++h) {
            short8 b = loadB(pWlv, t, h, l);
#pragma unroll
            for (int k = 0; k < 3; ++k) vD[k][t] = MFMA16(Av[k][h], b, vD[k][t]);
        }

    int z0 = spec_srt[i16], z1 = spec_srt[i16 + 15];
    float psD[4][4], pvsD[4][4];
    if (z0 == z1) {
        const float* pb = pw_i + z0 * 576 + cl;
        float pc[9][4];
#pragma unroll
        for (int c = 0; c < 9; ++c)
#pragma unroll
            for (int t = 0; t < 4; ++t) pc[c][t] = pb[c * 64 + t * 16];
#pragma unroll
        for (int t = 0; t < 4; ++t)
#pragma unroll
            for (int r = 0; r < 4; ++r) {
                float x = sD[t][r] * EPS_C;
                float w0 = vD[0][t][r] * EPS_C;
                float w1 = vD[1][t][r] * EPS_C;
                float w2 = vD[2][t][r] * EPS_C;
                vD[0][t][r] = w0; vD[1][t][r] = w1; vD[2][t][r] = w2;
                float vv = w0 * w0 + w1 * w1 + w2 * w2;
                float x2 = x * x;
                psD[t][r] = pc[0][t] * x + pc[1][t] * x2 + pc[2][t] * vv
                          + pc[3][t] * x2 * x + pc[4][t] * x * vv;
                pvsD[t][r] = pc[5][t] + pc[6][t] * x + pc[7][t] * x2 + pc[8][t] * vv;
            }
    } else {
#pragma unroll
        for (int r = 0; r < 4; ++r) {
            int z = spec_srt[i16 + q * 4 + r];
            const float* pb = pw_i + z * 576 + cl;
#pragma unroll
            for (int t = 0; t < 4; ++t) {
                float p0 = pb[t*16], p1 = pb[64+t*16], p2 = pb[128+t*16];
                float p3 = pb[192+t*16], p4 = pb[256+t*16], p5 = pb[320+t*16];
                float p6 = pb[384+t*16], p7 = pb[448+t*16], p8 = pb[512+t*16];
                float x = sD[t][r] * EPS_C;
                float w0 = vD[0][t][r] * EPS_C;
                float w1 = vD[1][t][r] * EPS_C;
                float w2 = vD[2][t][r] * EPS_C;
                vD[0][t][r] = w0; vD[1][t][r] = w1; vD[2][t][r] = w2;
                float vv = w0 * w0 + w1 * w1 + w2 * w2;
                float x2 = x * x;
                psD[t][r] = p0 * x + p1 * x2 + p2 * vv + p3 * x2 * x + p4 * x * vv;
                pvsD[t][r] = p5 + p6 * x + p7 * x2 + p8 * vv;
            }
        }
    }

#pragma unroll
    for (int t = 0; t < 4; ++t)
#pragma unroll
        for (int r = 0; r < 4; ++r)
            xls[(q * 4 + r) * 65 + t * 16 + cl] = psD[t][r];
    short8 psA[2];
#pragma unroll
    for (int h = 0; h < 2; ++h) {
        const float* rp = xls + cl * 65 + h * 32 + q * 8;
        float t0 = rp[0], t1 = rp[1], t2 = rp[2], t3 = rp[3];
        float t4 = rp[4], t5 = rp[5], t6 = rp[6], t7 = rp[7];
        psA[h] = cvt8(make_float4(t0, t1, t2, t3), make_float4(t4, t5, t6, t7));
    }

    f32x4 snD[4];
#pragma unroll
    for (int t = 0; t < 4; ++t) {
        f32x4 acc = {0.f, 0.f, 0.f, 0.f};
        acc = MFMA16(psA[0], loadB(pWps, t, 0, l), acc);
        acc = MFMA16(psA[1], loadB(pWps, t, 1, l), acc);
        snD[t] = acc;
    }
    if (has_skip) {
        const unsigned short* prow = svp + (size_t)(i16 + cl) * 256;
        short8 Ai0 = unpack_s(prow, q * 8);
        short8 Ai1 = unpack_s(prow, 32 + q * 8);
        int myz = spec_srt[i16 + cl];
        for (int z = z0; z <= z1; ++z) {
            bool keep = (myz == z);
            short8 m0 = keep ? Ai0 : z8;
            short8 m1 = keep ? Ai1 : z8;
            const short* pz = pSkS + (size_t)z * 4096;
#pragma unroll
            for (int t = 0; t < 4; ++t) {
                snD[t] = MFMA16(m0, loadB(pz, t, 0, l), snD[t]);
                snD[t] = MFMA16(m1, loadB(pz, t, 1, l), snD[t]);
            }
        }
    }

    // ---- fused readout (pre-rounded fp32 registers)
    if (it == 0) {
        float w0c[4];
#pragma unroll
        for (int t = 0; t < 4; ++t) w0c[t] = Wread0[t * 16 + cl];
#pragma unroll
        for (int r = 0; r < 4; ++r) {
            float a = snD[0][r] * w0c[0] + snD[1][r] * w0c[1]
                    + snD[2][r] * w0c[2] + snD[3][r] * w0c[3];
            a += __shfl_down(a, 8);
            a += __shfl_down(a, 4);
            a += __shfl_down(a, 2);
            a += __shfl_down(a, 1);
            if (cl == 0) out[(size_t)sidx[i16 + q * 4 + r] * 2 + 0] = a;
        }
    } else {
#pragma unroll
        for (int t = 0; t < 4; ++t)
#pragma unroll
            for (int r = 0; r < 4; ++r)
                xls[(q * 4 + r) * 65 + t * 16 + cl] = snD[t][r];
        float acc4[4] = {0.f, 0.f, 0.f, 0.f};
        for (int g = 0; g < 64; ++g) {
            float wa = Wr1a[g * 16 + cl];
#pragma unroll
            for (int j = 0; j < 4; ++j)
                acc4[j] = fmaf(xls[(q + 4 * j) * 65 + g], wa, acc4[j]);
        }
        float wb = Wr1b[cl];
#pragma unroll
        for (int j = 0; j < 4; ++j) {
            float av = acc4[j];
            float rr = (av / (1.f + expf(-av))) * wb;
            rr += __shfl_down(rr, 8);
            rr += __shfl_down(rr, 4);
            rr += __shfl_down(rr, 2);
            rr += __shfl_down(rr, 1);
            if (cl == 0) out[(size_t)sidx[i16 + q + 4 * j] * 2 + 1] = rr;
        }
    }

    short8 pvA[3][2];
#pragma unroll
    for (int k = 0; k < 3; ++k) {
#pragma unroll
        for (int t = 0; t < 4; ++t)
#pragma unroll
            for (int r = 0; r < 4; ++r)
                xls[(q * 4 + r) * 65 + t * 16 + cl] = pvsD[t][r] * vD[k][t][r];
#pragma unroll
        for (int h = 0; h < 2; ++h) {
            const float* rp = xls + cl * 65 + h * 32 + q * 8;
            float t0 = rp[0], t1 = rp[1], t2 = rp[2], t3 = rp[3];
            float t4 = rp[4], t5 = rp[5], t6 = rp[6], t7 = rp[7];
            pvA[k][h] = cvt8(make_float4(t0, t1, t2, t3), make_float4(t4, t5, t6, t7));
        }
    }

    f32x4 vnD[3][4];
#pragma unroll
    for (int k = 0; k < 3; ++k)
#pragma unroll
        for (int t = 0; t < 4; ++t) vnD[k][t] = (f32x4){0.f, 0.f, 0.f, 0.f};
#pragma unroll
    for (int t = 0; t < 4; ++t)
#pragma unroll
        for (int h = 0; h < 2; ++h) {
            short8 b = loadB(pWpv, t, h, l);
#pragma unroll
            for (int k = 0; k < 3; ++k) vnD[k][t] = MFMA16(pvA[k][h], b, vnD[k][t]);
        }
    if (has_skip) {
        const unsigned short* prow = svp + (size_t)(i16 + cl) * 256;
        short8 Aiv[3][2];
        unpack_v(prow, q * 8, Aiv, 0);
        unpack_v(prow, 32 + q * 8, Aiv, 1);
        int myz = spec_srt[i16 + cl];
        for (int z = z0; z <= z1; ++z) {
            bool keep = (myz == z);
            const short* pz = pSkV + (size_t)z * 4096;
#pragma unroll
            for (int t = 0; t < 4; ++t)
#pragma unroll
                for (int h = 0; h < 2; ++h) {
                    short8 b = loadB(pz, t, h, l);
#pragma unroll
                    for (int k = 0; k < 3; ++k) {
                        short8 a = keep ? Aiv[k][h] : z8;
                        vnD[k][t] = MFMA16(a, b, vnD[k][t]);
                    }
                }
        }
    }

    // ---- state store: ONLY at it==0 (state dead after last interaction).
    if (it == 0) {
#pragma unroll
        for (int t = 0; t < 4; ++t)
#pragma unroll
            for (int r = 0; r < 4; ++r) {
                uint2 pk;
                pk.x = cvt2u(snD[t][r], vnD[0][t][r]);
                pk.y = cvt2u(vnD[1][t][r], vnD[2][t][r]);
                *(uint2*)(svp + ((size_t)(i16 + q * 4 + r) * 64 + t * 16 + cl) * 4) = pk;
            }
    }

    // ---- it==0: zero this wave's own agg boundary rows for interaction 1.
    if (it == 0) {
        for (int rr = 0; rr < 16; ++rr) {
            int i = i16 + rr;
            int beg = row_start[i], end = row_start[i + 1];
            bool need = (end == beg) || (end > (((beg >> 4) + 1) << 4));
            if (need) {
                float* as = (float*)agg_s;
                float* av = (float*)agg_v;
                as[(size_t)i * 64 + l] = 0.f;
                av[((size_t)i * 3 + 0) * 64 + l] = 0.f;
                av[((size_t)i * 3 + 1) * 64 + l] = 0.f;
                av[((size_t)i * 3 + 2) * 64 + l] = 0.f;
            }
        }
    }
}

// ---------------------------------------------------------------------------
extern "C" void kernel_launch(void* const* d_in, const int* in_sizes, int n_in,
                              void* d_out, int out_size, void* d_ws, size_t ws_size,
                              hipStream_t stream)
{
    const float* vectors = (const float*)d_in[0];
    const float* embed_s = (const float*)d_in[1];
    const float* Wr      = (const float*)d_in[2];   // [2,8,320]
    const float* Wls     = (const float*)d_in[3];   // [2,64,64]
    const float* Wlv     = (const float*)d_in[4];
    const float* skip_s  = (const float*)d_in[5];   // [10,64,64]
    const float* skip_v  = (const float*)d_in[6];
    const float* pw      = (const float*)d_in[7];   // [2,10,9,64]
    const float* Wps     = (const float*)d_in[8];
    const float* Wpv     = (const float*)d_in[9];
    const float* Wread0  = (const float*)d_in[10];  // [64,1]
    const float* Wr1a    = (const float*)d_in[11];  // [64,16]
    const float* Wr1b    = (const float*)d_in[12];  // [16,1]
    const int* senders   = (const int*)d_in[13];
    const int* receivers = (const int*)d_in[14];
    const int* species   = (const int*)d_in[15];
    float* out = (float*)d_out;

    float* ws = (float*)d_ws;
    float* edata = ws; ws += (size_t)N_EDGES * 8;   // 8 MB (32 B/edge packed)
    float* agg_s = ws; ws += (size_t)N_NODES * 64;  // 8 MB
    float* agg_v = ws; ws += (size_t)N_NODES * 192; // 24 MB
    unsigned short* svp = (unsigned short*)ws; ws += (size_t)N_NODES * 128; // 16 MB packed {s,v0,v1,v2} bf16
    int* counts    = (int*)ws; ws += N_NODES;
    int* row_start = (int*)ws; ws += N_NODES + 4;
    int* cursor    = (int*)ws; ws += N_NODES;
    int* rrank     = (int*)ws; ws += N_EDGES;       // cached rank[receivers[e]]
    int* srk       = (int*)ws; ws += N_EDGES;
    int* grp_row   = (int*)ws; ws += N_EDGES / 16;
    int* sidx      = (int*)ws; ws += N_NODES;
    int* rank      = (int*)ws; ws += N_NODES;
    int* spec_srt  = (int*)ws; ws += N_NODES;
    int* lrank_arr = (int*)ws; ws += N_NODES;       // reused as rsp after sort3
    int* counts_blk = (int*)ws; ws += 128 * NSPEC;
    int* off_blk    = (int*)ws; ws += 128 * NSPEC;
    short* packW   = (short*)ws;                    // 224 KB

    // species counting sort (sort1 also zeroes CSR counts; sort3 fuses rsp)
    sort1_kernel<<<N_NODES / 256, 256, 0, stream>>>(
        species, counts_blk, lrank_arr, counts);
    sort2_kernel<<<1, 640, 0, stream>>>(counts_blk, off_blk);
    sort3_kernel<<<N_NODES / 256, 256, 0, stream>>>(
        species, lrank_arr, off_blk, sidx, rank, spec_srt);

    // receiver CSR in sorted space (hist caches rrank for the mega kernel)
    hist_kernel<<<N_EDGES / 256, 256, 0, stream>>>(receivers, rank, counts, rrank);
    scan_kernel<<<1, 1024, 0, stream>>>(counts, row_start, cursor);

    // MEGA: edge scatter + features + srk + weight pack + zero_bnd + grp_row
    mega_kernel<<<N_EDGES / 256, 256, 0, stream>>>(
        vectors, senders, lrank_arr /*rsp*/, rrank, cursor, row_start,
        edata, srk, grp_row,
        Wls, Wlv, Wps, Wpv, skip_s, skip_v, packW, agg_s, agg_v);

    // interaction 0 (gather reads embed table; node fuses read0 + re-zeroing
    // and writes the packed state for interaction 1's gather)
    gather_kernel<1><<<N_EDGES / 32, 64, 0, stream>>>(
        edata, srk, row_start, grp_row, embed_s, svp, Wr, agg_s, agg_v);
    node_mfma_kernel<<<N_NODES / 64, 256, 0, stream>>>(
        agg_s, agg_v, svp, packW, 0, pw, spec_srt,
        row_start, sidx, Wread0, Wr1a, Wr1b, out, 0);

    // interaction 1 (packed bf16 state: ONE 8-B random load per edge/lane)
    gather_kernel<0><<<N_EDGES / 32, 64, 0, stream>>>(
        edata, srk, row_start, grp_row, embed_s, svp, Wr + 2560, agg_s, agg_v);
    node_mfma_kernel<<<N_NODES / 64, 256, 0, stream>>>(
        agg_s, agg_v, svp, packW, 1, pw + 5760, spec_srt,
        row_start, sidx, Wread0, Wr1a, Wr1b, out, 1);
}